// Round 14
// baseline (191.785 us; speedup 1.0000x reference)
//
#include <hip/hip_runtime.h>
#include <hip/hip_bf16.h>
#include <cstdint>

typedef __bf16 bhalf;
typedef __bf16 bhalf8 __attribute__((ext_vector_type(8)));
typedef float f32x4 __attribute__((ext_vector_type(4)));

enum { EPI_Z2=0, EPI_UV=1, EPI_BIAS=2, EPI_QK=3, EPI_ATTN=4, EPI_PV=5, EPI_Y=6 };

// async global->LDS, 16B per lane, LDS dest = wave-uniform base + lane*16
__device__ __forceinline__ void gl_lds16(const bhalf* g, bhalf* l) {
  __builtin_amdgcn_global_load_lds(
      (const __attribute__((address_space(1))) unsigned int*)g,
      (__attribute__((address_space(3))) unsigned int*)l,
      16, 0, 0);
}
__device__ __forceinline__ void barrier_raw() { asm volatile("s_barrier" ::: "memory"); }
#define VMW(n)  asm volatile("s_waitcnt vmcnt(" #n ")" ::: "memory")
#define LGKM0() asm volatile("s_waitcnt lgkmcnt(0)" ::: "memory")

// Staging bank swizzle (verified R4-R13: SQ_LDS_BANK_CONFLICT == 0): 16B chunk
// c of a 64B row r holds global chunk c ^ ((r>>1)&3). Write: pre-swizzled
// GLOBAL source, linear LDS dest (rule #21); read: kqs = kq ^ ((lm>>1)&3).
// Epilogue token-major C-tile swizzle: 32B chunk ^ ((row>>2)&3).
// Epilogue TRANSPOSED C-tile swizzle: element t of row c at t ^ ((c&15)<<2).

// ---------------------------------------------------------------------------
// g4k: 128x128 tile, 4 waves (2M x 2N, wave 64x64), BK=64, 2 dbufs (64 KB ->
// 2 blocks/CU), 2-ahead in-place staging, VMW(8)/K-tile.
// One kernel for ALL GEMMs: z2 / UV / h / QK / score / PV / y.
// ---------------------------------------------------------------------------
template<int EPI>
__global__ void __launch_bounds__(256, 2)
g4k(const bhalf* __restrict__ A, const bhalf* __restrict__ Bw,
    void* __restrict__ Out, void* __restrict__ Out2,
    const float* __restrict__ bias, const float* __restrict__ bias2,
    const bhalf* __restrict__ auxb, const float* __restrict__ auxf,
    const float* __restrict__ xadd,
    int N, int K, long sA, long sB, long sO, float scale, int rowshift)
{
  constexpr int KSL = 256*64;     // 16 KB plane: A rows 0-127, B rows 128-255
  constexpr int DBUF = 2*KSL;     // 32 KB
  __shared__ __align__(16) char lds[2*DBUF];   // 64 KB

  const int gx = gridDim.x, gy = gridDim.y;
  const int nwg = gx*gy;
  const int flat = blockIdx.y*gx + blockIdx.x;
  const int q8 = nwg>>3, r8 = nwg&7, xcd = flat&7, o8 = flat>>3;
  const int w = (xcd<r8 ? xcd*(q8+1) : r8*(q8+1)+(xcd-r8)*q8) + o8;
  const int bx = w % gx, by = w / gx;
  const int m0 = by*128, n0 = bx*128;
  const int bz = blockIdx.z;

  const bhalf* Ab = A + (long)bz*sA;
  const bhalf* Bb = Bw + (long)bz*sB + (rowshift ? (long)(m0>>rowshift)*sB : 0);

  const int tid = threadIdx.x;
  const int wid = tid>>6, lane = tid&63;
  const int lm = lane&15, kq = lane>>4;
  const int wm = wid>>1, wn = wid&1;
  const int srow = lane>>2;
  const int csw = ((lane&3) ^ ((lane>>3)&3))*8;
  const int kqs = kq ^ ((lm>>1)&3);

  f32x4 acc[4][4];
  #pragma unroll
  for (int i=0;i<4;i++)
    #pragma unroll
    for (int j=0;j<4;j++) acc[i][j] = f32x4{0.f,0.f,0.f,0.f};

  auto stage = [&](int kt){                      // 8 loads/wave
    char* base = lds + (kt&1)*DBUF;
    const int k0 = kt*64;
    #pragma unroll
    for (int c=0;c<4;c++){
      const int r0 = c*64 + wid*16;
      #pragma unroll
      for (int ksl=0; ksl<2; ksl++){
        bhalf* d = (bhalf*)(base + ksl*KSL + r0*64);
        const bhalf* g = (r0 < 128)
          ? Ab + (long)(m0 + r0 + srow)*K + k0 + ksl*32 + csw
          : Bb + (long)(n0 + r0 - 128 + srow)*K + k0 + ksl*32 + csw;
        gl_lds16(g, d);
      }
    }
  };

  bhalf8 af[4][2], bf[4][2];
  auto readA = [&](int kt){
    char* base = lds + (kt&1)*DBUF;
    #pragma unroll
    for (int i2=0;i2<4;i2++)
      #pragma unroll
      for (int ksl=0;ksl<2;ksl++)
        af[i2][ksl] = *(const bhalf8*)(base + ksl*KSL + (wm*64 + i2*16 + lm)*64 + kqs*16);
  };
  auto readB = [&](int kt, int jh){
    char* base = lds + (kt&1)*DBUF;
    #pragma unroll
    for (int j2=0;j2<2;j2++)
      #pragma unroll
      for (int ksl=0;ksl<2;ksl++)
        bf[jh*2+j2][ksl] = *(const bhalf8*)(base + ksl*KSL + (128 + wn*64 + jh*32 + j2*16 + lm)*64 + kqs*16);
  };
  auto mfma16 = [&](int jh){
    __builtin_amdgcn_s_setprio(1);
    #pragma unroll
    for (int i2=0;i2<4;i2++)
      #pragma unroll
      for (int j2=0;j2<2;j2++)
        #pragma unroll
        for (int ksl=0;ksl<2;ksl++)
          acc[i2][jh*2+j2] = __builtin_amdgcn_mfma_f32_16x16x32_bf16(
              af[i2][ksl], bf[jh*2+j2][ksl], acc[i2][jh*2+j2], 0,0,0);
    __builtin_amdgcn_s_setprio(0);
  };

  const int NT = K>>6;
  stage(0); stage(1);
  for (int kt=0; kt<NT; ++kt){
    if (kt==NT-1) { VMW(0); } else { VMW(8); }
    barrier_raw();
    readA(kt); readB(kt,0);
    mfma16(0);
    barrier_raw();
    readB(kt,1);
    if (kt+2<NT) stage(kt+2);
    mfma16(1);
  }
  barrier_raw();

  // ---- epilogues ----
  if constexpr (EPI==EPI_Y){
    // fp32 transposed C-tile [c][128 tokens], fused residual add
    #pragma unroll
    for (int i=0;i<4;i++){
      #pragma unroll
      for (int j=0;j<4;j++){
        const int lcol = wn*64 + j*16 + lm;
        #pragma unroll
        for (int r=0;r<4;r++){
          const int lrow = wm*64 + i*16 + kq*4 + r;
          float v = acc[i][j][r] + bias[n0 + lcol];
          const int lb = lcol*512 + 4*(lrow ^ ((lcol&15)<<2));
          *(float*)(lds + lb) = v;
        }
      }
    }
    LGKM0();
    barrier_raw();
    const int b = m0 >> 11, nb = m0 & 2047;
    float* ob = (float*)Out + ((long)b*512 + n0)*2048 + nb;
    const float* xb = xadd + ((long)b*512 + n0)*2048 + nb;
    #pragma unroll
    for (int it=0; it<16; ++it){
      const int g = (it*256 + tid)*16;
      const int row = g >> 9, off = g & 511;
      const int t0 = off >> 2;
      const int s = (row&15)<<2;
      f32x4 vv = *(const f32x4*)(lds + row*512 + 4*(t0^s));
      f32x4 xx = *(const f32x4*)(xb + (long)row*2048 + t0);
      *(f32x4*)(ob + (long)row*2048 + t0) = vv + xx;
    }
  } else if constexpr (EPI==EPI_ATTN){
    float rs[4][4];
    #pragma unroll
    for (int i=0;i<4;i++)
      #pragma unroll
      for (int r=0;r<4;r++) rs[i][r]=0.f;
    #pragma unroll
    for (int i=0;i<4;i++){
      #pragma unroll
      for (int j=0;j<4;j++){
        const int lcol = wn*64 + j*16 + lm;
        #pragma unroll
        for (int r=0;r<4;r++){
          const int lrow = wm*64 + i*16 + kq*4 + r;
          float v = acc[i][j][r];
          v *= scale; v = fmaxf(v,0.f); v = v*v;
          rs[i][r] += v;
          const int cb = lcol*2;
          const int lb = lrow*256 + (((cb>>5) ^ ((lrow>>2)&3))<<5) + (cb&31);
          *(bhalf*)(lds + lb) = (bhalf)v;
        }
      }
    }
    float* rd = (float*)Out2 + (long)bz*2048;
    #pragma unroll
    for (int i=0;i<4;i++){
      const int rbase = m0 + wm*64 + i*16 + kq*4;
      #pragma unroll
      for (int r=0;r<4;r++){
        float s = rs[i][r];
        s += __shfl_xor(s,1); s += __shfl_xor(s,2);
        s += __shfl_xor(s,4); s += __shfl_xor(s,8);
        if (lm==0) atomicAdd(rd + rbase + r, s);
      }
    }
    LGKM0();
    barrier_raw();
    char* obase = (char*)Out + 2*((long)bz*sO + (long)m0*N + n0);
    const int ldb = N*2;
    #pragma unroll
    for (int it=0; it<8; ++it){
      const int g = (it*256 + tid)*16;
      const int row = g >> 8, off = g & 255;
      const int lb = row*256 + (((off>>5) ^ ((row>>2)&3))<<5) + (off&31);
      uint4 val = *(const uint4*)(lds + lb);
      *(uint4*)(obase + (long)row*ldb + off) = val;
    }
  } else if constexpr (EPI==EPI_UV){
    const bool uh = n0 < 1024;
    const float* bv = uh ? bias : bias2;
    const int bc0 = uh ? n0 : n0-1024;
    #pragma unroll
    for (int i=0;i<4;i++){
      #pragma unroll
      for (int j=0;j<4;j++){
        const int lcol = wn*64 + j*16 + lm;
        #pragma unroll
        for (int r=0;r<4;r++){
          const int lrow = wm*64 + i*16 + kq*4 + r;
          float v = acc[i][j][r] + bv[bc0 + lcol];
          if (uh){
            v = 1.f/(1.f + __expf(-v));
            const int cb = lcol*2;
            const int lb = lrow*256 + (((cb>>5) ^ ((lrow>>2)&3))<<5) + (cb&31);
            *(bhalf*)(lds + lb) = (bhalf)v;
          } else {
            // transposed: row = v-channel, elem = token (128), XOR-swizzled
            const int lb = lcol*256 + 2*(lrow ^ ((lcol&15)<<2));
            *(bhalf*)(lds + lb) = (bhalf)v;
          }
        }
      }
    }
    LGKM0();
    barrier_raw();
    if (uh){
      char* obase = (char*)Out + 2*((long)m0*1024 + n0);
      #pragma unroll
      for (int it=0; it<8; ++it){
        const int g = (it*256 + tid)*16;
        const int row = g >> 8, off = g & 255;
        const int lb = row*256 + (((off>>5) ^ ((row>>2)&3))<<5) + (off&31);
        uint4 val = *(const uint4*)(lds + lb);
        *(uint4*)(obase + (long)row*2048 + off) = val;
      }
    } else {
      // v_fm [B][1024][2048]: row = v-channel, 256B = 128 tokens
      char* vb = (char*)Out2 + 2*((long)(m0>>11)*1024*2048 + (long)(n0-1024)*2048 + (m0 & 2047));
      #pragma unroll
      for (int it=0; it<8; ++it){
        const int g = (it*256 + tid)*16;
        const int row = g >> 8, off = g & 255;
        const int t0 = off >> 1;
        const int s = (row&15)<<2;
        unsigned long long lo = *(const unsigned long long*)(lds + row*256 + 2*(t0^s));
        unsigned long long hi = *(const unsigned long long*)(lds + row*256 + 2*((t0+4)^s));
        char* dst = vb + (long)row*4096 + off;
        ((unsigned long long*)dst)[0] = lo;
        ((unsigned long long*)dst)[1] = hi;
      }
    }
  } else {
    char* obase; int ldb;
    if constexpr (EPI==EPI_QK){
      bool qh = n0 < 512;
      obase = (char*)(qh?Out:Out2) + 2*((long)m0*512 + (n0 - (qh?0:512)));
      ldb = 1024;
    } else {
      obase = (char*)Out + 2*((long)m0*N + n0);
      ldb = N*2;
    }
    #pragma unroll
    for (int i=0;i<4;i++){
      #pragma unroll
      for (int j=0;j<4;j++){
        const int lcol = wn*64 + j*16 + lm;
        #pragma unroll
        for (int r=0;r<4;r++){
          const int lrow = wm*64 + i*16 + kq*4 + r;
          float v = acc[i][j][r];
          if constexpr (EPI==EPI_Z2)
            v += (float)auxb[(long)(m0+lrow)*N + n0 + lcol];
          if constexpr (EPI==EPI_BIAS)
            v += bias[n0 + lcol];
          if constexpr (EPI==EPI_PV){
            const int rowg = m0 + lrow;
            float den = auxf[rowg];
            v *= __builtin_amdgcn_rcpf(den + 1e-8f);
            v *= (float)auxb[(long)rowg*1024 + n0 + lcol];
          }
          const int cb = lcol*2;
          const int lb = lrow*256 + (((cb>>5) ^ ((lrow>>2)&3))<<5) + (cb&31);
          *(bhalf*)(lds + lb) = (bhalf)v;
        }
      }
    }
    LGKM0();
    barrier_raw();
    #pragma unroll
    for (int it=0; it<8; ++it){
      const int g = (it*256 + tid)*16;
      const int row = g >> 8, off = g & 255;
      const int lb = row*256 + (((off>>5) ^ ((row>>2)&3))<<5) + (off&31);
      uint4 val = *(const uint4*)(lds + lb);
      *(uint4*)(obase + (long)row*ldb + off) = val;
    }
  }
  (void)xadd; (void)bias; (void)bias2; (void)auxb; (void)auxf; (void)scale;
}

// ---------------------------------------------------------------------------
struct CvtArgs { const float* src[7]; bhalf* dst[7]; int n[7]; };
__global__ void cvt_multi(CvtArgs a) {
  int seg = blockIdx.y;
  int i = (blockIdx.x*256 + threadIdx.x)*4;
  if (i >= a.n[seg]) return;
  float4 f = *(const float4*)(a.src[seg] + i);
  bhalf* d = a.dst[seg] + i;
  d[0]=(bhalf)f.x; d[1]=(bhalf)f.y; d[2]=(bhalf)f.z; d[3]=(bhalf)f.w;
}

__global__ void gn_part(const float* __restrict__ x, float* __restrict__ ps, float* __restrict__ pss) {
  int b = blockIdx.y;
  const float* xb = x + (long)b*(512*2048);
  float s=0.f, ss=0.f;
  #pragma unroll
  for (int it=0; it<8; it++){
    int idx = ((it*128 + blockIdx.x)*256 + threadIdx.x)*4;
    float4 f = *(const float4*)(xb + idx);
    s  += f.x+f.y+f.z+f.w;
    ss += f.x*f.x+f.y*f.y+f.z*f.z+f.w*f.w;
  }
  for (int off=32; off; off>>=1){ s += __shfl_xor(s,off); ss += __shfl_xor(ss,off); }
  __shared__ float ls[4], lss[4];
  int wid = threadIdx.x>>6, lane = threadIdx.x&63;
  if (lane==0){ ls[wid]=s; lss[wid]=ss; }
  __syncthreads();
  if (threadIdx.x==0){
    s = ls[0]+ls[1]+ls[2]+ls[3]; ss = lss[0]+lss[1]+lss[2]+lss[3];
    ps[b*128 + blockIdx.x] = s; pss[b*128 + blockIdx.x] = ss;
  }
}

__global__ void gn_final(const float* __restrict__ ps, const float* __restrict__ pss,
                         float* __restrict__ stats) {
  int b = blockIdx.x;
  float s = ps[b*128 + threadIdx.x], ss = pss[b*128 + threadIdx.x];
  for (int off=32; off; off>>=1){ s += __shfl_xor(s,off); ss += __shfl_xor(ss,off); }
  __shared__ float l0[2], l1[2];
  int wid = threadIdx.x>>6, lane = threadIdx.x&63;
  if (lane==0){ l0[wid]=s; l1[wid]=ss; }
  __syncthreads();
  if (threadIdx.x==0){
    s = l0[0]+l0[1]; ss = l1[0]+l1[1];
    float mean = s*(1.f/1048576.f);
    float var  = ss*(1.f/1048576.f) - mean*mean;
    stats[b*2] = mean; stats[b*2+1] = rsqrtf(var + 1e-8f);
  }
}

__global__ void norm_dw_T(const float* __restrict__ x, const float* __restrict__ stats,
                          const float* __restrict__ dw_w,
                          bhalf* __restrict__ zT, bhalf* __restrict__ dwT) {
  int b = blockIdx.z, n0 = blockIdx.x*32, c0 = blockIdx.y*32;
  float mean = stats[b*2], rstd = stats[b*2+1];
  __shared__ float zs[32][35];
  int tx = threadIdx.x, ty = threadIdx.y;
  #pragma unroll
  for (int r=0;r<4;r++){
    int c = c0 + ty + r*8;
    for (int cc=tx; cc<34; cc+=32){
      int n = n0 - 1 + cc;
      float v = 0.f;
      if (n>=0 && n<2048) v = (x[((long)b*512 + c)*2048 + n] - mean)*rstd;
      zs[ty + r*8][cc] = v;
    }
  }
  __syncthreads();
  float w0 = dw_w[(c0+tx)*3+0], w1 = dw_w[(c0+tx)*3+1], w2 = dw_w[(c0+tx)*3+2];
  #pragma unroll
  for (int r=0;r<4;r++){
    int ln = ty + r*8;
    float z = zs[tx][ln+1];
    float d = w0*zs[tx][ln] + w1*zs[tx][ln+1] + w2*zs[tx][ln+2];
    long o = ((long)b*2048 + n0 + ln)*512 + c0 + tx;
    zT[o] = (bhalf)z; dwT[o] = (bhalf)d;
  }
}

// ---------------------------------------------------------------------------
extern "C" void kernel_launch(void* const* d_in, const int* in_sizes, int n_in,
                              void* d_out, int out_size, void* d_ws, size_t ws_size,
                              hipStream_t stream) {
  (void)in_sizes; (void)n_in; (void)out_size; (void)ws_size;
  const float* x    = (const float*)d_in[0];
  const float* dw_w = (const float*)d_in[1];
  const float* pw_w = (const float*)d_in[2];
  const float* u_w  = (const float*)d_in[3];
  const float* u_b  = (const float*)d_in[4];
  const float* v_w  = (const float*)d_in[5];
  const float* v_b  = (const float*)d_in[6];
  const float* h_w  = (const float*)d_in[7];
  const float* h_b  = (const float*)d_in[8];
  const float* q_w  = (const float*)d_in[9];
  const float* k_w  = (const float*)d_in[10];
  const float* o_w  = (const float*)d_in[11];
  const float* o_b  = (const float*)d_in[12];
  float* out = (float*)d_out;

  char* ws = (char*)d_ws;
  size_t off = 0;
  auto alloc = [&](size_t bytes) -> void* {
    void* p = ws + off; off = (off + bytes + 255) & ~(size_t)255; return p;
  };

  float* ps    = (float*)alloc(4*128*4);
  float* pss   = (float*)alloc(4*128*4);
  float* stats = (float*)alloc(4*2*4);
  float* rden  = (float*)alloc(4*2048*4);
  bhalf* wb_pw = (bhalf*)alloc(512*512*2);
  bhalf* wb_uv = (bhalf*)alloc((size_t)2048*512*2);
  bhalf* wb_h  = (bhalf*)alloc(512*512*2);
  bhalf* wb_qk = (bhalf*)alloc((size_t)1024*512*2);
  bhalf* wb_o  = (bhalf*)alloc((size_t)512*1024*2);
  const size_t ACT = (size_t)4*2048*512;
  bhalf* zT   = (bhalf*)alloc(ACT*2);       // reused as qb
  bhalf* dwT  = (bhalf*)alloc(ACT*2);       // reused as kb
  bhalf* z2T  = (bhalf*)alloc(ACT*2);
  bhalf* ub   = (bhalf*)alloc(ACT*2*2);     // [B,N,1024]
  bhalf* v_fm = (bhalf*)alloc(ACT*2*2);     // [B,1024,2048] (written by UV)
  bhalf* hb   = (bhalf*)alloc(ACT*2);
  bhalf* wsc  = (bhalf*)alloc((size_t)4*2048*2048*2);
  bhalf* uav  = (bhalf*)alloc(ACT*2*2);
  bhalf* qb = zT;  bhalf* kb = dwT;

  // 0. zero attention-denominator accumulators
  hipMemsetAsync(rden, 0, 4*2048*4, stream);

  // 1. weights -> bf16 (u|v and q|k concatenated)
  CvtArgs ca;
  ca.src[0]=pw_w; ca.dst[0]=wb_pw;           ca.n[0]=512*512;
  ca.src[1]=u_w;  ca.dst[1]=wb_uv;           ca.n[1]=1024*512;
  ca.src[2]=v_w;  ca.dst[2]=wb_uv+1024*512;  ca.n[2]=1024*512;
  ca.src[3]=h_w;  ca.dst[3]=wb_h;            ca.n[3]=512*512;
  ca.src[4]=q_w;  ca.dst[4]=wb_qk;           ca.n[4]=512*512;
  ca.src[5]=k_w;  ca.dst[5]=wb_qk+512*512;   ca.n[5]=512*512;
  ca.src[6]=o_w;  ca.dst[6]=wb_o;            ca.n[6]=512*1024;
  cvt_multi<<<dim3(512,7), 256, 0, stream>>>(ca);

  // 2-3. GroupNorm stats
  gn_part<<<dim3(128,4), 256, 0, stream>>>(x, ps, pss);
  gn_final<<<dim3(4), 128, 0, stream>>>(ps, pss, stats);

  // 4. normalize + dw conv + transpose -> zT, dwT
  norm_dw_T<<<dim3(64,16,4), dim3(32,8), 0, stream>>>(x, stats, dw_w, zT, dwT);

  const float iscl = 0.044194173824159216f;   // 1/sqrt(512)
  // 5. z2 = z + dw @ pw^T
  g4k<EPI_Z2><<<dim3(4,64,1), 256, 0, stream>>>(dwT, wb_pw, z2T, nullptr,
      nullptr, nullptr, zT, nullptr, nullptr, 512, 512, 0,0,0, 0.f, 0);
  // 6. [u|v] = z2 @ [u_w|v_w]^T + b   (1024 blocks; u->ub, v->v_fm direct)
  g4k<EPI_UV><<<dim3(16,64,1), 256, 0, stream>>>(z2T, wb_uv, ub, v_fm,
      u_b, v_b, nullptr, nullptr, nullptr, 2048, 512, 0,0,0, 0.f, 0);
  // 7. h = z2 @ h_w^T + h_b
  g4k<EPI_BIAS><<<dim3(4,64,1), 256, 0, stream>>>(z2T, wb_h, hb, nullptr,
      h_b, nullptr, nullptr, nullptr, nullptr, 512, 512, 0,0,0, 0.f, 0);
  // 8. [q|k] = h @ [q_w|k_w]^T        (512 blocks)
  g4k<EPI_QK><<<dim3(8,64,1), 256, 0, stream>>>(hb, wb_qk, qb, kb,
      nullptr, nullptr, nullptr, nullptr, nullptr, 1024, 512, 0,0,0, 0.f, 0);
  // 9. w = relu(q@k^T * scale)^2 + fused row-sum atomics   (1024 blocks)
  g4k<EPI_ATTN><<<dim3(16,16,4), 256, 0, stream>>>(qb, kb, wsc, rden,
      nullptr, nullptr, nullptr, nullptr, nullptr, 2048, 512,
      (long)2048*512, (long)2048*512, (long)2048*2048, iscl, 0);
  // 10. uav = u * (w @ v_fm^T) / (den+eps)   (512 blocks, batch in M)
  g4k<EPI_PV><<<dim3(8,64,1), 256, 0, stream>>>(wsc, v_fm, uav, nullptr,
      nullptr, nullptr, ub, rden, nullptr, 1024, 2048,
      0, (long)1024*2048, 0, 0.f, 11);
  // 11. out = x + (uav @ o_w^T + o_b)^T   (fused residual add)
  g4k<EPI_Y><<<dim3(4,64,1), 256, 0, stream>>>(uav, wb_o, out, nullptr,
      o_b, nullptr, nullptr, nullptr, x, 512, 1024, 0,0,0, 0.f, 0);
}

// Round 15
// 185.683 us; speedup vs baseline: 1.0329x; 1.0329x over previous
//
#include <hip/hip_runtime.h>
#include <hip/hip_bf16.h>
#include <cstdint>

typedef __bf16 bhalf;
typedef __bf16 bhalf8 __attribute__((ext_vector_type(8)));
typedef float f32x4 __attribute__((ext_vector_type(4)));

enum { EPI_Z2=0, EPI_UV=1, EPI_BIAS=2, EPI_QK=3, EPI_ATTN=4, EPI_PV=5, EPI_Y=6, EPI_ST=7 };

// async global->LDS, 16B per lane, LDS dest = wave-uniform base + lane*16
__device__ __forceinline__ void gl_lds16(const bhalf* g, bhalf* l) {
  __builtin_amdgcn_global_load_lds(
      (const __attribute__((address_space(1))) unsigned int*)g,
      (__attribute__((address_space(3))) unsigned int*)l,
      16, 0, 0);
}
__device__ __forceinline__ void barrier_raw() { asm volatile("s_barrier" ::: "memory"); }
#define VMW(n)  asm volatile("s_waitcnt vmcnt(" #n ")" ::: "memory")
#define LGKM0() asm volatile("s_waitcnt lgkmcnt(0)" ::: "memory")

// Staging bank swizzle (verified R4-R14: SQ_LDS_BANK_CONFLICT == 0): 16B chunk
// c of a 64B row r holds global chunk c ^ ((r>>1)&3). Write: pre-swizzled
// GLOBAL source, linear LDS dest (rule #21); read: kqs = kq ^ ((lm>>1)&3).
// Epilogue token-major C-tile swizzle: 32B chunk ^ ((row>>2)&3).
// Epilogue TRANSPOSED C-tile swizzle: element t of row c at t ^ ((c&15)<<2).

// ---------------------------------------------------------------------------
// gA: 256x256, BK=64, 8 waves (2M x 4N, wave 128x64), 2 dbufs (128 KB),
// 4 phases/K-tile of 16 MFMA, in-place region staging, VMW(4)/K-tile.
// For score / UV. UV: u->ub (sigmoid), v->v_fm (transposed direct).
// ---------------------------------------------------------------------------
template<int EPI>
__global__ void __launch_bounds__(512, 2)
gA(const bhalf* __restrict__ A, const bhalf* __restrict__ Bw,
   void* __restrict__ Out, void* __restrict__ Out2,
   const float* __restrict__ bias, const float* __restrict__ bias2,
   int N, int K, long sA, long sB, long sO, long sAuxf, float scale)
{
  constexpr int KSL = 256*64;     // 16 KB per k-slice plane
  constexpr int REG = 2*KSL;      // 32 KB (one K-tile of A or B)
  constexpr int DBUF = 2*REG;     // 64 KB
  __shared__ __align__(16) char lds[2*DBUF];   // 128 KB

  const int gx = gridDim.x, gy = gridDim.y;
  const int nwg = gx*gy;
  const int flat = blockIdx.y*gx + blockIdx.x;
  const int q8 = nwg>>3, r8 = nwg&7, xcd = flat&7, o8 = flat>>3;
  const int wsw = (xcd<r8 ? xcd*(q8+1) : r8*(q8+1)+(xcd-r8)*q8) + o8;
  const int bx = wsw % gx, by = wsw / gx;
  const int m0 = by*256, n0 = bx*256;
  const int bz = blockIdx.z;

  const bhalf* Ab = A + (long)bz*sA;
  const bhalf* Bb = Bw + (long)bz*sB;

  const int tid = threadIdx.x, wid = tid>>6, lane = tid&63;
  const int lm = lane&15, kq = lane>>4;
  const int wm = wid>>2, wn = wid&3;
  const int srow = lane>>2;
  const int csw = ((lane&3) ^ ((lane>>3)&3)) * 8;
  const int kqs = kq ^ ((lm>>1)&3);

  f32x4 acc[8][4];
  #pragma unroll
  for (int i=0;i<8;i++)
    #pragma unroll
    for (int j=0;j<4;j++) acc[i][j] = f32x4{0.f,0.f,0.f,0.f};

  auto stageA = [&](int kt){                     // 4 loads/wave
    char* base = lds + (kt&1)*DBUF;
    const int k0 = kt*64;
    #pragma unroll
    for (int h=0; h<2; h++)
      #pragma unroll
      for (int ksl=0; ksl<2; ksl++){
        bhalf* d = (bhalf*)(base + ksl*KSL + (h*128 + wid*16)*64);
        gl_lds16(Ab + (long)(m0 + h*128 + wid*16 + srow)*K + k0 + ksl*32 + csw, d);
      }
  };
  auto stageB = [&](int kt){                     // 4 loads/wave
    char* base = lds + (kt&1)*DBUF + REG;
    const int k0 = kt*64;
    #pragma unroll
    for (int h=0; h<2; h++)
      #pragma unroll
      for (int ksl=0; ksl<2; ksl++){
        bhalf* d = (bhalf*)(base + ksl*KSL + (h*128 + wid*16)*64);
        gl_lds16(Bb + (long)(n0 + h*128 + wid*16 + srow)*K + k0 + ksl*32 + csw, d);
      }
  };

  bhalf8 af[4][2], bf[4][2];
  auto readA = [&](int kt, int ih){
    char* base = lds + (kt&1)*DBUF;
    #pragma unroll
    for (int i2=0;i2<4;i2++)
      #pragma unroll
      for (int ksl=0;ksl<2;ksl++)
        af[i2][ksl] = *(const bhalf8*)(base + ksl*KSL + (wm*128 + ih*64 + i2*16 + lm)*64 + kqs*16);
  };
  auto readB = [&](int kt, int jh){
    char* base = lds + (kt&1)*DBUF + REG;
    #pragma unroll
    for (int j2=0;j2<2;j2++)
      #pragma unroll
      for (int ksl=0;ksl<2;ksl++)
        bf[jh*2+j2][ksl] = *(const bhalf8*)(base + ksl*KSL + (wn*64 + jh*32 + j2*16 + lm)*64 + kqs*16);
  };
  auto mfma16 = [&](int ih, int jh){
    __builtin_amdgcn_s_setprio(1);
    #pragma unroll
    for (int i2=0;i2<4;i2++)
      #pragma unroll
      for (int j2=0;j2<2;j2++)
        #pragma unroll
        for (int ksl=0;ksl<2;ksl++)
          acc[ih*4+i2][jh*2+j2] = __builtin_amdgcn_mfma_f32_16x16x32_bf16(
              af[i2][ksl], bf[jh*2+j2][ksl], acc[ih*4+i2][jh*2+j2], 0,0,0);
    __builtin_amdgcn_s_setprio(0);
  };

  const int NT = K>>6;
  stageA(0); stageB(0); stageA(1);               // 12 loads
  for (int kt=0; kt<NT; ++kt){
    if (kt==NT-1) { VMW(0); } else { VMW(4); }
    barrier_raw();
    readA(kt,0); readB(kt,0);
    if (kt+1<NT) stageB(kt+1);
    mfma16(0,0);
    barrier_raw();
    readB(kt,1);
    mfma16(0,1);
    barrier_raw();
    readA(kt,1);
    mfma16(1,0);
    barrier_raw();
    if (kt+2<NT) stageA(kt+2);
    mfma16(1,1);
  }
  barrier_raw();

  // ---- epilogues ----
  if constexpr (EPI==EPI_ATTN){
    float rs[8][4];
    #pragma unroll
    for (int i=0;i<8;i++)
      #pragma unroll
      for (int r=0;r<4;r++) rs[i][r]=0.f;
    #pragma unroll
    for (int i=0;i<8;i++){
      #pragma unroll
      for (int j=0;j<4;j++){
        const int lcol = wn*64 + j*16 + lm;
        #pragma unroll
        for (int r=0;r<4;r++){
          const int lrow = wm*128 + i*16 + kq*4 + r;
          float v = acc[i][j][r];
          v *= scale; v = fmaxf(v,0.f); v = v*v;
          rs[i][r] += v;
          const int cb = lcol*2;
          const int lb = lrow*512 + (((cb>>5) ^ ((lrow>>2)&3))<<5) + (cb&31);
          *(bhalf*)(lds + lb) = (bhalf)v;
        }
      }
    }
    float* rd = (float*)Out2;
    #pragma unroll
    for (int i=0;i<8;i++){
      const int rbase = m0 + wm*128 + i*16 + kq*4;
      #pragma unroll
      for (int r=0;r<4;r++){
        float s = rs[i][r];
        s += __shfl_xor(s,1); s += __shfl_xor(s,2);
        s += __shfl_xor(s,4); s += __shfl_xor(s,8);
        if (lm==0) atomicAdd(rd + (long)bz*sAuxf + rbase + r, s);
      }
    }
    LGKM0();
    barrier_raw();
    char* obase = (char*)Out + 2*((long)bz*sO + (long)m0*N + n0);
    const int ldb = N*2;
    #pragma unroll
    for (int it=0; it<16; ++it){
      const int g = (it*512 + tid)*16;
      const int row = g >> 9, off = g & 511;
      const int lb = row*512 + (((off>>5) ^ ((row>>2)&3))<<5) + (off&31);
      uint4 val = *(const uint4*)(lds + lb);
      *(uint4*)(obase + (long)row*ldb + off) = val;
    }
  }
  if constexpr (EPI==EPI_UV){
    const bool uh = n0 < 1024;
    const float* bv = uh ? bias : bias2;
    const int bc0 = uh ? n0 : n0-1024;
    #pragma unroll
    for (int i=0;i<8;i++){
      #pragma unroll
      for (int j=0;j<4;j++){
        const int lcol = wn*64 + j*16 + lm;
        #pragma unroll
        for (int r=0;r<4;r++){
          const int lrow = wm*128 + i*16 + kq*4 + r;
          float v = acc[i][j][r] + bv[bc0 + lcol];
          if (uh){
            v = 1.f/(1.f + __expf(-v));
            const int cb = lcol*2;
            const int lb = lrow*512 + (((cb>>5) ^ ((lrow>>2)&3))<<5) + (cb&31);
            *(bhalf*)(lds + lb) = (bhalf)v;
          } else {
            const int lb = lcol*512 + 2*(lrow ^ ((lcol&15)<<2));
            *(bhalf*)(lds + lb) = (bhalf)v;
          }
        }
      }
    }
    LGKM0();
    barrier_raw();
    if (uh){
      char* obase = (char*)Out + 2*((long)m0*1024 + n0);
      #pragma unroll
      for (int it=0; it<16; ++it){
        const int g = (it*512 + tid)*16;
        const int row = g >> 9, off = g & 511;
        const int lb = row*512 + (((off>>5) ^ ((row>>2)&3))<<5) + (off&31);
        uint4 val = *(const uint4*)(lds + lb);
        *(uint4*)(obase + (long)row*2048 + off) = val;
      }
    } else {
      char* vb = (char*)Out2 + 2*((long)(m0>>11)*1024*2048 + (long)(n0-1024)*2048 + (m0 & 2047));
      #pragma unroll
      for (int it=0; it<16; ++it){
        const int g = (it*512 + tid)*16;
        const int row = g >> 9, off = g & 511;
        const int t0 = off >> 1;
        const int s = (row&15)<<2;
        unsigned long long lo = *(const unsigned long long*)(lds + row*512 + 2*(t0^s));
        unsigned long long hi = *(const unsigned long long*)(lds + row*512 + 2*((t0+4)^s));
        char* dst = vb + (long)row*4096 + off;
        ((unsigned long long*)dst)[0] = lo;
        ((unsigned long long*)dst)[1] = hi;
      }
    }
  }
  (void)scale; (void)bias; (void)bias2; (void)N;
}

// ---------------------------------------------------------------------------
// g4k: 128x128 tile, 4 waves (2M x 2N, wave 64x64), BK=64, 2 dbufs (64 KB),
// 2-ahead in-place staging, VMW(8)/K-tile. For z2 / QK / PV / y / wqk2.
// ---------------------------------------------------------------------------
template<int EPI>
__global__ void __launch_bounds__(256, 2)
g4k(const bhalf* __restrict__ A, const bhalf* __restrict__ Bw,
    void* __restrict__ Out, void* __restrict__ Out2,
    const float* __restrict__ bias,
    const bhalf* __restrict__ auxb, const float* __restrict__ auxf,
    const float* __restrict__ xadd,
    int M, int N, int K, long sB, int rowshift)
{
  constexpr int KSL = 256*64;     // 16 KB plane: A rows 0-127, B rows 128-255
  constexpr int DBUF = 2*KSL;     // 32 KB
  __shared__ __align__(16) char lds[2*DBUF];   // 64 KB

  const int gx = gridDim.x, gy = gridDim.y;
  const int nwg = gx*gy;
  const int flat = blockIdx.y*gx + blockIdx.x;
  const int q8 = nwg>>3, r8 = nwg&7, xcd = flat&7, o8 = flat>>3;
  const int w = (xcd<r8 ? xcd*(q8+1) : r8*(q8+1)+(xcd-r8)*q8) + o8;
  const int bx = w % gx, by = w / gx;
  const int m0 = by*128, n0 = bx*128;

  const bhalf* Bb = Bw + (rowshift ? (long)(m0>>rowshift)*sB : 0);

  const int tid = threadIdx.x;
  const int wid = tid>>6, lane = tid&63;
  const int lm = lane&15, kq = lane>>4;
  const int wm = wid>>1, wn = wid&1;
  const int srow = lane>>2;
  const int csw = ((lane&3) ^ ((lane>>3)&3))*8;
  const int kqs = kq ^ ((lm>>1)&3);

  f32x4 acc[4][4];
  #pragma unroll
  for (int i=0;i<4;i++)
    #pragma unroll
    for (int j=0;j<4;j++) acc[i][j] = f32x4{0.f,0.f,0.f,0.f};

  auto stage = [&](int kt){                      // 8 loads/wave
    char* base = lds + (kt&1)*DBUF;
    const int k0 = kt*64;
    #pragma unroll
    for (int c=0;c<4;c++){
      const int r0 = c*64 + wid*16;
      #pragma unroll
      for (int ksl=0; ksl<2; ksl++){
        bhalf* d = (bhalf*)(base + ksl*KSL + r0*64);
        const bhalf* g = (r0 < 128)
          ? A  + (long)(m0 + r0 + srow)*K + k0 + ksl*32 + csw
          : Bb + (long)(n0 + r0 - 128 + srow)*K + k0 + ksl*32 + csw;
        gl_lds16(g, d);
      }
    }
  };

  bhalf8 af[4][2], bf[4][2];
  auto readA = [&](int kt){
    char* base = lds + (kt&1)*DBUF;
    #pragma unroll
    for (int i2=0;i2<4;i2++)
      #pragma unroll
      for (int ksl=0;ksl<2;ksl++)
        af[i2][ksl] = *(const bhalf8*)(base + ksl*KSL + (wm*64 + i2*16 + lm)*64 + kqs*16);
  };
  auto readB = [&](int kt, int jh){
    char* base = lds + (kt&1)*DBUF;
    #pragma unroll
    for (int j2=0;j2<2;j2++)
      #pragma unroll
      for (int ksl=0;ksl<2;ksl++)
        bf[jh*2+j2][ksl] = *(const bhalf8*)(base + ksl*KSL + (128 + wn*64 + jh*32 + j2*16 + lm)*64 + kqs*16);
  };
  auto mfma16 = [&](int jh){
    __builtin_amdgcn_s_setprio(1);
    #pragma unroll
    for (int i2=0;i2<4;i2++)
      #pragma unroll
      for (int j2=0;j2<2;j2++)
        #pragma unroll
        for (int ksl=0;ksl<2;ksl++)
          acc[i2][jh*2+j2] = __builtin_amdgcn_mfma_f32_16x16x32_bf16(
              af[i2][ksl], bf[jh*2+j2][ksl], acc[i2][jh*2+j2], 0,0,0);
    __builtin_amdgcn_s_setprio(0);
  };

  const int NT = K>>6;
  stage(0); stage(1);
  for (int kt=0; kt<NT; ++kt){
    if (kt==NT-1) { VMW(0); } else { VMW(8); }
    barrier_raw();
    readA(kt); readB(kt,0);
    mfma16(0);
    barrier_raw();
    readB(kt,1);
    if (kt+2<NT) stage(kt+2);
    mfma16(1);
  }
  barrier_raw();

  // ---- epilogues ----
  if constexpr (EPI==EPI_Y){
    #pragma unroll
    for (int i=0;i<4;i++){
      #pragma unroll
      for (int j=0;j<4;j++){
        const int lcol = wn*64 + j*16 + lm;
        #pragma unroll
        for (int r=0;r<4;r++){
          const int lrow = wm*64 + i*16 + kq*4 + r;
          float v = acc[i][j][r] + bias[n0 + lcol];
          const int lb = lcol*512 + 4*(lrow ^ ((lcol&15)<<2));
          *(float*)(lds + lb) = v;
        }
      }
    }
    LGKM0();
    barrier_raw();
    const int b = m0 >> 11, nb = m0 & 2047;
    float* ob = (float*)Out + ((long)b*512 + n0)*2048 + nb;
    const float* xb = xadd + ((long)b*512 + n0)*2048 + nb;
    #pragma unroll
    for (int it=0; it<16; ++it){
      const int g = (it*256 + tid)*16;
      const int row = g >> 9, off = g & 511;
      const int t0 = off >> 2;
      const int s = (row&15)<<2;
      f32x4 vv = *(const f32x4*)(lds + row*512 + 4*(t0^s));
      f32x4 xx = *(const f32x4*)(xb + (long)row*2048 + t0);
      *(f32x4*)(ob + (long)row*2048 + t0) = vv + xx;
    }
  } else {
    char* obase; int ldb;
    if constexpr (EPI==EPI_QK){
      bool qh = n0 < 512;
      obase = (char*)(qh?Out:Out2) + 2*((long)m0*512 + (n0 - (qh?0:512)));
      ldb = 1024;
    } else {
      obase = (char*)Out + 2*((long)m0*N + n0);
      ldb = N*2;
    }
    #pragma unroll
    for (int i=0;i<4;i++){
      #pragma unroll
      for (int j=0;j<4;j++){
        const int lcol = wn*64 + j*16 + lm;
        #pragma unroll
        for (int r=0;r<4;r++){
          const int lrow = wm*64 + i*16 + kq*4 + r;
          float v = acc[i][j][r];
          if constexpr (EPI==EPI_Z2)
            v += (float)auxb[(long)(m0+lrow)*N + n0 + lcol];
          if constexpr (EPI==EPI_BIAS)
            v += bias[n0 + lcol];
          if constexpr (EPI==EPI_QK)
            v += bias[n0 + lcol];           // bq = [q_w;k_w] @ h_b
          if constexpr (EPI==EPI_PV){
            const int rowg = m0 + lrow;
            float den = auxf[rowg];
            v *= __builtin_amdgcn_rcpf(den + 1e-8f);
            v *= (float)auxb[(long)rowg*1024 + n0 + lcol];
          }
          const int cb = lcol*2;
          const int lb = lrow*256 + (((cb>>5) ^ ((lrow>>2)&3))<<5) + (cb&31);
          *(bhalf*)(lds + lb) = (bhalf)v;
        }
      }
    }
    LGKM0();
    barrier_raw();
    #pragma unroll
    for (int it=0; it<8; ++it){
      const int g = (it*256 + tid)*16;
      const int row = g >> 8, off = g & 255;
      const int lb = row*256 + (((off>>5) ^ ((row>>2)&3))<<5) + (off&31);
      uint4 val = *(const uint4*)(lds + lb);
      *(uint4*)(obase + (long)row*ldb + off) = val;
    }
  }
  (void)M; (void)xadd; (void)bias; (void)auxb; (void)auxf;
}

// ---------------------------------------------------------------------------
struct CvtArgs { const float* src[7]; bhalf* dst[7]; int n[7]; };
__global__ void cvt_multi(CvtArgs a) {
  int seg = blockIdx.y;
  int i = (blockIdx.x*256 + threadIdx.x)*4;
  if (i >= a.n[seg]) return;
  float4 f = *(const float4*)(a.src[seg] + i);
  bhalf* d = a.dst[seg] + i;
  d[0]=(bhalf)f.x; d[1]=(bhalf)f.y; d[2]=(bhalf)f.z; d[3]=(bhalf)f.w;
}

// bf16 transpose: in [R,C] -> out [C,R]
__global__ void transpose_bf16(const bhalf* __restrict__ in, bhalf* __restrict__ out,
                               int R, int C) {
  __shared__ bhalf t[32][33];
  int r0 = blockIdx.x*32, c0 = blockIdx.y*32;
  int tx = threadIdx.x, ty = threadIdx.y;
  #pragma unroll
  for (int r=0;r<4;r++)
    t[ty + r*8][tx] = in[(long)(r0 + ty + r*8)*C + c0 + tx];
  __syncthreads();
  #pragma unroll
  for (int r=0;r<4;r++)
    out[(long)(c0 + ty + r*8)*R + r0 + tx] = t[tx][ty + r*8];
}

// bq[row] = sum_m wqk[row][m] * hb[m]   (row in [0,1024))
__global__ void qk_bias(const bhalf* __restrict__ wqk, const float* __restrict__ hb,
                        float* __restrict__ bq){
  int row = blockIdx.x*4 + (threadIdx.x>>6);
  int lane = threadIdx.x & 63;
  const bhalf* p = wqk + (long)row*512;
  float s = 0.f;
  #pragma unroll
  for (int j=0;j<8;j++) s += (float)p[lane*8+j] * hb[lane*8+j];
  for (int off=32; off; off>>=1) s += __shfl_xor(s, off);
  if (lane==0) bq[row] = s;
}

__global__ void gn_part(const float* __restrict__ x, float* __restrict__ ps, float* __restrict__ pss) {
  int b = blockIdx.y;
  const float* xb = x + (long)b*(512*2048);
  float s=0.f, ss=0.f;
  #pragma unroll
  for (int it=0; it<8; it++){
    int idx = ((it*128 + blockIdx.x)*256 + threadIdx.x)*4;
    float4 f = *(const float4*)(xb + idx);
    s  += f.x+f.y+f.z+f.w;
    ss += f.x*f.x+f.y*f.y+f.z*f.z+f.w*f.w;
  }
  for (int off=32; off; off>>=1){ s += __shfl_xor(s,off); ss += __shfl_xor(ss,off); }
  __shared__ float ls[4], lss[4];
  int wid = threadIdx.x>>6, lane = threadIdx.x&63;
  if (lane==0){ ls[wid]=s; lss[wid]=ss; }
  __syncthreads();
  if (threadIdx.x==0){
    s = ls[0]+ls[1]+ls[2]+ls[3]; ss = lss[0]+lss[1]+lss[2]+lss[3];
    ps[b*128 + blockIdx.x] = s; pss[b*128 + blockIdx.x] = ss;
  }
}

__global__ void gn_final(const float* __restrict__ ps, const float* __restrict__ pss,
                         float* __restrict__ stats) {
  int b = blockIdx.x;
  float s = ps[b*128 + threadIdx.x], ss = pss[b*128 + threadIdx.x];
  for (int off=32; off; off>>=1){ s += __shfl_xor(s,off); ss += __shfl_xor(ss,off); }
  __shared__ float l0[2], l1[2];
  int wid = threadIdx.x>>6, lane = threadIdx.x&63;
  if (lane==0){ l0[wid]=s; l1[wid]=ss; }
  __syncthreads();
  if (threadIdx.x==0){
    s = l0[0]+l0[1]; ss = l1[0]+l1[1];
    float mean = s*(1.f/1048576.f);
    float var  = ss*(1.f/1048576.f) - mean*mean;
    stats[b*2] = mean; stats[b*2+1] = rsqrtf(var + 1e-8f);
  }
}

__global__ void norm_dw_T(const float* __restrict__ x, const float* __restrict__ stats,
                          const float* __restrict__ dw_w,
                          bhalf* __restrict__ zT, bhalf* __restrict__ dwT) {
  int b = blockIdx.z, n0 = blockIdx.x*32, c0 = blockIdx.y*32;
  float mean = stats[b*2], rstd = stats[b*2+1];
  __shared__ float zs[32][35];
  int tx = threadIdx.x, ty = threadIdx.y;
  #pragma unroll
  for (int r=0;r<4;r++){
    int c = c0 + ty + r*8;
    for (int cc=tx; cc<34; cc+=32){
      int n = n0 - 1 + cc;
      float v = 0.f;
      if (n>=0 && n<2048) v = (x[((long)b*512 + c)*2048 + n] - mean)*rstd;
      zs[ty + r*8][cc] = v;
    }
  }
  __syncthreads();
  float w0 = dw_w[(c0+tx)*3+0], w1 = dw_w[(c0+tx)*3+1], w2 = dw_w[(c0+tx)*3+2];
  #pragma unroll
  for (int r=0;r<4;r++){
    int ln = ty + r*8;
    float z = zs[tx][ln+1];
    float d = w0*zs[tx][ln] + w1*zs[tx][ln+1] + w2*zs[tx][ln+2];
    long o = ((long)b*2048 + n0 + ln)*512 + c0 + tx;
    zT[o] = (bhalf)z; dwT[o] = (bhalf)d;
  }
}

// ---------------------------------------------------------------------------
extern "C" void kernel_launch(void* const* d_in, const int* in_sizes, int n_in,
                              void* d_out, int out_size, void* d_ws, size_t ws_size,
                              hipStream_t stream) {
  (void)in_sizes; (void)n_in; (void)out_size; (void)ws_size;
  const float* x    = (const float*)d_in[0];
  const float* dw_w = (const float*)d_in[1];
  const float* pw_w = (const float*)d_in[2];
  const float* u_w  = (const float*)d_in[3];
  const float* u_b  = (const float*)d_in[4];
  const float* v_w  = (const float*)d_in[5];
  const float* v_b  = (const float*)d_in[6];
  const float* h_w  = (const float*)d_in[7];
  const float* h_b  = (const float*)d_in[8];
  const float* q_w  = (const float*)d_in[9];
  const float* k_w  = (const float*)d_in[10];
  const float* o_w  = (const float*)d_in[11];
  const float* o_b  = (const float*)d_in[12];
  float* out = (float*)d_out;

  char* ws = (char*)d_ws;
  size_t off = 0;
  auto alloc = [&](size_t bytes) -> void* {
    void* p = ws + off; off = (off + bytes + 255) & ~(size_t)255; return p;
  };

  float* ps    = (float*)alloc(4*128*4);
  float* pss   = (float*)alloc(4*128*4);
  float* stats = (float*)alloc(4*2*4);
  float* rden  = (float*)alloc(4*2048*4);
  float* bq    = (float*)alloc(1024*4);
  bhalf* wb_pw = (bhalf*)alloc(512*512*2);
  bhalf* wb_uv = (bhalf*)alloc((size_t)2048*512*2);
  bhalf* wb_h  = (bhalf*)alloc(512*512*2);
  bhalf* hwT   = (bhalf*)alloc(512*512*2);
  bhalf* wb_qk = (bhalf*)alloc((size_t)1024*512*2);
  bhalf* wqk2  = (bhalf*)alloc((size_t)1024*512*2);
  bhalf* wb_o  = (bhalf*)alloc((size_t)512*1024*2);
  const size_t ACT = (size_t)4*2048*512;
  bhalf* zT   = (bhalf*)alloc(ACT*2);       // reused as qb
  bhalf* dwT  = (bhalf*)alloc(ACT*2);       // reused as kb
  bhalf* z2T  = (bhalf*)alloc(ACT*2);
  bhalf* ub   = (bhalf*)alloc(ACT*2*2);     // [B,N,1024]
  bhalf* v_fm = (bhalf*)alloc(ACT*2*2);     // [B,1024,2048] (written by UV)
  bhalf* wsc  = (bhalf*)alloc((size_t)4*2048*2048*2);
  bhalf* uav  = (bhalf*)alloc(ACT*2*2);
  bhalf* qb = zT;  bhalf* kb = dwT;

  // 0. zero attention-denominator accumulators
  hipMemsetAsync(rden, 0, 4*2048*4, stream);

  // 1. weights -> bf16 (u|v and q|k concatenated)
  CvtArgs ca;
  ca.src[0]=pw_w; ca.dst[0]=wb_pw;           ca.n[0]=512*512;
  ca.src[1]=u_w;  ca.dst[1]=wb_uv;           ca.n[1]=1024*512;
  ca.src[2]=v_w;  ca.dst[2]=wb_uv+1024*512;  ca.n[2]=1024*512;
  ca.src[3]=h_w;  ca.dst[3]=wb_h;            ca.n[3]=512*512;
  ca.src[4]=q_w;  ca.dst[4]=wb_qk;           ca.n[4]=512*512;
  ca.src[5]=k_w;  ca.dst[5]=wb_qk+512*512;   ca.n[5]=512*512;
  ca.src[6]=o_w;  ca.dst[6]=wb_o;            ca.n[6]=512*1024;
  cvt_multi<<<dim3(512,7), 256, 0, stream>>>(ca);

  // 2. fold h into q/k: wqk2 = [q_w;k_w] @ h_w, bq = [q_w;k_w] @ h_b
  transpose_bf16<<<dim3(16,16), dim3(32,8), 0, stream>>>(wb_h, hwT, 512, 512);
  g4k<EPI_ST><<<dim3(4,8,1), 256, 0, stream>>>(wb_qk, hwT, wqk2, nullptr,
      nullptr, nullptr, nullptr, nullptr, 1024, 512, 512, 0, 0);
  qk_bias<<<dim3(256), 256, 0, stream>>>(wb_qk, h_b, bq);

  // 3-4. GroupNorm stats
  gn_part<<<dim3(128,4), 256, 0, stream>>>(x, ps, pss);
  gn_final<<<dim3(4), 128, 0, stream>>>(ps, pss, stats);

  // 5. normalize + dw conv + transpose -> zT, dwT
  norm_dw_T<<<dim3(64,16,4), dim3(32,8), 0, stream>>>(x, stats, dw_w, zT, dwT);

  const float iscl = 0.044194173824159216f;   // 1/sqrt(512)
  // 6. z2 = z + dw @ pw^T
  g4k<EPI_Z2><<<dim3(4,64,1), 256, 0, stream>>>(dwT, wb_pw, z2T, nullptr,
      nullptr, zT, nullptr, nullptr, 8192, 512, 512, 0, 0);
  // 7. [u|v] = z2 @ [u_w|v_w]^T + b      (gA; u->ub, v->v_fm direct)
  gA<EPI_UV><<<dim3(8,32,1), 512, 0, stream>>>(z2T, wb_uv, ub, v_fm,
      u_b, v_b, 2048, 512, 0, 0, 0, 0, 0.f);
  // 8. [q|k] = z2 @ wqk2^T + bq          (h folded away; 512 blocks)
  g4k<EPI_QK><<<dim3(8,64,1), 256, 0, stream>>>(z2T, wqk2, qb, kb,
      bq, nullptr, nullptr, nullptr, 8192, 1024, 512, 0, 0);
  // 9. w = relu(q@k^T * scale)^2 + fused row-sum atomics into rden  (gA)
  gA<EPI_ATTN><<<dim3(8,8,4), 512, 0, stream>>>(qb, kb, wsc, rden,
      nullptr, nullptr, 2048, 512,
      (long)2048*512, (long)2048*512, (long)2048*2048, 2048, iscl);
  // 10. uav = u * (w @ v_fm^T) / (den+eps)  (512 blocks, batch in M)
  g4k<EPI_PV><<<dim3(8,64,1), 256, 0, stream>>>(wsc, v_fm, uav, nullptr,
      nullptr, ub, rden, nullptr, 8192, 1024, 2048, (long)1024*2048, 11);
  // 11. out = x + (uav @ o_w^T + o_b)^T  (fused residual add)
  g4k<EPI_Y><<<dim3(4,64,1), 256, 0, stream>>>(uav, wb_o, out, nullptr,
      o_b, nullptr, nullptr, x, 8192, 512, 1024, 0, 0);
}

// Round 16
// 177.998 us; speedup vs baseline: 1.0775x; 1.0432x over previous
//
#include <hip/hip_runtime.h>
#include <hip/hip_bf16.h>
#include <cstdint>

typedef __bf16 bhalf;
typedef __bf16 bhalf8 __attribute__((ext_vector_type(8)));
typedef float f32x4 __attribute__((ext_vector_type(4)));

enum { EPI_Z2=0, EPI_UV=1, EPI_BIAS=2, EPI_QK=3, EPI_ATTN=4, EPI_PV=5, EPI_Y=6, EPI_ST=7 };

// async global->LDS, 16B per lane, LDS dest = wave-uniform base + lane*16
__device__ __forceinline__ void gl_lds16(const void* g, void* l) {
  __builtin_amdgcn_global_load_lds(
      (const __attribute__((address_space(1))) unsigned int*)g,
      (__attribute__((address_space(3))) unsigned int*)l,
      16, 0, 0);
}
__device__ __forceinline__ void barrier_raw() { asm volatile("s_barrier" ::: "memory"); }
#define VMW(n)  asm volatile("s_waitcnt vmcnt(" #n ")" ::: "memory")
#define LGKM0() asm volatile("s_waitcnt lgkmcnt(0)" ::: "memory")

// float -> fp8 e4m3 (OCP on gfx950) via HW cvt
__device__ __forceinline__ unsigned char to_fp8(float v){
  return (unsigned char)(__builtin_amdgcn_cvt_pk_fp8_f32(v, v, 0, false) & 0xff);
}

// Staging bank swizzle (verified R4-R15: SQ_LDS_BANK_CONFLICT == 0): 16B chunk
// c of a 64B row r holds global chunk c ^ ((r>>1)&3). Write: pre-swizzled
// GLOBAL source, linear LDS dest (rule #21); read side applies same XOR.
// Epilogue token-major bf16 C-tile swizzle: 32B chunk ^ ((row>>2)&3).
// fp8 C-tile (256B rows): 16B chunk ^ (row&15).

// ---------------------------------------------------------------------------
// gA: 256x256, BK=64, 8 waves (2M x 4N, wave 128x64), 2 dbufs (128 KB),
// 4 phases/K-tile of 16 MFMA, in-place region staging, VMW(4)/K-tile.
// score: fp8 wsc out + fused row-sums. UV: u->ub bf16, v->v_fm fp8 transposed.
// ---------------------------------------------------------------------------
template<int EPI>
__global__ void __launch_bounds__(512, 2)
gA(const bhalf* __restrict__ A, const bhalf* __restrict__ Bw,
   void* __restrict__ Out, void* __restrict__ Out2,
   const float* __restrict__ bias, const float* __restrict__ bias2,
   int N, int K, long sA, long sB, long sO, long sAuxf, float scale)
{
  constexpr int KSL = 256*64;     // 16 KB per k-slice plane
  constexpr int REG = 2*KSL;      // 32 KB (one K-tile of A or B)
  constexpr int DBUF = 2*REG;     // 64 KB
  __shared__ __align__(16) char lds[2*DBUF];   // 128 KB

  const int gx = gridDim.x, gy = gridDim.y;
  const int nwg = gx*gy;
  const int flat = blockIdx.y*gx + blockIdx.x;
  const int q8 = nwg>>3, r8 = nwg&7, xcd = flat&7, o8 = flat>>3;
  const int wsw = (xcd<r8 ? xcd*(q8+1) : r8*(q8+1)+(xcd-r8)*q8) + o8;
  const int bx = wsw % gx, by = wsw / gx;
  const int m0 = by*256, n0 = bx*256;
  const int bz = blockIdx.z;

  const bhalf* Ab = A + (long)bz*sA;
  const bhalf* Bb = Bw + (long)bz*sB;

  const int tid = threadIdx.x, wid = tid>>6, lane = tid&63;
  const int lm = lane&15, kq = lane>>4;
  const int wm = wid>>2, wn = wid&3;
  const int srow = lane>>2;
  const int csw = ((lane&3) ^ ((lane>>3)&3)) * 8;
  const int kqs = kq ^ ((lm>>1)&3);

  f32x4 acc[8][4];
  #pragma unroll
  for (int i=0;i<8;i++)
    #pragma unroll
    for (int j=0;j<4;j++) acc[i][j] = f32x4{0.f,0.f,0.f,0.f};

  auto stageA = [&](int kt){                     // 4 loads/wave
    char* base = lds + (kt&1)*DBUF;
    const int k0 = kt*64;
    #pragma unroll
    for (int h=0; h<2; h++)
      #pragma unroll
      for (int ksl=0; ksl<2; ksl++){
        bhalf* d = (bhalf*)(base + ksl*KSL + (h*128 + wid*16)*64);
        gl_lds16(Ab + (long)(m0 + h*128 + wid*16 + srow)*K + k0 + ksl*32 + csw, d);
      }
  };
  auto stageB = [&](int kt){                     // 4 loads/wave
    char* base = lds + (kt&1)*DBUF + REG;
    const int k0 = kt*64;
    #pragma unroll
    for (int h=0; h<2; h++)
      #pragma unroll
      for (int ksl=0; ksl<2; ksl++){
        bhalf* d = (bhalf*)(base + ksl*KSL + (h*128 + wid*16)*64);
        gl_lds16(Bb + (long)(n0 + h*128 + wid*16 + srow)*K + k0 + ksl*32 + csw, d);
      }
  };

  bhalf8 af[4][2], bf[4][2];
  auto readA = [&](int kt, int ih){
    char* base = lds + (kt&1)*DBUF;
    #pragma unroll
    for (int i2=0;i2<4;i2++)
      #pragma unroll
      for (int ksl=0;ksl<2;ksl++)
        af[i2][ksl] = *(const bhalf8*)(base + ksl*KSL + (wm*128 + ih*64 + i2*16 + lm)*64 + kqs*16);
  };
  auto readB = [&](int kt, int jh){
    char* base = lds + (kt&1)*DBUF + REG;
    #pragma unroll
    for (int j2=0;j2<2;j2++)
      #pragma unroll
      for (int ksl=0;ksl<2;ksl++)
        bf[jh*2+j2][ksl] = *(const bhalf8*)(base + ksl*KSL + (wn*64 + jh*32 + j2*16 + lm)*64 + kqs*16);
  };
  auto mfma16 = [&](int ih, int jh){
    __builtin_amdgcn_s_setprio(1);
    #pragma unroll
    for (int i2=0;i2<4;i2++)
      #pragma unroll
      for (int j2=0;j2<2;j2++)
        #pragma unroll
        for (int ksl=0;ksl<2;ksl++)
          acc[ih*4+i2][jh*2+j2] = __builtin_amdgcn_mfma_f32_16x16x32_bf16(
              af[i2][ksl], bf[jh*2+j2][ksl], acc[ih*4+i2][jh*2+j2], 0,0,0);
    __builtin_amdgcn_s_setprio(0);
  };

  const int NT = K>>6;
  stageA(0); stageB(0); stageA(1);               // 12 loads
  for (int kt=0; kt<NT; ++kt){
    if (kt==NT-1) { VMW(0); } else { VMW(4); }
    barrier_raw();
    readA(kt,0); readB(kt,0);
    if (kt+1<NT) stageB(kt+1);
    mfma16(0,0);
    barrier_raw();
    readB(kt,1);
    mfma16(0,1);
    barrier_raw();
    readA(kt,1);
    mfma16(1,0);
    barrier_raw();
    if (kt+2<NT) stageA(kt+2);
    mfma16(1,1);
  }
  barrier_raw();

  // ---- epilogues ----
  if constexpr (EPI==EPI_ATTN){
    float rs[8][4];
    #pragma unroll
    for (int i=0;i<8;i++)
      #pragma unroll
      for (int r=0;r<4;r++) rs[i][r]=0.f;
    #pragma unroll
    for (int i=0;i<8;i++){
      #pragma unroll
      for (int j=0;j<4;j++){
        const int lcol = wn*64 + j*16 + lm;
        #pragma unroll
        for (int r=0;r<4;r++){
          const int lrow = wm*128 + i*16 + kq*4 + r;
          float v = acc[i][j][r];
          v *= scale; v = fmaxf(v,0.f); v = v*v;
          rs[i][r] += v;
          // fp8 C-tile: 256 rows x 256 B, 16B chunk ^ (row&15)
          const int lb = lrow*256 + ((((lcol>>4) ^ (lrow&15)))<<4) + (lcol&15);
          *(unsigned char*)(lds + lb) = to_fp8(v);
        }
      }
    }
    float* rd = (float*)Out2;
    #pragma unroll
    for (int i=0;i<8;i++){
      const int rbase = m0 + wm*128 + i*16 + kq*4;
      #pragma unroll
      for (int r=0;r<4;r++){
        float s = rs[i][r];
        s += __shfl_xor(s,1); s += __shfl_xor(s,2);
        s += __shfl_xor(s,4); s += __shfl_xor(s,8);
        if (lm==0) atomicAdd(rd + (long)bz*sAuxf + rbase + r, s);
      }
    }
    LGKM0();
    barrier_raw();
    char* obase = (char*)Out + (long)bz*sO + (long)m0*N + n0;   // fp8 bytes
    #pragma unroll
    for (int it=0; it<8; ++it){
      const int g = (it*512 + tid)*16;
      const int row = g >> 8, off = g & 255;
      const int lb = row*256 + ((((off>>4) ^ (row&15)))<<4);
      uint4 val = *(const uint4*)(lds + lb);
      *(uint4*)(obase + (long)row*N + off) = val;
    }
  }
  if constexpr (EPI==EPI_UV){
    const bool uh = n0 < 1024;
    const float* bv = uh ? bias : bias2;
    const int bc0 = uh ? n0 : n0-1024;
    #pragma unroll
    for (int i=0;i<8;i++){
      #pragma unroll
      for (int j=0;j<4;j++){
        const int lcol = wn*64 + j*16 + lm;
        #pragma unroll
        for (int r=0;r<4;r++){
          const int lrow = wm*128 + i*16 + kq*4 + r;
          float v = acc[i][j][r] + bv[bc0 + lcol];
          if (uh){
            v = 1.f/(1.f + __expf(-v));
            const int cb = lcol*2;
            const int lb = lrow*512 + (((cb>>5) ^ ((lrow>>2)&3))<<5) + (cb&31);
            *(bhalf*)(lds + lb) = (bhalf)v;
          } else {
            // fp8 transposed: row = v-channel (256B = 256 tokens), chunk^(ch&15)
            const int lb = lcol*256 + ((((lrow>>4) ^ (lcol&15)))<<4) + (lrow&15);
            *(unsigned char*)(lds + lb) = to_fp8(v);
          }
        }
      }
    }
    LGKM0();
    barrier_raw();
    if (uh){
      char* obase = (char*)Out + 2*((long)m0*1024 + n0);
      #pragma unroll
      for (int it=0; it<16; ++it){
        const int g = (it*512 + tid)*16;
        const int row = g >> 9, off = g & 511;
        const int lb = row*512 + (((off>>5) ^ ((row>>2)&3))<<5) + (off&31);
        uint4 val = *(const uint4*)(lds + lb);
        *(uint4*)(obase + (long)row*2048 + off) = val;
      }
    } else {
      // v_fm fp8 [B][1024][2048]: row = v-channel
      char* vb = (char*)Out2 + ((long)(m0>>11)*1024*2048 + (long)(n0-1024)*2048 + (m0 & 2047));
      #pragma unroll
      for (int it=0; it<8; ++it){
        const int g = (it*512 + tid)*16;
        const int row = g >> 8, off = g & 255;
        const int lb = row*256 + ((((off>>4) ^ (row&15)))<<4);
        uint4 val = *(const uint4*)(lds + lb);
        *(uint4*)(vb + (long)row*2048 + off) = val;
      }
    }
  }
  (void)scale; (void)bias; (void)bias2; (void)N;
}

// ---------------------------------------------------------------------------
// g4k8: fp8 x fp8 PV GEMM. 128x128 tile, 4 waves (2x2, wave 64x64), BK=64
// (64B fp8 rows), ring-of-4 16KB bufs (64 KB -> 2 blocks/CU), 3-ahead
// staging, VMW(8)/K-tile. uav = u * (wsc @ v_fm^T) / (den+eps).
// ---------------------------------------------------------------------------
__global__ void __launch_bounds__(256, 2)
g4k8(const unsigned char* __restrict__ A, const unsigned char* __restrict__ Bw,
     bhalf* __restrict__ Out,
     const bhalf* __restrict__ ub, const float* __restrict__ rden,
     int K, long sB, int rowshift)
{
  constexpr int DBUF = 256*64;    // 16 KB: A rows 0-127, B rows 128-255
  __shared__ __align__(16) char lds[4*DBUF];   // 64 KB

  const int gx = gridDim.x, gy = gridDim.y;
  const int nwg = gx*gy;
  const int flat = blockIdx.y*gx + blockIdx.x;
  const int q8 = nwg>>3, r8 = nwg&7, xcd = flat&7, o8 = flat>>3;
  const int w = (xcd<r8 ? xcd*(q8+1) : r8*(q8+1)+(xcd-r8)*q8) + o8;
  const int bx = w % gx, by = w / gx;
  const int m0 = by*128, n0 = bx*128;

  const unsigned char* Bb = Bw + (long)(m0>>rowshift)*sB;

  const int tid = threadIdx.x;
  const int wid = tid>>6, lane = tid&63;
  const int lm = lane&15, kq = lane>>4;
  const int wm = wid>>1, wn = wid&1;
  const int srow = lane>>2;
  const int csw8 = ((lane&3) ^ ((lane>>3)&3))*16;   // fp8: chunk = 16 elems
  // frag read byte offsets within 64B row, per ksl (chunk-XOR swizzled)
  int coff[2];
  #pragma unroll
  for (int ksl=0; ksl<2; ksl++)
    coff[ksl] = ((((ksl*2 + (kq>>1)) ^ ((lm>>1)&3)))<<4) + ((kq&1)<<3);

  f32x4 acc[4][4];
  #pragma unroll
  for (int i=0;i<4;i++)
    #pragma unroll
    for (int j=0;j<4;j++) acc[i][j] = f32x4{0.f,0.f,0.f,0.f};

  auto stage = [&](int kt){                      // 4 loads/wave
    char* base = lds + (kt&3)*DBUF;
    const int k0 = kt*64;
    #pragma unroll
    for (int c=0;c<4;c++){
      const int r0 = c*64 + wid*16;
      char* d = base + r0*64;
      const unsigned char* g = (r0 < 128)
        ? A  + (long)(m0 + r0 + srow)*K + k0 + csw8
        : Bb + (long)(n0 + r0 - 128 + srow)*K + k0 + csw8;
      gl_lds16(g, d);
    }
  };

  long af[4][2], bf[4][2];
  auto readA = [&](int kt){
    char* base = lds + (kt&3)*DBUF;
    #pragma unroll
    for (int i2=0;i2<4;i2++)
      #pragma unroll
      for (int ksl=0;ksl<2;ksl++)
        af[i2][ksl] = *(const long*)(base + (wm*64 + i2*16 + lm)*64 + coff[ksl]);
  };
  auto readB = [&](int kt, int jh){
    char* base = lds + (kt&3)*DBUF;
    #pragma unroll
    for (int j2=0;j2<2;j2++)
      #pragma unroll
      for (int ksl=0;ksl<2;ksl++)
        bf[jh*2+j2][ksl] = *(const long*)(base + (128 + wn*64 + jh*32 + j2*16 + lm)*64 + coff[ksl]);
  };
  auto mfma16 = [&](int jh){
    __builtin_amdgcn_s_setprio(1);
    #pragma unroll
    for (int i2=0;i2<4;i2++)
      #pragma unroll
      for (int j2=0;j2<2;j2++)
        #pragma unroll
        for (int ksl=0;ksl<2;ksl++)
          acc[i2][jh*2+j2] = __builtin_amdgcn_mfma_f32_16x16x32_fp8_fp8(
              af[i2][ksl], bf[jh*2+j2][ksl], acc[i2][jh*2+j2], 0,0,0);
    __builtin_amdgcn_s_setprio(0);
  };

  const int NT = K>>6;
  stage(0); stage(1); stage(2);                  // 12 loads
  for (int kt=0; kt<NT; ++kt){
    if (kt==NT-1)      { VMW(0); }
    else if (kt==NT-2) { VMW(4); }
    else               { VMW(8); }
    barrier_raw();
    readA(kt); readB(kt,0);
    if (kt+3<NT) stage(kt+3);
    mfma16(0);
    readB(kt,1);
    mfma16(1);
  }
  barrier_raw();

  // ---- epilogue: u-gate + normalize -> bf16 C-tile -> coalesced ----
  char* obase = (char*)Out + 2*((long)m0*1024 + n0);
  #pragma unroll
  for (int i=0;i<4;i++){
    #pragma unroll
    for (int j=0;j<4;j++){
      const int lcol = wn*64 + j*16 + lm;
      #pragma unroll
      for (int r=0;r<4;r++){
        const int lrow = wm*64 + i*16 + kq*4 + r;
        const int rowg = m0 + lrow;
        float v = acc[i][j][r];
        float den = rden[rowg];
        v *= __builtin_amdgcn_rcpf(den + 1e-8f);
        v *= (float)ub[(long)rowg*1024 + n0 + lcol];
        const int cb = lcol*2;
        const int lb = lrow*256 + (((cb>>5) ^ ((lrow>>2)&3))<<5) + (cb&31);
        *(bhalf*)(lds + lb) = (bhalf)v;
      }
    }
  }
  LGKM0();
  barrier_raw();
  #pragma unroll
  for (int it=0; it<8; ++it){
    const int g = (it*256 + tid)*16;
    const int row = g >> 8, off = g & 255;
    const int lb = row*256 + (((off>>5) ^ ((row>>2)&3))<<5) + (off&31);
    uint4 val = *(const uint4*)(lds + lb);
    *(uint4*)(obase + (long)row*2048 + off) = val;
  }
}

// ---------------------------------------------------------------------------
// g4k: bf16 128x128 tile, 4 waves (2x2, wave 64x64), BK=64, 2 dbufs (64 KB),
// 2-ahead in-place staging, VMW(8)/K-tile. For z2 / QK / y / wqk2.
// ---------------------------------------------------------------------------
template<int EPI>
__global__ void __launch_bounds__(256, 2)
g4k(const bhalf* __restrict__ A, const bhalf* __restrict__ Bw,
    void* __restrict__ Out, void* __restrict__ Out2,
    const float* __restrict__ bias,
    const bhalf* __restrict__ auxb,
    const float* __restrict__ xadd,
    int M, int N, int K)
{
  constexpr int KSL = 256*64;     // 16 KB plane: A rows 0-127, B rows 128-255
  constexpr int DBUF = 2*KSL;     // 32 KB
  __shared__ __align__(16) char lds[2*DBUF];   // 64 KB

  const int gx = gridDim.x, gy = gridDim.y;
  const int nwg = gx*gy;
  const int flat = blockIdx.y*gx + blockIdx.x;
  const int q8 = nwg>>3, r8 = nwg&7, xcd = flat&7, o8 = flat>>3;
  const int w = (xcd<r8 ? xcd*(q8+1) : r8*(q8+1)+(xcd-r8)*q8) + o8;
  const int bx = w % gx, by = w / gx;
  const int m0 = by*128, n0 = bx*128;

  const int tid = threadIdx.x;
  const int wid = tid>>6, lane = tid&63;
  const int lm = lane&15, kq = lane>>4;
  const int wm = wid>>1, wn = wid&1;
  const int srow = lane>>2;
  const int csw = ((lane&3) ^ ((lane>>3)&3))*8;
  const int kqs = kq ^ ((lm>>1)&3);

  f32x4 acc[4][4];
  #pragma unroll
  for (int i=0;i<4;i++)
    #pragma unroll
    for (int j=0;j<4;j++) acc[i][j] = f32x4{0.f,0.f,0.f,0.f};

  auto stage = [&](int kt){                      // 8 loads/wave
    char* base = lds + (kt&1)*DBUF;
    const int k0 = kt*64;
    #pragma unroll
    for (int c=0;c<4;c++){
      const int r0 = c*64 + wid*16;
      #pragma unroll
      for (int ksl=0; ksl<2; ksl++){
        bhalf* d = (bhalf*)(base + ksl*KSL + r0*64);
        const bhalf* g = (r0 < 128)
          ? A  + (long)(m0 + r0 + srow)*K + k0 + ksl*32 + csw
          : Bw + (long)(n0 + r0 - 128 + srow)*K + k0 + ksl*32 + csw;
        gl_lds16(g, d);
      }
    }
  };

  bhalf8 af[4][2], bf[4][2];
  auto readA = [&](int kt){
    char* base = lds + (kt&1)*DBUF;
    #pragma unroll
    for (int i2=0;i2<4;i2++)
      #pragma unroll
      for (int ksl=0;ksl<2;ksl++)
        af[i2][ksl] = *(const bhalf8*)(base + ksl*KSL + (wm*64 + i2*16 + lm)*64 + kqs*16);
  };
  auto readB = [&](int kt, int jh){
    char* base = lds + (kt&1)*DBUF;
    #pragma unroll
    for (int j2=0;j2<2;j2++)
      #pragma unroll
      for (int ksl=0;ksl<2;ksl++)
        bf[jh*2+j2][ksl] = *(const bhalf8*)(base + ksl*KSL + (128 + wn*64 + jh*32 + j2*16 + lm)*64 + kqs*16);
  };
  auto mfma16 = [&](int jh){
    __builtin_amdgcn_s_setprio(1);
    #pragma unroll
    for (int i2=0;i2<4;i2++)
      #pragma unroll
      for (int j2=0;j2<2;j2++)
        #pragma unroll
        for (int ksl=0;ksl<2;ksl++)
          acc[i2][jh*2+j2] = __builtin_amdgcn_mfma_f32_16x16x32_bf16(
              af[i2][ksl], bf[jh*2+j2][ksl], acc[i2][jh*2+j2], 0,0,0);
    __builtin_amdgcn_s_setprio(0);
  };

  const int NT = K>>6;
  stage(0); stage(1);
  for (int kt=0; kt<NT; ++kt){
    if (kt==NT-1) { VMW(0); } else { VMW(8); }
    barrier_raw();
    readA(kt); readB(kt,0);
    mfma16(0);
    barrier_raw();
    readB(kt,1);
    if (kt+2<NT) stage(kt+2);
    mfma16(1);
  }
  barrier_raw();

  // ---- epilogues ----
  if constexpr (EPI==EPI_Y){
    #pragma unroll
    for (int i=0;i<4;i++){
      #pragma unroll
      for (int j=0;j<4;j++){
        const int lcol = wn*64 + j*16 + lm;
        #pragma unroll
        for (int r=0;r<4;r++){
          const int lrow = wm*64 + i*16 + kq*4 + r;
          float v = acc[i][j][r] + bias[n0 + lcol];
          const int lb = lcol*512 + 4*(lrow ^ ((lcol&15)<<2));
          *(float*)(lds + lb) = v;
        }
      }
    }
    LGKM0();
    barrier_raw();
    const int b = m0 >> 11, nb = m0 & 2047;
    float* ob = (float*)Out + ((long)b*512 + n0)*2048 + nb;
    const float* xb = xadd + ((long)b*512 + n0)*2048 + nb;
    #pragma unroll
    for (int it=0; it<16; ++it){
      const int g = (it*256 + tid)*16;
      const int row = g >> 9, off = g & 511;
      const int t0 = off >> 2;
      const int s = (row&15)<<2;
      f32x4 vv = *(const f32x4*)(lds + row*512 + 4*(t0^s));
      f32x4 xx = *(const f32x4*)(xb + (long)row*2048 + t0);
      *(f32x4*)(ob + (long)row*2048 + t0) = vv + xx;
    }
  } else {
    char* obase; int ldb;
    if constexpr (EPI==EPI_QK){
      bool qh = n0 < 512;
      obase = (char*)(qh?Out:Out2) + 2*((long)m0*512 + (n0 - (qh?0:512)));
      ldb = 1024;
    } else {
      obase = (char*)Out + 2*((long)m0*N + n0);
      ldb = N*2;
    }
    #pragma unroll
    for (int i=0;i<4;i++){
      #pragma unroll
      for (int j=0;j<4;j++){
        const int lcol = wn*64 + j*16 + lm;
        #pragma unroll
        for (int r=0;r<4;r++){
          const int lrow = wm*64 + i*16 + kq*4 + r;
          float v = acc[i][j][r];
          if constexpr (EPI==EPI_Z2)
            v += (float)auxb[(long)(m0+lrow)*N + n0 + lcol];
          if constexpr (EPI==EPI_BIAS)
            v += bias[n0 + lcol];
          if constexpr (EPI==EPI_QK)
            v += bias[n0 + lcol];           // bq = [q_w;k_w] @ h_b
          const int cb = lcol*2;
          const int lb = lrow*256 + (((cb>>5) ^ ((lrow>>2)&3))<<5) + (cb&31);
          *(bhalf*)(lds + lb) = (bhalf)v;
        }
      }
    }
    LGKM0();
    barrier_raw();
    #pragma unroll
    for (int it=0; it<8; ++it){
      const int g = (it*256 + tid)*16;
      const int row = g >> 8, off = g & 255;
      const int lb = row*256 + (((off>>5) ^ ((row>>2)&3))<<5) + (off&31);
      uint4 val = *(const uint4*)(lds + lb);
      *(uint4*)(obase + (long)row*ldb + off) = val;
    }
  }
  (void)M; (void)xadd; (void)bias; (void)auxb;
}

// ---------------------------------------------------------------------------
struct CvtArgs { const float* src[7]; bhalf* dst[7]; int n[7]; };
__global__ void cvt_multi(CvtArgs a) {
  int seg = blockIdx.y;
  int i = (blockIdx.x*256 + threadIdx.x)*4;
  if (i >= a.n[seg]) return;
  float4 f = *(const float4*)(a.src[seg] + i);
  bhalf* d = a.dst[seg] + i;
  d[0]=(bhalf)f.x; d[1]=(bhalf)f.y; d[2]=(bhalf)f.z; d[3]=(bhalf)f.w;
}

// bf16 transpose: in [R,C] -> out [C,R]
__global__ void transpose_bf16(const bhalf* __restrict__ in, bhalf* __restrict__ out,
                               int R, int C) {
  __shared__ bhalf t[32][33];
  int r0 = blockIdx.x*32, c0 = blockIdx.y*32;
  int tx = threadIdx.x, ty = threadIdx.y;
  #pragma unroll
  for (int r=0;r<4;r++)
    t[ty + r*8][tx] = in[(long)(r0 + ty + r*8)*C + c0 + tx];
  __syncthreads();
  #pragma unroll
  for (int r=0;r<4;r++)
    out[(long)(c0 + ty + r*8)*R + r0 + tx] = t[tx][ty + r*8];
}

// bq[row] = sum_m wqk[row][m] * hb[m]
__global__ void qk_bias(const bhalf* __restrict__ wqk, const float* __restrict__ hb,
                        float* __restrict__ bq){
  int row = blockIdx.x*4 + (threadIdx.x>>6);
  int lane = threadIdx.x & 63;
  const bhalf* p = wqk + (long)row*512;
  float s = 0.f;
  #pragma unroll
  for (int j=0;j<8;j++) s += (float)p[lane*8+j] * hb[lane*8+j];
  for (int off=32; off; off>>=1) s += __shfl_xor(s, off);
  if (lane==0) bq[row] = s;
}

__global__ void gn_part(const float* __restrict__ x, float* __restrict__ ps, float* __restrict__ pss) {
  int b = blockIdx.y;
  const float* xb = x + (long)b*(512*2048);
  float s=0.f, ss=0.f;
  #pragma unroll
  for (int it=0; it<8; it++){
    int idx = ((it*128 + blockIdx.x)*256 + threadIdx.x)*4;
    float4 f = *(const float4*)(xb + idx);
    s  += f.x+f.y+f.z+f.w;
    ss += f.x*f.x+f.y*f.y+f.z*f.z+f.w*f.w;
  }
  for (int off=32; off; off>>=1){ s += __shfl_xor(s,off); ss += __shfl_xor(ss,off); }
  __shared__ float ls[4], lss[4];
  int wid = threadIdx.x>>6, lane = threadIdx.x&63;
  if (lane==0){ ls[wid]=s; lss[wid]=ss; }
  __syncthreads();
  if (threadIdx.x==0){
    s = ls[0]+ls[1]+ls[2]+ls[3]; ss = lss[0]+lss[1]+lss[2]+lss[3];
    ps[b*128 + blockIdx.x] = s; pss[b*128 + blockIdx.x] = ss;
  }
}

__global__ void gn_final(const float* __restrict__ ps, const float* __restrict__ pss,
                         float* __restrict__ stats) {
  int b = blockIdx.x;
  float s = ps[b*128 + threadIdx.x], ss = pss[b*128 + threadIdx.x];
  for (int off=32; off; off>>=1){ s += __shfl_xor(s,off); ss += __shfl_xor(ss,off); }
  __shared__ float l0[2], l1[2];
  int wid = threadIdx.x>>6, lane = threadIdx.x&63;
  if (lane==0){ l0[wid]=s; l1[wid]=ss; }
  __syncthreads();
  if (threadIdx.x==0){
    s = l0[0]+l0[1]; ss = l1[0]+l1[1];
    float mean = s*(1.f/1048576.f);
    float var  = ss*(1.f/1048576.f) - mean*mean;
    stats[b*2] = mean; stats[b*2+1] = rsqrtf(var + 1e-8f);
  }
}

__global__ void norm_dw_T(const float* __restrict__ x, const float* __restrict__ stats,
                          const float* __restrict__ dw_w,
                          bhalf* __restrict__ zT, bhalf* __restrict__ dwT) {
  int b = blockIdx.z, n0 = blockIdx.x*32, c0 = blockIdx.y*32;
  float mean = stats[b*2], rstd = stats[b*2+1];
  __shared__ float zs[32][35];
  int tx = threadIdx.x, ty = threadIdx.y;
  #pragma unroll
  for (int r=0;r<4;r++){
    int c = c0 + ty + r*8;
    for (int cc=tx; cc<34; cc+=32){
      int n = n0 - 1 + cc;
      float v = 0.f;
      if (n>=0 && n<2048) v = (x[((long)b*512 + c)*2048 + n] - mean)*rstd;
      zs[ty + r*8][cc] = v;
    }
  }
  __syncthreads();
  float w0 = dw_w[(c0+tx)*3+0], w1 = dw_w[(c0+tx)*3+1], w2 = dw_w[(c0+tx)*3+2];
  #pragma unroll
  for (int r=0;r<4;r++){
    int ln = ty + r*8;
    float z = zs[tx][ln+1];
    float d = w0*zs[tx][ln] + w1*zs[tx][ln+1] + w2*zs[tx][ln+2];
    long o = ((long)b*2048 + n0 + ln)*512 + c0 + tx;
    zT[o] = (bhalf)z; dwT[o] = (bhalf)d;
  }
}

// ---------------------------------------------------------------------------
extern "C" void kernel_launch(void* const* d_in, const int* in_sizes, int n_in,
                              void* d_out, int out_size, void* d_ws, size_t ws_size,
                              hipStream_t stream) {
  (void)in_sizes; (void)n_in; (void)out_size; (void)ws_size;
  const float* x    = (const float*)d_in[0];
  const float* dw_w = (const float*)d_in[1];
  const float* pw_w = (const float*)d_in[2];
  const float* u_w  = (const float*)d_in[3];
  const float* u_b  = (const float*)d_in[4];
  const float* v_w  = (const float*)d_in[5];
  const float* v_b  = (const float*)d_in[6];
  const float* h_w  = (const float*)d_in[7];
  const float* h_b  = (const float*)d_in[8];
  const float* q_w  = (const float*)d_in[9];
  const float* k_w  = (const float*)d_in[10];
  const float* o_w  = (const float*)d_in[11];
  const float* o_b  = (const float*)d_in[12];
  float* out = (float*)d_out;

  char* ws = (char*)d_ws;
  size_t off = 0;
  auto alloc = [&](size_t bytes) -> void* {
    void* p = ws + off; off = (off + bytes + 255) & ~(size_t)255; return p;
  };

  float* ps    = (float*)alloc(4*128*4);
  float* pss   = (float*)alloc(4*128*4);
  float* stats = (float*)alloc(4*2*4);
  float* rden  = (float*)alloc(4*2048*4);
  float* bq    = (float*)alloc(1024*4);
  bhalf* wb_pw = (bhalf*)alloc(512*512*2);
  bhalf* wb_uv = (bhalf*)alloc((size_t)2048*512*2);
  bhalf* wb_h  = (bhalf*)alloc(512*512*2);
  bhalf* hwT   = (bhalf*)alloc(512*512*2);
  bhalf* wb_qk = (bhalf*)alloc((size_t)1024*512*2);
  bhalf* wqk2  = (bhalf*)alloc((size_t)1024*512*2);
  bhalf* wb_o  = (bhalf*)alloc((size_t)512*1024*2);
  const size_t ACT = (size_t)4*2048*512;
  bhalf* zT   = (bhalf*)alloc(ACT*2);       // reused as qb
  bhalf* dwT  = (bhalf*)alloc(ACT*2);       // reused as kb
  bhalf* z2T  = (bhalf*)alloc(ACT*2);
  bhalf* ub   = (bhalf*)alloc(ACT*2*2);     // [B,N,1024]
  unsigned char* v_fm = (unsigned char*)alloc((size_t)4*1024*2048);   // fp8
  unsigned char* wsc  = (unsigned char*)alloc((size_t)4*2048*2048);   // fp8
  bhalf* uav  = (bhalf*)alloc(ACT*2*2);
  bhalf* qb = zT;  bhalf* kb = dwT;

  // 0. zero attention-denominator accumulators
  hipMemsetAsync(rden, 0, 4*2048*4, stream);

  // 1. weights -> bf16 (u|v and q|k concatenated)
  CvtArgs ca;
  ca.src[0]=pw_w; ca.dst[0]=wb_pw;           ca.n[0]=512*512;
  ca.src[1]=u_w;  ca.dst[1]=wb_uv;           ca.n[1]=1024*512;
  ca.src[2]=v_w;  ca.dst[2]=wb_uv+1024*512;  ca.n[2]=1024*512;
  ca.src[3]=h_w;  ca.dst[3]=wb_h;            ca.n[3]=512*512;
  ca.src[4]=q_w;  ca.dst[4]=wb_qk;           ca.n[4]=512*512;
  ca.src[5]=k_w;  ca.dst[5]=wb_qk+512*512;   ca.n[5]=512*512;
  ca.src[6]=o_w;  ca.dst[6]=wb_o;            ca.n[6]=512*1024;
  cvt_multi<<<dim3(512,7), 256, 0, stream>>>(ca);

  // 2. fold h into q/k: wqk2 = [q_w;k_w] @ h_w, bq = [q_w;k_w] @ h_b
  transpose_bf16<<<dim3(16,16), dim3(32,8), 0, stream>>>(wb_h, hwT, 512, 512);
  g4k<EPI_ST><<<dim3(4,8,1), 256, 0, stream>>>(wb_qk, hwT, wqk2, nullptr,
      nullptr, nullptr, nullptr, 1024, 512, 512);
  qk_bias<<<dim3(256), 256, 0, stream>>>(wb_qk, h_b, bq);

  // 3-4. GroupNorm stats
  gn_part<<<dim3(128,4), 256, 0, stream>>>(x, ps, pss);
  gn_final<<<dim3(4), 128, 0, stream>>>(ps, pss, stats);

  // 5. normalize + dw conv + transpose -> zT, dwT
  norm_dw_T<<<dim3(64,16,4), dim3(32,8), 0, stream>>>(x, stats, dw_w, zT, dwT);

  const float iscl = 0.044194173824159216f;   // 1/sqrt(512)
  // 6. z2 = z + dw @ pw^T
  g4k<EPI_Z2><<<dim3(4,64,1), 256, 0, stream>>>(dwT, wb_pw, z2T, nullptr,
      nullptr, zT, nullptr, 8192, 512, 512);
  // 7. [u|v] = z2 @ [u_w|v_w]^T + b      (gA; u->ub bf16, v->v_fm fp8)
  gA<EPI_UV><<<dim3(8,32,1), 512, 0, stream>>>(z2T, wb_uv, ub, v_fm,
      u_b, v_b, 2048, 512, 0, 0, 0, 0, 0.f);
  // 8. [q|k] = z2 @ wqk2^T + bq          (h folded away)
  g4k<EPI_QK><<<dim3(8,64,1), 256, 0, stream>>>(z2T, wqk2, qb, kb,
      bq, nullptr, nullptr, 8192, 1024, 512);
  // 9. wsc(fp8) = relu(q@k^T * scale)^2 + fused row-sum atomics
  gA<EPI_ATTN><<<dim3(8,8,4), 512, 0, stream>>>(qb, kb, wsc, rden,
      nullptr, nullptr, 2048, 512,
      (long)2048*512, (long)2048*512, (long)2048*2048, 2048, iscl);
  // 10. uav = u * (wsc @ v_fm^T) / (den+eps)   (fp8 MFMA, batch in M)
  g4k8<<<dim3(8,64,1), 256, 0, stream>>>(wsc, v_fm, uav, ub, rden,
      2048, (long)1024*2048, 11);
  // 11. out = x + (uav @ o_w^T + o_b)^T  (fused residual add)
  g4k<EPI_Y><<<dim3(4,64,1), 256, 0, stream>>>(uav, wb_o, out, nullptr,
      o_b, nullptr, x, 8192, 512, 1024);
}

// Round 18
// 176.284 us; speedup vs baseline: 1.0879x; 1.0097x over previous
//
#include <hip/hip_runtime.h>
#include <hip/hip_bf16.h>
#include <cstdint>

typedef __bf16 bhalf;
typedef __bf16 bhalf8 __attribute__((ext_vector_type(8)));
typedef float f32x4 __attribute__((ext_vector_type(4)));

enum { EPI_Z2=0, EPI_UV=1, EPI_BIAS=2, EPI_QK=3, EPI_ATTN=4, EPI_PV=5, EPI_Y=6, EPI_ST=7 };

// async global->LDS, 16B per lane, LDS dest = wave-uniform base + lane*16
__device__ __forceinline__ void gl_lds16(const void* g, void* l) {
  __builtin_amdgcn_global_load_lds(
      (const __attribute__((address_space(1))) unsigned int*)g,
      (__attribute__((address_space(3))) unsigned int*)l,
      16, 0, 0);
}
__device__ __forceinline__ void barrier_raw() { asm volatile("s_barrier" ::: "memory"); }
#define VMW(n)  asm volatile("s_waitcnt vmcnt(" #n ")" ::: "memory")
#define LGKM0() asm volatile("s_waitcnt lgkmcnt(0)" ::: "memory")

// float -> fp8 e4m3 (OCP on gfx950) via HW cvt
__device__ __forceinline__ unsigned char to_fp8(float v){
  return (unsigned char)(__builtin_amdgcn_cvt_pk_fp8_f32(v, v, 0, false) & 0xff);
}

// Staging bank swizzle (verified R4-R16, SQ_LDS_BANK_CONFLICT == 0): 16B chunk
// c of a 64B row r holds global chunk c ^ ((r>>1)&3). Write: pre-swizzled
// GLOBAL source, linear LDS dest (rule #21); read side applies same XOR.
// bf16 C-tile (256B rows): 32B chunk ^ ((row>>2)&3).
// fp8 C-tile 256B rows: 16B chunk ^ (row&15); 128B rows: 16B chunk ^ (row&7).
// vmcnt ledger rule (R17 lesson): with P prologue-staged tiles of L loads each
// and stage-at-(kt+P), steady-state wait is VMW((P-1)*L); tail decrements by L.

// ---------------------------------------------------------------------------
// gA: 256x256 bf16, BK=64, 8 waves (2M x 4N, wave 128x64), 2 dbufs (128 KB),
// 4 phases/K-tile of 16 MFMA, in-place region staging, VMW(4)/K-tile.
// Used for UV: u->ub bf16, v->v_fm fp8 transposed.
// ---------------------------------------------------------------------------
template<int EPI>
__global__ void __launch_bounds__(512, 2)
gA(const bhalf* __restrict__ A, const bhalf* __restrict__ Bw,
   void* __restrict__ Out, void* __restrict__ Out2,
   const float* __restrict__ bias, const float* __restrict__ bias2,
   int N, int K, long sA, long sB, long sO, long sAuxf, float scale)
{
  constexpr int KSL = 256*64;     // 16 KB per k-slice plane
  constexpr int REG = 2*KSL;      // 32 KB (one K-tile of A or B)
  constexpr int DBUF = 2*REG;     // 64 KB
  __shared__ __align__(16) char lds[2*DBUF];   // 128 KB

  const int gx = gridDim.x, gy = gridDim.y;
  const int nwg = gx*gy;
  const int flat = blockIdx.y*gx + blockIdx.x;
  const int q8 = nwg>>3, r8 = nwg&7, xcd = flat&7, o8 = flat>>3;
  const int wsw = (xcd<r8 ? xcd*(q8+1) : r8*(q8+1)+(xcd-r8)*q8) + o8;
  const int bx = wsw % gx, by = wsw / gx;
  const int m0 = by*256, n0 = bx*256;
  const int bz = blockIdx.z;

  const bhalf* Ab = A + (long)bz*sA;
  const bhalf* Bb = Bw + (long)bz*sB;

  const int tid = threadIdx.x, wid = tid>>6, lane = tid&63;
  const int lm = lane&15, kq = lane>>4;
  const int wm = wid>>2, wn = wid&3;
  const int srow = lane>>2;
  const int csw = ((lane&3) ^ ((lane>>3)&3)) * 8;
  const int kqs = kq ^ ((lm>>1)&3);

  f32x4 acc[8][4];
  #pragma unroll
  for (int i=0;i<8;i++)
    #pragma unroll
    for (int j=0;j<4;j++) acc[i][j] = f32x4{0.f,0.f,0.f,0.f};

  auto stageA = [&](int kt){                     // 4 loads/wave
    char* base = lds + (kt&1)*DBUF;
    const int k0 = kt*64;
    #pragma unroll
    for (int h=0; h<2; h++)
      #pragma unroll
      for (int ksl=0; ksl<2; ksl++){
        bhalf* d = (bhalf*)(base + ksl*KSL + (h*128 + wid*16)*64);
        gl_lds16(Ab + (long)(m0 + h*128 + wid*16 + srow)*K + k0 + ksl*32 + csw, d);
      }
  };
  auto stageB = [&](int kt){                     // 4 loads/wave
    char* base = lds + (kt&1)*DBUF + REG;
    const int k0 = kt*64;
    #pragma unroll
    for (int h=0; h<2; h++)
      #pragma unroll
      for (int ksl=0; ksl<2; ksl++){
        bhalf* d = (bhalf*)(base + ksl*KSL + (h*128 + wid*16)*64);
        gl_lds16(Bb + (long)(n0 + h*128 + wid*16 + srow)*K + k0 + ksl*32 + csw, d);
      }
  };

  bhalf8 af[4][2], bf[4][2];
  auto readA = [&](int kt, int ih){
    char* base = lds + (kt&1)*DBUF;
    #pragma unroll
    for (int i2=0;i2<4;i2++)
      #pragma unroll
      for (int ksl=0;ksl<2;ksl++)
        af[i2][ksl] = *(const bhalf8*)(base + ksl*KSL + (wm*128 + ih*64 + i2*16 + lm)*64 + kqs*16);
  };
  auto readB = [&](int kt, int jh){
    char* base = lds + (kt&1)*DBUF + REG;
    #pragma unroll
    for (int j2=0;j2<2;j2++)
      #pragma unroll
      for (int ksl=0;ksl<2;ksl++)
        bf[jh*2+j2][ksl] = *(const bhalf8*)(base + ksl*KSL + (wn*64 + jh*32 + j2*16 + lm)*64 + kqs*16);
  };
  auto mfma16 = [&](int ih, int jh){
    __builtin_amdgcn_s_setprio(1);
    #pragma unroll
    for (int i2=0;i2<4;i2++)
      #pragma unroll
      for (int j2=0;j2<2;j2++)
        #pragma unroll
        for (int ksl=0;ksl<2;ksl++)
          acc[ih*4+i2][jh*2+j2] = __builtin_amdgcn_mfma_f32_16x16x32_bf16(
              af[i2][ksl], bf[jh*2+j2][ksl], acc[ih*4+i2][jh*2+j2], 0,0,0);
    __builtin_amdgcn_s_setprio(0);
  };

  const int NT = K>>6;
  stageA(0); stageB(0); stageA(1);               // 12 loads
  for (int kt=0; kt<NT; ++kt){
    if (kt==NT-1) { VMW(0); } else { VMW(4); }
    barrier_raw();
    readA(kt,0); readB(kt,0);
    if (kt+1<NT) stageB(kt+1);
    mfma16(0,0);
    barrier_raw();
    readB(kt,1);
    mfma16(0,1);
    barrier_raw();
    readA(kt,1);
    mfma16(1,0);
    barrier_raw();
    if (kt+2<NT) stageA(kt+2);
    mfma16(1,1);
  }
  barrier_raw();

  // ---- UV epilogue ----
  if constexpr (EPI==EPI_UV){
    const bool uh = n0 < 1024;
    const float* bv = uh ? bias : bias2;
    const int bc0 = uh ? n0 : n0-1024;
    #pragma unroll
    for (int i=0;i<8;i++){
      #pragma unroll
      for (int j=0;j<4;j++){
        const int lcol = wn*64 + j*16 + lm;
        #pragma unroll
        for (int r=0;r<4;r++){
          const int lrow = wm*128 + i*16 + kq*4 + r;
          float v = acc[i][j][r] + bv[bc0 + lcol];
          if (uh){
            v = 1.f/(1.f + __expf(-v));
            const int cb = lcol*2;
            const int lb = lrow*512 + (((cb>>5) ^ ((lrow>>2)&3))<<5) + (cb&31);
            *(bhalf*)(lds + lb) = (bhalf)v;
          } else {
            // fp8 transposed: row = v-channel (256B = 256 tokens), chunk^(ch&15)
            const int lb = lcol*256 + ((((lrow>>4) ^ (lcol&15)))<<4) + (lrow&15);
            *(unsigned char*)(lds + lb) = to_fp8(v);
          }
        }
      }
    }
    LGKM0();
    barrier_raw();
    if (uh){
      char* obase = (char*)Out + 2*((long)m0*1024 + n0);
      #pragma unroll
      for (int it=0; it<16; ++it){
        const int g = (it*512 + tid)*16;
        const int row = g >> 9, off = g & 511;
        const int lb = row*512 + (((off>>5) ^ ((row>>2)&3))<<5) + (off&31);
        uint4 val = *(const uint4*)(lds + lb);
        *(uint4*)(obase + (long)row*2048 + off) = val;
      }
    } else {
      // v_fm fp8 [B][1024][2048]: row = v-channel
      char* vb = (char*)Out2 + ((long)(m0>>11)*1024*2048 + (long)(n0-1024)*2048 + (m0 & 2047));
      #pragma unroll
      for (int it=0; it<8; ++it){
        const int g = (it*512 + tid)*16;
        const int row = g >> 8, off = g & 255;
        const int lb = row*256 + ((((off>>4) ^ (row&15)))<<4);
        uint4 val = *(const uint4*)(lds + lb);
        *(uint4*)(vb + (long)row*2048 + off) = val;
      }
    }
  }
  (void)scale; (void)bias; (void)bias2; (void)N; (void)sO; (void)sAuxf;
}

// ---------------------------------------------------------------------------
// gsc8: fp8 x fp8 score GEMM. 128x128 tile, 4 waves (2x2, wave 64x64), BK=64,
// ring-of-3 16 KB bufs (48 KB -> 3 blocks/CU), 2-ahead staging.
// Ledger (P=2 prologue, L=4): steady VMW(4), last tile VMW(0).  [R17 fix]
// wsc(fp8) = relu(q@k^T * scale)^2, fused row-sum atomics into rden.
// ---------------------------------------------------------------------------
__global__ void __launch_bounds__(256, 2)
gsc8(const unsigned char* __restrict__ Q, const unsigned char* __restrict__ Kp,
     unsigned char* __restrict__ Wsc, float* __restrict__ rden, float scale)
{
  constexpr int DBUF = 256*64;    // 16 KB: A rows 0-127, B rows 128-255
  __shared__ __align__(16) char lds[3*DBUF];   // 48 KB

  const int gx = gridDim.x, gy = gridDim.y;
  const int nwg = gx*gy;
  const int flat = blockIdx.y*gx + blockIdx.x;
  const int q8 = nwg>>3, r8 = nwg&7, xcd = flat&7, o8 = flat>>3;
  const int w = (xcd<r8 ? xcd*(q8+1) : r8*(q8+1)+(xcd-r8)*q8) + o8;
  const int bx = w % gx, by = w / gx;
  const int m0 = by*128, n0 = bx*128;
  const int bz = blockIdx.z;
  const int K = 512;

  const unsigned char* Ab = Q  + (long)bz*2048*512;
  const unsigned char* Bb = Kp + (long)bz*2048*512;

  const int tid = threadIdx.x;
  const int wid = tid>>6, lane = tid&63;
  const int lm = lane&15, kq = lane>>4;
  const int wm = wid>>1, wn = wid&1;
  const int srow = lane>>2;
  const int csw8 = ((lane&3) ^ ((lane>>3)&3))*16;   // fp8: 16B chunk = 16 elems
  int coff[2];
  #pragma unroll
  for (int ksl=0; ksl<2; ksl++)
    coff[ksl] = ((((ksl*2 + (kq>>1)) ^ ((lm>>1)&3)))<<4) + ((kq&1)<<3);

  f32x4 acc[4][4];
  #pragma unroll
  for (int i=0;i<4;i++)
    #pragma unroll
    for (int j=0;j<4;j++) acc[i][j] = f32x4{0.f,0.f,0.f,0.f};

  auto stage = [&](int kt){                      // 4 loads/wave
    char* base = lds + (kt%3)*DBUF;
    const int k0 = kt*64;
    #pragma unroll
    for (int c=0;c<4;c++){
      const int r0 = c*64 + wid*16;
      char* d = base + r0*64;
      const unsigned char* g = (r0 < 128)
        ? Ab + (long)(m0 + r0 + srow)*K + k0 + csw8
        : Bb + (long)(n0 + r0 - 128 + srow)*K + k0 + csw8;
      gl_lds16(g, d);
    }
  };

  long af[4][2], bf[4][2];
  auto readA = [&](int kt){
    char* base = lds + (kt%3)*DBUF;
    #pragma unroll
    for (int i2=0;i2<4;i2++)
      #pragma unroll
      for (int ksl=0;ksl<2;ksl++)
        af[i2][ksl] = *(const long*)(base + (wm*64 + i2*16 + lm)*64 + coff[ksl]);
  };
  auto readB = [&](int kt, int jh){
    char* base = lds + (kt%3)*DBUF;
    #pragma unroll
    for (int j2=0;j2<2;j2++)
      #pragma unroll
      for (int ksl=0;ksl<2;ksl++)
        bf[jh*2+j2][ksl] = *(const long*)(base + (128 + wn*64 + jh*32 + j2*16 + lm)*64 + coff[ksl]);
  };
  auto mfma16 = [&](int jh){
    __builtin_amdgcn_s_setprio(1);
    #pragma unroll
    for (int i2=0;i2<4;i2++)
      #pragma unroll
      for (int j2=0;j2<2;j2++)
        #pragma unroll
        for (int ksl=0;ksl<2;ksl++)
          acc[i2][jh*2+j2] = __builtin_amdgcn_mfma_f32_16x16x32_fp8_fp8(
              af[i2][ksl], bf[jh*2+j2][ksl], acc[i2][jh*2+j2], 0,0,0);
    __builtin_amdgcn_s_setprio(0);
  };

  const int NT = 8;
  stage(0); stage(1);                            // P=2 prologue: 8 loads
  for (int kt=0; kt<NT; ++kt){
    if (kt==NT-1) { VMW(0); } else { VMW(4); }   // R17 fix: guarantees S(kt)
    barrier_raw();
    readA(kt); readB(kt,0);
    if (kt+2<NT) stage(kt+2);
    mfma16(0);
    readB(kt,1);
    mfma16(1);
  }
  barrier_raw();

  // ---- epilogue: relu^2 + row-sums + fp8 C-tile (128B rows) ----
  float rs[4][4];
  #pragma unroll
  for (int i=0;i<4;i++)
    #pragma unroll
    for (int r=0;r<4;r++) rs[i][r]=0.f;
  #pragma unroll
  for (int i=0;i<4;i++){
    #pragma unroll
    for (int j=0;j<4;j++){
      const int lcol = wn*64 + j*16 + lm;
      #pragma unroll
      for (int r=0;r<4;r++){
        const int lrow = wm*64 + i*16 + kq*4 + r;
        float v = acc[i][j][r];
        v *= scale; v = fmaxf(v,0.f); v = v*v;
        rs[i][r] += v;
        const int lb = lrow*128 + ((((lcol>>4) ^ (lrow&7)))<<4) + (lcol&15);
        *(unsigned char*)(lds + lb) = to_fp8(v);
      }
    }
  }
  float* rd = rden + (long)bz*2048;
  #pragma unroll
  for (int i=0;i<4;i++){
    const int rbase = m0 + wm*64 + i*16 + kq*4;
    #pragma unroll
    for (int r=0;r<4;r++){
      float s = rs[i][r];
      s += __shfl_xor(s,1); s += __shfl_xor(s,2);
      s += __shfl_xor(s,4); s += __shfl_xor(s,8);
      if (lm==0) atomicAdd(rd + rbase + r, s);
    }
  }
  LGKM0();
  barrier_raw();
  unsigned char* obase = Wsc + (long)bz*2048*2048 + (long)m0*2048 + n0;
  #pragma unroll
  for (int it=0; it<4; ++it){
    const int g = (it*256 + tid)*16;
    const int row = g >> 7, off = g & 127;
    const int lb = row*128 + ((((off>>4) ^ (row&7)))<<4);
    uint4 val = *(const uint4*)(lds + lb);
    *(uint4*)(obase + (long)row*2048 + off) = val;
  }
}

// ---------------------------------------------------------------------------
// g4k8: fp8 x fp8 PV GEMM. 128x128 tile, 4 waves (2x2, wave 64x64), BK=64,
// ring-of-4 16KB bufs (64 KB -> 2 blocks/CU), 3-ahead staging.
// Ledger (P=3 prologue, L=4): steady VMW(8), then 4, then 0.  [verified R16]
// uav = u * (wsc @ v_fm^T) / (den+eps).
// ---------------------------------------------------------------------------
__global__ void __launch_bounds__(256, 2)
g4k8(const unsigned char* __restrict__ A, const unsigned char* __restrict__ Bw,
     bhalf* __restrict__ Out,
     const bhalf* __restrict__ ub, const float* __restrict__ rden,
     int K, long sB, int rowshift)
{
  constexpr int DBUF = 256*64;    // 16 KB: A rows 0-127, B rows 128-255
  __shared__ __align__(16) char lds[4*DBUF];   // 64 KB

  const int gx = gridDim.x, gy = gridDim.y;
  const int nwg = gx*gy;
  const int flat = blockIdx.y*gx + blockIdx.x;
  const int q8 = nwg>>3, r8 = nwg&7, xcd = flat&7, o8 = flat>>3;
  const int w = (xcd<r8 ? xcd*(q8+1) : r8*(q8+1)+(xcd-r8)*q8) + o8;
  const int bx = w % gx, by = w / gx;
  const int m0 = by*128, n0 = bx*128;

  const unsigned char* Bb = Bw + (long)(m0>>rowshift)*sB;

  const int tid = threadIdx.x;
  const int wid = tid>>6, lane = tid&63;
  const int lm = lane&15, kq = lane>>4;
  const int wm = wid>>1, wn = wid&1;
  const int srow = lane>>2;
  const int csw8 = ((lane&3) ^ ((lane>>3)&3))*16;
  int coff[2];
  #pragma unroll
  for (int ksl=0; ksl<2; ksl++)
    coff[ksl] = ((((ksl*2 + (kq>>1)) ^ ((lm>>1)&3)))<<4) + ((kq&1)<<3);

  f32x4 acc[4][4];
  #pragma unroll
  for (int i=0;i<4;i++)
    #pragma unroll
    for (int j=0;j<4;j++) acc[i][j] = f32x4{0.f,0.f,0.f,0.f};

  auto stage = [&](int kt){                      // 4 loads/wave
    char* base = lds + (kt&3)*DBUF;
    const int k0 = kt*64;
    #pragma unroll
    for (int c=0;c<4;c++){
      const int r0 = c*64 + wid*16;
      char* d = base + r0*64;
      const unsigned char* g = (r0 < 128)
        ? A  + (long)(m0 + r0 + srow)*K + k0 + csw8
        : Bb + (long)(n0 + r0 - 128 + srow)*K + k0 + csw8;
      gl_lds16(g, d);
    }
  };

  long af[4][2], bf[4][2];
  auto readA = [&](int kt){
    char* base = lds + (kt&3)*DBUF;
    #pragma unroll
    for (int i2=0;i2<4;i2++)
      #pragma unroll
      for (int ksl=0;ksl<2;ksl++)
        af[i2][ksl] = *(const long*)(base + (wm*64 + i2*16 + lm)*64 + coff[ksl]);
  };
  auto readB = [&](int kt, int jh){
    char* base = lds + (kt&3)*DBUF;
    #pragma unroll
    for (int j2=0;j2<2;j2++)
      #pragma unroll
      for (int ksl=0;ksl<2;ksl++)
        bf[jh*2+j2][ksl] = *(const long*)(base + (128 + wn*64 + jh*32 + j2*16 + lm)*64 + coff[ksl]);
  };
  auto mfma16 = [&](int jh){
    __builtin_amdgcn_s_setprio(1);
    #pragma unroll
    for (int i2=0;i2<4;i2++)
      #pragma unroll
      for (int j2=0;j2<2;j2++)
        #pragma unroll
        for (int ksl=0;ksl<2;ksl++)
          acc[i2][jh*2+j2] = __builtin_amdgcn_mfma_f32_16x16x32_fp8_fp8(
              af[i2][ksl], bf[jh*2+j2][ksl], acc[i2][jh*2+j2], 0,0,0);
    __builtin_amdgcn_s_setprio(0);
  };

  const int NT = K>>6;
  stage(0); stage(1); stage(2);                  // P=3 prologue: 12 loads
  for (int kt=0; kt<NT; ++kt){
    if (kt==NT-1)      { VMW(0); }
    else if (kt==NT-2) { VMW(4); }
    else               { VMW(8); }
    barrier_raw();
    readA(kt); readB(kt,0);
    if (kt+3<NT) stage(kt+3);
    mfma16(0);
    readB(kt,1);
    mfma16(1);
  }
  barrier_raw();

  // ---- epilogue: u-gate + normalize -> bf16 C-tile -> coalesced ----
  char* obase = (char*)Out + 2*((long)m0*1024 + n0);
  #pragma unroll
  for (int i=0;i<4;i++){
    #pragma unroll
    for (int j=0;j<4;j++){
      const int lcol = wn*64 + j*16 + lm;
      #pragma unroll
      for (int r=0;r<4;r++){
        const int lrow = wm*64 + i*16 + kq*4 + r;
        const int rowg = m0 + lrow;
        float v = acc[i][j][r];
        float den = rden[rowg];
        v *= __builtin_amdgcn_rcpf(den + 1e-8f);
        v *= (float)ub[(long)rowg*1024 + n0 + lcol];
        const int cb = lcol*2;
        const int lb = lrow*256 + (((cb>>5) ^ ((lrow>>2)&3))<<5) + (cb&31);
        *(bhalf*)(lds + lb) = (bhalf)v;
      }
    }
  }
  LGKM0();
  barrier_raw();
  #pragma unroll
  for (int it=0; it<8; ++it){
    const int g = (it*256 + tid)*16;
    const int row = g >> 8, off = g & 255;
    const int lb = row*256 + (((off>>5) ^ ((row>>2)&3))<<5) + (off&31);
    uint4 val = *(const uint4*)(lds + lb);
    *(uint4*)(obase + (long)row*2048 + off) = val;
  }
}

// ---------------------------------------------------------------------------
// g4k: bf16 128x128 tile, 4 waves (2x2, wave 64x64), BK=64, 2 dbufs (64 KB),
// 2-ahead in-place staging, VMW(8)/K-tile (in-place dbuf: S(kt),S(kt+1) out-
// standing = 16 loads max, wait to 8 drains S(kt); verified R13-R16).
// For z2 / QK(fp8 out) / y / wqk2.
// ---------------------------------------------------------------------------
template<int EPI>
__global__ void __launch_bounds__(256, 2)
g4k(const bhalf* __restrict__ A, const bhalf* __restrict__ Bw,
    void* __restrict__ Out, void* __restrict__ Out2,
    const float* __restrict__ bias,
    const bhalf* __restrict__ auxb,
    const float* __restrict__ xadd,
    int M, int N, int K)
{
  constexpr int KSL = 256*64;     // 16 KB plane: A rows 0-127, B rows 128-255
  constexpr int DBUF = 2*KSL;     // 32 KB
  __shared__ __align__(16) char lds[2*DBUF];   // 64 KB

  const int gx = gridDim.x, gy = gridDim.y;
  const int nwg = gx*gy;
  const int flat = blockIdx.y*gx + blockIdx.x;
  const int q8 = nwg>>3, r8 = nwg&7, xcd = flat&7, o8 = flat>>3;
  const int w = (xcd<r8 ? xcd*(q8+1) : r8*(q8+1)+(xcd-r8)*q8) + o8;
  const int bx = w % gx, by = w / gx;
  const int m0 = by*128, n0 = bx*128;

  const int tid = threadIdx.x;
  const int wid = tid>>6, lane = tid&63;
  const int lm = lane&15, kq = lane>>4;
  const int wm = wid>>1, wn = wid&1;
  const int srow = lane>>2;
  const int csw = ((lane&3) ^ ((lane>>3)&3))*8;
  const int kqs = kq ^ ((lm>>1)&3);

  f32x4 acc[4][4];
  #pragma unroll
  for (int i=0;i<4;i++)
    #pragma unroll
    for (int j=0;j<4;j++) acc[i][j] = f32x4{0.f,0.f,0.f,0.f};

  auto stage = [&](int kt){                      // 8 loads/wave
    char* base = lds + (kt&1)*DBUF;
    const int k0 = kt*64;
    #pragma unroll
    for (int c=0;c<4;c++){
      const int r0 = c*64 + wid*16;
      #pragma unroll
      for (int ksl=0; ksl<2; ksl++){
        bhalf* d = (bhalf*)(base + ksl*KSL + r0*64);
        const bhalf* g = (r0 < 128)
          ? A  + (long)(m0 + r0 + srow)*K + k0 + ksl*32 + csw
          : Bw + (long)(n0 + r0 - 128 + srow)*K + k0 + ksl*32 + csw;
        gl_lds16(g, d);
      }
    }
  };

  bhalf8 af[4][2], bf[4][2];
  auto readA = [&](int kt){
    char* base = lds + (kt&1)*DBUF;
    #pragma unroll
    for (int i2=0;i2<4;i2++)
      #pragma unroll
      for (int ksl=0;ksl<2;ksl++)
        af[i2][ksl] = *(const bhalf8*)(base + ksl*KSL + (wm*64 + i2*16 + lm)*64 + kqs*16);
  };
  auto readB = [&](int kt, int jh){
    char* base = lds + (kt&1)*DBUF;
    #pragma unroll
    for (int j2=0;j2<2;j2++)
      #pragma unroll
      for (int ksl=0;ksl<2;ksl++)
        bf[jh*2+j2][ksl] = *(const bhalf8*)(base + ksl*KSL + (128 + wn*64 + jh*32 + j2*16 + lm)*64 + kqs*16);
  };
  auto mfma16 = [&](int jh){
    __builtin_amdgcn_s_setprio(1);
    #pragma unroll
    for (int i2=0;i2<4;i2++)
      #pragma unroll
      for (int j2=0;j2<2;j2++)
        #pragma unroll
        for (int ksl=0;ksl<2;ksl++)
          acc[i2][jh*2+j2] = __builtin_amdgcn_mfma_f32_16x16x32_bf16(
              af[i2][ksl], bf[jh*2+j2][ksl], acc[i2][jh*2+j2], 0,0,0);
    __builtin_amdgcn_s_setprio(0);
  };

  const int NT = K>>6;
  stage(0); stage(1);
  for (int kt=0; kt<NT; ++kt){
    if (kt==NT-1) { VMW(0); } else { VMW(8); }
    barrier_raw();
    readA(kt); readB(kt,0);
    mfma16(0);
    barrier_raw();
    readB(kt,1);
    if (kt+2<NT) stage(kt+2);
    mfma16(1);
  }
  barrier_raw();

  // ---- epilogues ----
  if constexpr (EPI==EPI_Y){
    #pragma unroll
    for (int i=0;i<4;i++){
      #pragma unroll
      for (int j=0;j<4;j++){
        const int lcol = wn*64 + j*16 + lm;
        #pragma unroll
        for (int r=0;r<4;r++){
          const int lrow = wm*64 + i*16 + kq*4 + r;
          float v = acc[i][j][r] + bias[n0 + lcol];
          const int lb = lcol*512 + 4*(lrow ^ ((lcol&15)<<2));
          *(float*)(lds + lb) = v;
        }
      }
    }
    LGKM0();
    barrier_raw();
    const int b = m0 >> 11, nb = m0 & 2047;
    float* ob = (float*)Out + ((long)b*512 + n0)*2048 + nb;
    const float* xb = xadd + ((long)b*512 + n0)*2048 + nb;
    #pragma unroll
    for (int it=0; it<16; ++it){
      const int g = (it*256 + tid)*16;
      const int row = g >> 9, off = g & 511;
      const int t0 = off >> 2;
      const int s = (row&15)<<2;
      f32x4 vv = *(const f32x4*)(lds + row*512 + 4*(t0^s));
      f32x4 xx = *(const f32x4*)(xb + (long)row*2048 + t0);
      *(f32x4*)(ob + (long)row*2048 + t0) = vv + xx;
    }
  } else if constexpr (EPI==EPI_QK){
    // fp8 q/k output: bias then e4m3; 128B-row fp8 C-tile
    bool qh = n0 < 512;
    unsigned char* obase = (unsigned char*)(qh?Out:Out2) + (long)m0*512 + (n0 - (qh?0:512));
    #pragma unroll
    for (int i=0;i<4;i++){
      #pragma unroll
      for (int j=0;j<4;j++){
        const int lcol = wn*64 + j*16 + lm;
        #pragma unroll
        for (int r=0;r<4;r++){
          const int lrow = wm*64 + i*16 + kq*4 + r;
          float v = acc[i][j][r] + bias[n0 + lcol];
          const int lb = lrow*128 + ((((lcol>>4) ^ (lrow&7)))<<4) + (lcol&15);
          *(unsigned char*)(lds + lb) = to_fp8(v);
        }
      }
    }
    LGKM0();
    barrier_raw();
    #pragma unroll
    for (int it=0; it<4; ++it){
      const int g = (it*256 + tid)*16;
      const int row = g >> 7, off = g & 127;
      const int lb = row*128 + ((((off>>4) ^ (row&7)))<<4);
      uint4 val = *(const uint4*)(lds + lb);
      *(uint4*)(obase + (long)row*512 + off) = val;
    }
  } else {
    char* obase = (char*)Out + 2*((long)m0*N + n0);
    const int ldb = N*2;
    #pragma unroll
    for (int i=0;i<4;i++){
      #pragma unroll
      for (int j=0;j<4;j++){
        const int lcol = wn*64 + j*16 + lm;
        #pragma unroll
        for (int r=0;r<4;r++){
          const int lrow = wm*64 + i*16 + kq*4 + r;
          float v = acc[i][j][r];
          if constexpr (EPI==EPI_Z2)
            v += (float)auxb[(long)(m0+lrow)*N + n0 + lcol];
          if constexpr (EPI==EPI_BIAS)
            v += bias[n0 + lcol];
          const int cb = lcol*2;
          const int lb = lrow*256 + (((cb>>5) ^ ((lrow>>2)&3))<<5) + (cb&31);
          *(bhalf*)(lds + lb) = (bhalf)v;
        }
      }
    }
    LGKM0();
    barrier_raw();
    #pragma unroll
    for (int it=0; it<8; ++it){
      const int g = (it*256 + tid)*16;
      const int row = g >> 8, off = g & 255;
      const int lb = row*256 + (((off>>5) ^ ((row>>2)&3))<<5) + (off&31);
      uint4 val = *(const uint4*)(lds + lb);
      *(uint4*)(obase + (long)row*ldb + off) = val;
    }
  }
  (void)M; (void)xadd; (void)bias; (void)auxb;
}

// ---------------------------------------------------------------------------
struct CvtArgs { const float* src[7]; bhalf* dst[7]; int n[7]; };
__global__ void cvt_multi(CvtArgs a) {
  int seg = blockIdx.y;
  int i = (blockIdx.x*256 + threadIdx.x)*4;
  if (i >= a.n[seg]) return;
  float4 f = *(const float4*)(a.src[seg] + i);
  bhalf* d = a.dst[seg] + i;
  d[0]=(bhalf)f.x; d[1]=(bhalf)f.y; d[2]=(bhalf)f.z; d[3]=(bhalf)f.w;
}

// bf16 transpose: in [R,C] -> out [C,R]
__global__ void transpose_bf16(const bhalf* __restrict__ in, bhalf* __restrict__ out,
                               int R, int C) {
  __shared__ bhalf t[32][33];
  int r0 = blockIdx.x*32, c0 = blockIdx.y*32;
  int tx = threadIdx.x, ty = threadIdx.y;
  #pragma unroll
  for (int r=0;r<4;r++)
    t[ty + r*8][tx] = in[(long)(r0 + ty + r*8)*C + c0 + tx];
  __syncthreads();
  #pragma unroll
  for (int r=0;r<4;r++)
    out[(long)(c0 + ty + r*8)*R + r0 + tx] = t[tx][ty + r*8];
}

// bq[row] = sum_m wqk[row][m] * hb[m]
__global__ void qk_bias(const bhalf* __restrict__ wqk, const float* __restrict__ hb,
                        float* __restrict__ bq){
  int row = blockIdx.x*4 + (threadIdx.x>>6);
  int lane = threadIdx.x & 63;
  const bhalf* p = wqk + (long)row*512;
  float s = 0.f;
  #pragma unroll
  for (int j=0;j<8;j++) s += (float)p[lane*8+j] * hb[lane*8+j];
  for (int off=32; off; off>>=1) s += __shfl_xor(s, off);
  if (lane==0) bq[row] = s;
}

__global__ void gn_part(const float* __restrict__ x, float* __restrict__ ps, float* __restrict__ pss) {
  int b = blockIdx.y;
  const float* xb = x + (long)b*(512*2048);
  float s=0.f, ss=0.f;
  #pragma unroll
  for (int it=0; it<8; it++){
    int idx = ((it*128 + blockIdx.x)*256 + threadIdx.x)*4;
    float4 f = *(const float4*)(xb + idx);
    s  += f.x+f.y+f.z+f.w;
    ss += f.x*f.x+f.y*f.y+f.z*f.z+f.w*f.w;
  }
  for (int off=32; off; off>>=1){ s += __shfl_xor(s,off); ss += __shfl_xor(ss,off); }
  __shared__ float ls[4], lss[4];
  int wid = threadIdx.x>>6, lane = threadIdx.x&63;
  if (lane==0){ ls[wid]=s; lss[wid]=ss; }
  __syncthreads();
  if (threadIdx.x==0){
    s = ls[0]+ls[1]+ls[2]+ls[3]; ss = lss[0]+lss[1]+lss[2]+lss[3];
    ps[b*128 + blockIdx.x] = s; pss[b*128 + blockIdx.x] = ss;
  }
}

__global__ void gn_final(const float* __restrict__ ps, const float* __restrict__ pss,
                         float* __restrict__ stats) {
  int b = blockIdx.x;
  float s = ps[b*128 + threadIdx.x], ss = pss[b*128 + threadIdx.x];
  for (int off=32; off; off>>=1){ s += __shfl_xor(s,off); ss += __shfl_xor(ss,off); }
  __shared__ float l0[2], l1[2];
  int wid = threadIdx.x>>6, lane = threadIdx.x&63;
  if (lane==0){ l0[wid]=s; l1[wid]=ss; }
  __syncthreads();
  if (threadIdx.x==0){
    s = l0[0]+l0[1]; ss = l1[0]+l1[1];
    float mean = s*(1.f/1048576.f);
    float var  = ss*(1.f/1048576.f) - mean*mean;
    stats[b*2] = mean; stats[b*2+1] = rsqrtf(var + 1e-8f);
  }
}

__global__ void norm_dw_T(const float* __restrict__ x, const float* __restrict__ stats,
                          const float* __restrict__ dw_w,
                          bhalf* __restrict__ zT, bhalf* __restrict__ dwT) {
  int b = blockIdx.z, n0 = blockIdx.x*32, c0 = blockIdx.y*32;
  float mean = stats[b*2], rstd = stats[b*2+1];
  __shared__ float zs[32][35];
  int tx = threadIdx.x, ty = threadIdx.y;
  #pragma unroll
  for (int r=0;r<4;r++){
    int c = c0 + ty + r*8;
    for (int cc=tx; cc<34; cc+=32){
      int n = n0 - 1 + cc;
      float v = 0.f;
      if (n>=0 && n<2048) v = (x[((long)b*512 + c)*2048 + n] - mean)*rstd;
      zs[ty + r*8][cc] = v;
    }
  }
  __syncthreads();
  float w0 = dw_w[(c0+tx)*3+0], w1 = dw_w[(c0+tx)*3+1], w2 = dw_w[(c0+tx)*3+2];
  #pragma unroll
  for (int r=0;r<4;r++){
    int ln = ty + r*8;
    float z = zs[tx][ln+1];
    float d = w0*zs[tx][ln] + w1*zs[tx][ln+1] + w2*zs[tx][ln+2];
    long o = ((long)b*2048 + n0 + ln)*512 + c0 + tx;
    zT[o] = (bhalf)z; dwT[o] = (bhalf)d;
  }
}

// ---------------------------------------------------------------------------
extern "C" void kernel_launch(void* const* d_in, const int* in_sizes, int n_in,
                              void* d_out, int out_size, void* d_ws, size_t ws_size,
                              hipStream_t stream) {
  (void)in_sizes; (void)n_in; (void)out_size; (void)ws_size;
  const float* x    = (const float*)d_in[0];
  const float* dw_w = (const float*)d_in[1];
  const float* pw_w = (const float*)d_in[2];
  const float* u_w  = (const float*)d_in[3];
  const float* u_b  = (const float*)d_in[4];
  const float* v_w  = (const float*)d_in[5];
  const float* v_b  = (const float*)d_in[6];
  const float* h_w  = (const float*)d_in[7];
  const float* h_b  = (const float*)d_in[8];
  const float* q_w  = (const float*)d_in[9];
  const float* k_w  = (const float*)d_in[10];
  const float* o_w  = (const float*)d_in[11];
  const float* o_b  = (const float*)d_in[12];
  float* out = (float*)d_out;

  char* ws = (char*)d_ws;
  size_t off = 0;
  auto alloc = [&](size_t bytes) -> void* {
    void* p = ws + off; off = (off + bytes + 255) & ~(size_t)255; return p;
  };

  float* ps    = (float*)alloc(4*128*4);
  float* pss   = (float*)alloc(4*128*4);
  float* stats = (float*)alloc(4*2*4);
  float* rden  = (float*)alloc(4*2048*4);
  float* bq    = (float*)alloc(1024*4);
  bhalf* wb_pw = (bhalf*)alloc(512*512*2);
  bhalf* wb_uv = (bhalf*)alloc((size_t)2048*512*2);
  bhalf* wb_h  = (bhalf*)alloc(512*512*2);
  bhalf* hwT   = (bhalf*)alloc(512*512*2);
  bhalf* wb_qk = (bhalf*)alloc((size_t)1024*512*2);
  bhalf* wqk2  = (bhalf*)alloc((size_t)1024*512*2);
  bhalf* wb_o  = (bhalf*)alloc((size_t)512*1024*2);
  const size_t ACT = (size_t)4*2048*512;
  bhalf* zT   = (bhalf*)alloc(ACT*2);
  bhalf* dwT  = (bhalf*)alloc(ACT*2);
  bhalf* z2T  = (bhalf*)alloc(ACT*2);
  bhalf* ub   = (bhalf*)alloc(ACT*2*2);     // [B,N,1024]
  unsigned char* v_fm = (unsigned char*)alloc((size_t)4*1024*2048);   // fp8
  unsigned char* wsc  = (unsigned char*)alloc((size_t)4*2048*2048);   // fp8
  unsigned char* qb8  = (unsigned char*)alloc(ACT);                   // fp8 q
  unsigned char* kb8  = (unsigned char*)alloc(ACT);                   // fp8 k
  bhalf* uav  = (bhalf*)alloc(ACT*2*2);

  // 0. zero attention-denominator accumulators
  hipMemsetAsync(rden, 0, 4*2048*4, stream);

  // 1. weights -> bf16 (u|v and q|k concatenated)
  CvtArgs ca;
  ca.src[0]=pw_w; ca.dst[0]=wb_pw;           ca.n[0]=512*512;
  ca.src[1]=u_w;  ca.dst[1]=wb_uv;           ca.n[1]=1024*512;
  ca.src[2]=v_w;  ca.dst[2]=wb_uv+1024*512;  ca.n[2]=1024*512;
  ca.src[3]=h_w;  ca.dst[3]=wb_h;            ca.n[3]=512*512;
  ca.src[4]=q_w;  ca.dst[4]=wb_qk;           ca.n[4]=512*512;
  ca.src[5]=k_w;  ca.dst[5]=wb_qk+512*512;   ca.n[5]=512*512;
  ca.src[6]=o_w;  ca.dst[6]=wb_o;            ca.n[6]=512*1024;
  cvt_multi<<<dim3(512,7), 256, 0, stream>>>(ca);

  // 2. fold h into q/k: wqk2 = [q_w;k_w] @ h_w, bq = [q_w;k_w] @ h_b
  transpose_bf16<<<dim3(16,16), dim3(32,8), 0, stream>>>(wb_h, hwT, 512, 512);
  g4k<EPI_ST><<<dim3(4,8,1), 256, 0, stream>>>(wb_qk, hwT, wqk2, nullptr,
      nullptr, nullptr, nullptr, 1024, 512, 512);
  qk_bias<<<dim3(256), 256, 0, stream>>>(wb_qk, h_b, bq);

  // 3-4. GroupNorm stats
  gn_part<<<dim3(128,4), 256, 0, stream>>>(x, ps, pss);
  gn_final<<<dim3(4), 128, 0, stream>>>(ps, pss, stats);

  // 5. normalize + dw conv + transpose -> zT, dwT
  norm_dw_T<<<dim3(64,16,4), dim3(32,8), 0, stream>>>(x, stats, dw_w, zT, dwT);

  const float iscl = 0.044194173824159216f;   // 1/sqrt(512)
  // 6. z2 = z + dw @ pw^T
  g4k<EPI_Z2><<<dim3(4,64,1), 256, 0, stream>>>(dwT, wb_pw, z2T, nullptr,
      nullptr, zT, nullptr, 8192, 512, 512);
  // 7. [u|v] = z2 @ [u_w|v_w]^T + b      (gA; u->ub bf16, v->v_fm fp8)
  gA<EPI_UV><<<dim3(8,32,1), 512, 0, stream>>>(z2T, wb_uv, ub, v_fm,
      u_b, v_b, 2048, 512, 0, 0, 0, 0, 0.f);
  // 8. [q|k](fp8) = z2 @ wqk2^T + bq     (h folded away)
  g4k<EPI_QK><<<dim3(8,64,1), 256, 0, stream>>>(z2T, wqk2, qb8, kb8,
      bq, nullptr, nullptr, 8192, 1024, 512);
  // 9. wsc(fp8) = relu(q@k^T * scale)^2 + fused row-sum atomics (fp8 MFMA)
  gsc8<<<dim3(16,16,4), 256, 0, stream>>>(qb8, kb8, wsc, rden, iscl);
  // 10. uav = u * (wsc @ v_fm^T) / (den+eps)   (fp8 MFMA, batch in M)
  g4k8<<<dim3(8,64,1), 256, 0, stream>>>(wsc, v_fm, uav, ub, rden,
      2048, (long)1024*2048, 11);
  // 11. out = x + (uav @ o_w^T + o_b)^T  (fused residual add)
  g4k<EPI_Y><<<dim3(4,64,1), 256, 0, stream>>>(uav, wb_o, out, nullptr,
      o_b, nullptr, x, 8192, 512, 1024);
}

// Round 19
// 172.833 us; speedup vs baseline: 1.1097x; 1.0200x over previous
//
#include <hip/hip_runtime.h>
#include <hip/hip_bf16.h>
#include <cstdint>

typedef __bf16 bhalf;
typedef __bf16 bhalf8 __attribute__((ext_vector_type(8)));
typedef float f32x4 __attribute__((ext_vector_type(4)));

enum { EPI_Z2=0, EPI_BIAS=2, EPI_QK=3, EPI_Y=6, EPI_ST=7 };

// async global->LDS, 16B per lane, LDS dest = wave-uniform base + lane*16
__device__ __forceinline__ void gl_lds16(const void* g, void* l) {
  __builtin_amdgcn_global_load_lds(
      (const __attribute__((address_space(1))) unsigned int*)g,
      (__attribute__((address_space(3))) unsigned int*)l,
      16, 0, 0);
}
__device__ __forceinline__ void barrier_raw() { asm volatile("s_barrier" ::: "memory"); }
#define VMW(n)  asm volatile("s_waitcnt vmcnt(" #n ")" ::: "memory")
#define LGKM0() asm volatile("s_waitcnt lgkmcnt(0)" ::: "memory")

// float -> fp8 e4m3 (OCP on gfx950) via HW cvt
__device__ __forceinline__ unsigned char to_fp8(float v){
  return (unsigned char)(__builtin_amdgcn_cvt_pk_fp8_f32(v, v, 0, false) & 0xff);
}

// Staging bank swizzle (verified R4-R18, SQ_LDS_BANK_CONFLICT == 0): 16B chunk
// c of a 64B row r holds global chunk c ^ ((r>>1)&3). Write: pre-swizzled
// GLOBAL source, linear LDS dest (rule #21); read side applies same XOR.
// bf16 C-tile (256B rows): 32B chunk ^ ((row>>2)&3).
// fp8 C-tile 256B rows: 16B chunk ^ (row&15); 128B rows: 16B chunk ^ (row&7).
// vmcnt ledger rule (R17 lesson): with P prologue-staged tiles of L loads each
// and stage-at-(kt+P), steady-state wait is VMW((P-1)*L); tail decrements by L.

// ---------------------------------------------------------------------------
// gsc8: fp8 x fp8 score GEMM. 128x128 tile, 4 waves (2x2, wave 64x64), BK=64,
// ring-of-3 16 KB bufs (48 KB), 2-ahead staging. Ledger: P=2, L=4 -> VMW(4).
// wsc(fp8) = relu(q@k^T * scale)^2, fused row-sum atomics into rden.
// ---------------------------------------------------------------------------
__global__ void __launch_bounds__(256, 2)
gsc8(const unsigned char* __restrict__ Q, const unsigned char* __restrict__ Kp,
     unsigned char* __restrict__ Wsc, float* __restrict__ rden, float scale)
{
  constexpr int DBUF = 256*64;    // 16 KB: A rows 0-127, B rows 128-255
  __shared__ __align__(16) char lds[3*DBUF];   // 48 KB

  const int gx = gridDim.x, gy = gridDim.y;
  const int nwg = gx*gy;
  const int flat = blockIdx.y*gx + blockIdx.x;
  const int q8 = nwg>>3, r8 = nwg&7, xcd = flat&7, o8 = flat>>3;
  const int w = (xcd<r8 ? xcd*(q8+1) : r8*(q8+1)+(xcd-r8)*q8) + o8;
  const int bx = w % gx, by = w / gx;
  const int m0 = by*128, n0 = bx*128;
  const int bz = blockIdx.z;
  const int K = 512;

  const unsigned char* Ab = Q  + (long)bz*2048*512;
  const unsigned char* Bb = Kp + (long)bz*2048*512;

  const int tid = threadIdx.x;
  const int wid = tid>>6, lane = tid&63;
  const int lm = lane&15, kq = lane>>4;
  const int wm = wid>>1, wn = wid&1;
  const int srow = lane>>2;
  const int csw8 = ((lane&3) ^ ((lane>>3)&3))*16;
  int coff[2];
  #pragma unroll
  for (int ksl=0; ksl<2; ksl++)
    coff[ksl] = ((((ksl*2 + (kq>>1)) ^ ((lm>>1)&3)))<<4) + ((kq&1)<<3);

  f32x4 acc[4][4];
  #pragma unroll
  for (int i=0;i<4;i++)
    #pragma unroll
    for (int j=0;j<4;j++) acc[i][j] = f32x4{0.f,0.f,0.f,0.f};

  auto stage = [&](int kt){                      // 4 loads/wave
    char* base = lds + (kt%3)*DBUF;
    const int k0 = kt*64;
    #pragma unroll
    for (int c=0;c<4;c++){
      const int r0 = c*64 + wid*16;
      char* d = base + r0*64;
      const unsigned char* g = (r0 < 128)
        ? Ab + (long)(m0 + r0 + srow)*K + k0 + csw8
        : Bb + (long)(n0 + r0 - 128 + srow)*K + k0 + csw8;
      gl_lds16(g, d);
    }
  };

  long af[4][2], bf[4][2];
  auto readA = [&](int kt){
    char* base = lds + (kt%3)*DBUF;
    #pragma unroll
    for (int i2=0;i2<4;i2++)
      #pragma unroll
      for (int ksl=0;ksl<2;ksl++)
        af[i2][ksl] = *(const long*)(base + (wm*64 + i2*16 + lm)*64 + coff[ksl]);
  };
  auto readB = [&](int kt, int jh){
    char* base = lds + (kt%3)*DBUF;
    #pragma unroll
    for (int j2=0;j2<2;j2++)
      #pragma unroll
      for (int ksl=0;ksl<2;ksl++)
        bf[jh*2+j2][ksl] = *(const long*)(base + (128 + wn*64 + jh*32 + j2*16 + lm)*64 + coff[ksl]);
  };
  auto mfma16 = [&](int jh){
    __builtin_amdgcn_s_setprio(1);
    #pragma unroll
    for (int i2=0;i2<4;i2++)
      #pragma unroll
      for (int j2=0;j2<2;j2++)
        #pragma unroll
        for (int ksl=0;ksl<2;ksl++)
          acc[i2][jh*2+j2] = __builtin_amdgcn_mfma_f32_16x16x32_fp8_fp8(
              af[i2][ksl], bf[jh*2+j2][ksl], acc[i2][jh*2+j2], 0,0,0);
    __builtin_amdgcn_s_setprio(0);
  };

  const int NT = 8;
  stage(0); stage(1);                            // P=2 prologue: 8 loads
  for (int kt=0; kt<NT; ++kt){
    if (kt==NT-1) { VMW(0); } else { VMW(4); }
    barrier_raw();
    readA(kt); readB(kt,0);
    if (kt+2<NT) stage(kt+2);
    mfma16(0);
    readB(kt,1);
    mfma16(1);
  }
  barrier_raw();

  // ---- epilogue: relu^2 + row-sums + fp8 C-tile (128B rows) ----
  float rs[4][4];
  #pragma unroll
  for (int i=0;i<4;i++)
    #pragma unroll
    for (int r=0;r<4;r++) rs[i][r]=0.f;
  #pragma unroll
  for (int i=0;i<4;i++){
    #pragma unroll
    for (int j=0;j<4;j++){
      const int lcol = wn*64 + j*16 + lm;
      #pragma unroll
      for (int r=0;r<4;r++){
        const int lrow = wm*64 + i*16 + kq*4 + r;
        float v = acc[i][j][r];
        v *= scale; v = fmaxf(v,0.f); v = v*v;
        rs[i][r] += v;
        const int lb = lrow*128 + ((((lcol>>4) ^ (lrow&7)))<<4) + (lcol&15);
        *(unsigned char*)(lds + lb) = to_fp8(v);
      }
    }
  }
  float* rd = rden + (long)bz*2048;
  #pragma unroll
  for (int i=0;i<4;i++){
    const int rbase = m0 + wm*64 + i*16 + kq*4;
    #pragma unroll
    for (int r=0;r<4;r++){
      float s = rs[i][r];
      s += __shfl_xor(s,1); s += __shfl_xor(s,2);
      s += __shfl_xor(s,4); s += __shfl_xor(s,8);
      if (lm==0) atomicAdd(rd + rbase + r, s);
    }
  }
  LGKM0();
  barrier_raw();
  unsigned char* obase = Wsc + (long)bz*2048*2048 + (long)m0*2048 + n0;
  #pragma unroll
  for (int it=0; it<4; ++it){
    const int g = (it*256 + tid)*16;
    const int row = g >> 7, off = g & 127;
    const int lb = row*128 + ((((off>>4) ^ (row&7)))<<4);
    uint4 val = *(const uint4*)(lds + lb);
    *(uint4*)(obase + (long)row*2048 + off) = val;
  }
}

// ---------------------------------------------------------------------------
// guv8: fp8 x fp8 UV GEMM (z2f8 x wuv8). Same skeleton/ledger as gsc8.
// u-half: sigmoid -> ub bf16 token-major. v-half: fp8 transposed -> v_fm.
// ---------------------------------------------------------------------------
__global__ void __launch_bounds__(256, 2)
guv8(const unsigned char* __restrict__ A, const unsigned char* __restrict__ Bw,
     bhalf* __restrict__ Ub, unsigned char* __restrict__ Vfm,
     const float* __restrict__ ubias, const float* __restrict__ vbias)
{
  constexpr int DBUF = 256*64;    // 16 KB
  __shared__ __align__(16) char lds[3*DBUF];   // 48 KB

  const int gx = gridDim.x, gy = gridDim.y;
  const int nwg = gx*gy;
  const int flat = blockIdx.y*gx + blockIdx.x;
  const int q8 = nwg>>3, r8 = nwg&7, xcd = flat&7, o8 = flat>>3;
  const int w = (xcd<r8 ? xcd*(q8+1) : r8*(q8+1)+(xcd-r8)*q8) + o8;
  const int bx = w % gx, by = w / gx;
  const int m0 = by*128, n0 = bx*128;
  const int K = 512;

  const int tid = threadIdx.x;
  const int wid = tid>>6, lane = tid&63;
  const int lm = lane&15, kq = lane>>4;
  const int wm = wid>>1, wn = wid&1;
  const int srow = lane>>2;
  const int csw8 = ((lane&3) ^ ((lane>>3)&3))*16;
  int coff[2];
  #pragma unroll
  for (int ksl=0; ksl<2; ksl++)
    coff[ksl] = ((((ksl*2 + (kq>>1)) ^ ((lm>>1)&3)))<<4) + ((kq&1)<<3);

  f32x4 acc[4][4];
  #pragma unroll
  for (int i=0;i<4;i++)
    #pragma unroll
    for (int j=0;j<4;j++) acc[i][j] = f32x4{0.f,0.f,0.f,0.f};

  auto stage = [&](int kt){                      // 4 loads/wave
    char* base = lds + (kt%3)*DBUF;
    const int k0 = kt*64;
    #pragma unroll
    for (int c=0;c<4;c++){
      const int r0 = c*64 + wid*16;
      char* d = base + r0*64;
      const unsigned char* g = (r0 < 128)
        ? A  + (long)(m0 + r0 + srow)*K + k0 + csw8
        : Bw + (long)(n0 + r0 - 128 + srow)*K + k0 + csw8;
      gl_lds16(g, d);
    }
  };

  long af[4][2], bf[4][2];
  auto readA = [&](int kt){
    char* base = lds + (kt%3)*DBUF;
    #pragma unroll
    for (int i2=0;i2<4;i2++)
      #pragma unroll
      for (int ksl=0;ksl<2;ksl++)
        af[i2][ksl] = *(const long*)(base + (wm*64 + i2*16 + lm)*64 + coff[ksl]);
  };
  auto readB = [&](int kt, int jh){
    char* base = lds + (kt%3)*DBUF;
    #pragma unroll
    for (int j2=0;j2<2;j2++)
      #pragma unroll
      for (int ksl=0;ksl<2;ksl++)
        bf[jh*2+j2][ksl] = *(const long*)(base + (128 + wn*64 + jh*32 + j2*16 + lm)*64 + coff[ksl]);
  };
  auto mfma16 = [&](int jh){
    __builtin_amdgcn_s_setprio(1);
    #pragma unroll
    for (int i2=0;i2<4;i2++)
      #pragma unroll
      for (int j2=0;j2<2;j2++)
        #pragma unroll
        for (int ksl=0;ksl<2;ksl++)
          acc[i2][jh*2+j2] = __builtin_amdgcn_mfma_f32_16x16x32_fp8_fp8(
              af[i2][ksl], bf[jh*2+j2][ksl], acc[i2][jh*2+j2], 0,0,0);
    __builtin_amdgcn_s_setprio(0);
  };

  const int NT = 8;
  stage(0); stage(1);                            // P=2 prologue: 8 loads
  for (int kt=0; kt<NT; ++kt){
    if (kt==NT-1) { VMW(0); } else { VMW(4); }
    barrier_raw();
    readA(kt); readB(kt,0);
    if (kt+2<NT) stage(kt+2);
    mfma16(0);
    readB(kt,1);
    mfma16(1);
  }
  barrier_raw();

  // ---- epilogue ----
  const bool uh = n0 < 1024;
  if (uh){
    #pragma unroll
    for (int i=0;i<4;i++){
      #pragma unroll
      for (int j=0;j<4;j++){
        const int lcol = wn*64 + j*16 + lm;
        #pragma unroll
        for (int r=0;r<4;r++){
          const int lrow = wm*64 + i*16 + kq*4 + r;
          float v = acc[i][j][r] + ubias[n0 + lcol];
          v = 1.f/(1.f + __expf(-v));
          const int cb = lcol*2;
          const int lb = lrow*256 + (((cb>>5) ^ ((lrow>>2)&3))<<5) + (cb&31);
          *(bhalf*)(lds + lb) = (bhalf)v;
        }
      }
    }
    LGKM0();
    barrier_raw();
    char* obase = (char*)Ub + 2*((long)m0*1024 + n0);
    #pragma unroll
    for (int it=0; it<8; ++it){
      const int g = (it*256 + tid)*16;
      const int row = g >> 8, off = g & 255;
      const int lb = row*256 + (((off>>5) ^ ((row>>2)&3))<<5) + (off&31);
      uint4 val = *(const uint4*)(lds + lb);
      *(uint4*)(obase + (long)row*2048 + off) = val;
    }
  } else {
    // fp8 transposed tile: row = v-channel (128B = 128 tokens), chunk^(row&7)
    #pragma unroll
    for (int i=0;i<4;i++){
      #pragma unroll
      for (int j=0;j<4;j++){
        const int lcol = wn*64 + j*16 + lm;
        #pragma unroll
        for (int r=0;r<4;r++){
          const int lrow = wm*64 + i*16 + kq*4 + r;
          float v = acc[i][j][r] + vbias[n0 - 1024 + lcol];
          const int lb = lcol*128 + ((((lrow>>4) ^ (lcol&7)))<<4) + (lrow&15);
          *(unsigned char*)(lds + lb) = to_fp8(v);
        }
      }
    }
    LGKM0();
    barrier_raw();
    unsigned char* vb = Vfm + ((long)(m0>>11)*1024*2048 + (long)(n0-1024)*2048 + (m0 & 2047));
    #pragma unroll
    for (int it=0; it<4; ++it){
      const int g = (it*256 + tid)*16;
      const int row = g >> 7, off = g & 127;
      const int lb = row*128 + ((((off>>4) ^ (row&7)))<<4);
      uint4 val = *(const uint4*)(lds + lb);
      *(uint4*)(vb + (long)row*2048 + off) = val;
    }
  }
}

// ---------------------------------------------------------------------------
// g4k8: fp8 x fp8 PV GEMM. 128x128 tile, ring-of-4 (64 KB), 3-ahead staging.
// Ledger: P=3, L=4 -> VMW(8)/4/0. uav = u * (wsc @ v_fm^T) / (den+eps).
// ---------------------------------------------------------------------------
__global__ void __launch_bounds__(256, 2)
g4k8(const unsigned char* __restrict__ A, const unsigned char* __restrict__ Bw,
     bhalf* __restrict__ Out,
     const bhalf* __restrict__ ub, const float* __restrict__ rden,
     int K, long sB, int rowshift)
{
  constexpr int DBUF = 256*64;    // 16 KB
  __shared__ __align__(16) char lds[4*DBUF];   // 64 KB

  const int gx = gridDim.x, gy = gridDim.y;
  const int nwg = gx*gy;
  const int flat = blockIdx.y*gx + blockIdx.x;
  const int q8 = nwg>>3, r8 = nwg&7, xcd = flat&7, o8 = flat>>3;
  const int w = (xcd<r8 ? xcd*(q8+1) : r8*(q8+1)+(xcd-r8)*q8) + o8;
  const int bx = w % gx, by = w / gx;
  const int m0 = by*128, n0 = bx*128;

  const unsigned char* Bb = Bw + (long)(m0>>rowshift)*sB;

  const int tid = threadIdx.x;
  const int wid = tid>>6, lane = tid&63;
  const int lm = lane&15, kq = lane>>4;
  const int wm = wid>>1, wn = wid&1;
  const int srow = lane>>2;
  const int csw8 = ((lane&3) ^ ((lane>>3)&3))*16;
  int coff[2];
  #pragma unroll
  for (int ksl=0; ksl<2; ksl++)
    coff[ksl] = ((((ksl*2 + (kq>>1)) ^ ((lm>>1)&3)))<<4) + ((kq&1)<<3);

  f32x4 acc[4][4];
  #pragma unroll
  for (int i=0;i<4;i++)
    #pragma unroll
    for (int j=0;j<4;j++) acc[i][j] = f32x4{0.f,0.f,0.f,0.f};

  auto stage = [&](int kt){                      // 4 loads/wave
    char* base = lds + (kt&3)*DBUF;
    const int k0 = kt*64;
    #pragma unroll
    for (int c=0;c<4;c++){
      const int r0 = c*64 + wid*16;
      char* d = base + r0*64;
      const unsigned char* g = (r0 < 128)
        ? A  + (long)(m0 + r0 + srow)*K + k0 + csw8
        : Bb + (long)(n0 + r0 - 128 + srow)*K + k0 + csw8;
      gl_lds16(g, d);
    }
  };

  long af[4][2], bf[4][2];
  auto readA = [&](int kt){
    char* base = lds + (kt&3)*DBUF;
    #pragma unroll
    for (int i2=0;i2<4;i2++)
      #pragma unroll
      for (int ksl=0;ksl<2;ksl++)
        af[i2][ksl] = *(const long*)(base + (wm*64 + i2*16 + lm)*64 + coff[ksl]);
  };
  auto readB = [&](int kt, int jh){
    char* base = lds + (kt&3)*DBUF;
    #pragma unroll
    for (int j2=0;j2<2;j2++)
      #pragma unroll
      for (int ksl=0;ksl<2;ksl++)
        bf[jh*2+j2][ksl] = *(const long*)(base + (128 + wn*64 + jh*32 + j2*16 + lm)*64 + coff[ksl]);
  };
  auto mfma16 = [&](int jh){
    __builtin_amdgcn_s_setprio(1);
    #pragma unroll
    for (int i2=0;i2<4;i2++)
      #pragma unroll
      for (int j2=0;j2<2;j2++)
        #pragma unroll
        for (int ksl=0;ksl<2;ksl++)
          acc[i2][jh*2+j2] = __builtin_amdgcn_mfma_f32_16x16x32_fp8_fp8(
              af[i2][ksl], bf[jh*2+j2][ksl], acc[i2][jh*2+j2], 0,0,0);
    __builtin_amdgcn_s_setprio(0);
  };

  const int NT = K>>6;
  stage(0); stage(1); stage(2);                  // P=3 prologue: 12 loads
  for (int kt=0; kt<NT; ++kt){
    if (kt==NT-1)      { VMW(0); }
    else if (kt==NT-2) { VMW(4); }
    else               { VMW(8); }
    barrier_raw();
    readA(kt); readB(kt,0);
    if (kt+3<NT) stage(kt+3);
    mfma16(0);
    readB(kt,1);
    mfma16(1);
  }
  barrier_raw();

  // ---- epilogue: u-gate + normalize -> bf16 C-tile -> coalesced ----
  char* obase = (char*)Out + 2*((long)m0*1024 + n0);
  #pragma unroll
  for (int i=0;i<4;i++){
    #pragma unroll
    for (int j=0;j<4;j++){
      const int lcol = wn*64 + j*16 + lm;
      #pragma unroll
      for (int r=0;r<4;r++){
        const int lrow = wm*64 + i*16 + kq*4 + r;
        const int rowg = m0 + lrow;
        float v = acc[i][j][r];
        float den = rden[rowg];
        v *= __builtin_amdgcn_rcpf(den + 1e-8f);
        v *= (float)ub[(long)rowg*1024 + n0 + lcol];
        const int cb = lcol*2;
        const int lb = lrow*256 + (((cb>>5) ^ ((lrow>>2)&3))<<5) + (cb&31);
        *(bhalf*)(lds + lb) = (bhalf)v;
      }
    }
  }
  LGKM0();
  barrier_raw();
  #pragma unroll
  for (int it=0; it<8; ++it){
    const int g = (it*256 + tid)*16;
    const int row = g >> 8, off = g & 255;
    const int lb = row*256 + (((off>>5) ^ ((row>>2)&3))<<5) + (off&31);
    uint4 val = *(const uint4*)(lds + lb);
    *(uint4*)(obase + (long)row*2048 + off) = val;
  }
}

// ---------------------------------------------------------------------------
// g4k: bf16 128x128 tile, 4 waves, BK=64, 2 dbufs, 2-ahead, VMW(8)/K-tile.
// For z2 (bf16 + fp8 dual out) / QK(fp8 out) / y / wqk2.
// ---------------------------------------------------------------------------
template<int EPI>
__global__ void __launch_bounds__(256, 2)
g4k(const bhalf* __restrict__ A, const bhalf* __restrict__ Bw,
    void* __restrict__ Out, void* __restrict__ Out2,
    const float* __restrict__ bias,
    const bhalf* __restrict__ auxb,
    const float* __restrict__ xadd,
    int M, int N, int K)
{
  constexpr int KSL = 256*64;     // 16 KB plane: A rows 0-127, B rows 128-255
  constexpr int DBUF = 2*KSL;     // 32 KB
  __shared__ __align__(16) char lds[2*DBUF];   // 64 KB

  const int gx = gridDim.x, gy = gridDim.y;
  const int nwg = gx*gy;
  const int flat = blockIdx.y*gx + blockIdx.x;
  const int q8 = nwg>>3, r8 = nwg&7, xcd = flat&7, o8 = flat>>3;
  const int w = (xcd<r8 ? xcd*(q8+1) : r8*(q8+1)+(xcd-r8)*q8) + o8;
  const int bx = w % gx, by = w / gx;
  const int m0 = by*128, n0 = bx*128;

  const int tid = threadIdx.x;
  const int wid = tid>>6, lane = tid&63;
  const int lm = lane&15, kq = lane>>4;
  const int wm = wid>>1, wn = wid&1;
  const int srow = lane>>2;
  const int csw = ((lane&3) ^ ((lane>>3)&3))*8;
  const int kqs = kq ^ ((lm>>1)&3);

  f32x4 acc[4][4];
  #pragma unroll
  for (int i=0;i<4;i++)
    #pragma unroll
    for (int j=0;j<4;j++) acc[i][j] = f32x4{0.f,0.f,0.f,0.f};

  auto stage = [&](int kt){                      // 8 loads/wave
    char* base = lds + (kt&1)*DBUF;
    const int k0 = kt*64;
    #pragma unroll
    for (int c=0;c<4;c++){
      const int r0 = c*64 + wid*16;
      #pragma unroll
      for (int ksl=0; ksl<2; ksl++){
        bhalf* d = (bhalf*)(base + ksl*KSL + r0*64);
        const bhalf* g = (r0 < 128)
          ? A  + (long)(m0 + r0 + srow)*K + k0 + ksl*32 + csw
          : Bw + (long)(n0 + r0 - 128 + srow)*K + k0 + ksl*32 + csw;
        gl_lds16(g, d);
      }
    }
  };

  bhalf8 af[4][2], bf[4][2];
  auto readA = [&](int kt){
    char* base = lds + (kt&1)*DBUF;
    #pragma unroll
    for (int i2=0;i2<4;i2++)
      #pragma unroll
      for (int ksl=0;ksl<2;ksl++)
        af[i2][ksl] = *(const bhalf8*)(base + ksl*KSL + (wm*64 + i2*16 + lm)*64 + kqs*16);
  };
  auto readB = [&](int kt, int jh){
    char* base = lds + (kt&1)*DBUF;
    #pragma unroll
    for (int j2=0;j2<2;j2++)
      #pragma unroll
      for (int ksl=0;ksl<2;ksl++)
        bf[jh*2+j2][ksl] = *(const bhalf8*)(base + ksl*KSL + (128 + wn*64 + jh*32 + j2*16 + lm)*64 + kqs*16);
  };
  auto mfma16 = [&](int jh){
    __builtin_amdgcn_s_setprio(1);
    #pragma unroll
    for (int i2=0;i2<4;i2++)
      #pragma unroll
      for (int j2=0;j2<2;j2++)
        #pragma unroll
        for (int ksl=0;ksl<2;ksl++)
          acc[i2][jh*2+j2] = __builtin_amdgcn_mfma_f32_16x16x32_bf16(
              af[i2][ksl], bf[jh*2+j2][ksl], acc[i2][jh*2+j2], 0,0,0);
    __builtin_amdgcn_s_setprio(0);
  };

  const int NT = K>>6;
  stage(0); stage(1);
  for (int kt=0; kt<NT; ++kt){
    if (kt==NT-1) { VMW(0); } else { VMW(8); }
    barrier_raw();
    readA(kt); readB(kt,0);
    mfma16(0);
    barrier_raw();
    readB(kt,1);
    if (kt+2<NT) stage(kt+2);
    mfma16(1);
  }
  barrier_raw();

  // ---- epilogues ----
  if constexpr (EPI==EPI_Y){
    #pragma unroll
    for (int i=0;i<4;i++){
      #pragma unroll
      for (int j=0;j<4;j++){
        const int lcol = wn*64 + j*16 + lm;
        #pragma unroll
        for (int r=0;r<4;r++){
          const int lrow = wm*64 + i*16 + kq*4 + r;
          float v = acc[i][j][r] + bias[n0 + lcol];
          const int lb = lcol*512 + 4*(lrow ^ ((lcol&15)<<2));
          *(float*)(lds + lb) = v;
        }
      }
    }
    LGKM0();
    barrier_raw();
    const int b = m0 >> 11, nb = m0 & 2047;
    float* ob = (float*)Out + ((long)b*512 + n0)*2048 + nb;
    const float* xb = xadd + ((long)b*512 + n0)*2048 + nb;
    #pragma unroll
    for (int it=0; it<16; ++it){
      const int g = (it*256 + tid)*16;
      const int row = g >> 9, off = g & 511;
      const int t0 = off >> 2;
      const int s = (row&15)<<2;
      f32x4 vv = *(const f32x4*)(lds + row*512 + 4*(t0^s));
      f32x4 xx = *(const f32x4*)(xb + (long)row*2048 + t0);
      *(f32x4*)(ob + (long)row*2048 + t0) = vv + xx;
    }
  } else if constexpr (EPI==EPI_QK){
    // fp8 q/k output: bias then e4m3; 128B-row fp8 C-tile
    bool qh = n0 < 512;
    unsigned char* obase = (unsigned char*)(qh?Out:Out2) + (long)m0*512 + (n0 - (qh?0:512));
    #pragma unroll
    for (int i=0;i<4;i++){
      #pragma unroll
      for (int j=0;j<4;j++){
        const int lcol = wn*64 + j*16 + lm;
        #pragma unroll
        for (int r=0;r<4;r++){
          const int lrow = wm*64 + i*16 + kq*4 + r;
          float v = acc[i][j][r] + bias[n0 + lcol];
          const int lb = lrow*128 + ((((lcol>>4) ^ (lrow&7)))<<4) + (lcol&15);
          *(unsigned char*)(lds + lb) = to_fp8(v);
        }
      }
    }
    LGKM0();
    barrier_raw();
    #pragma unroll
    for (int it=0; it<4; ++it){
      const int g = (it*256 + tid)*16;
      const int row = g >> 7, off = g & 127;
      const int lb = row*128 + ((((off>>4) ^ (row&7)))<<4);
      uint4 val = *(const uint4*)(lds + lb);
      *(uint4*)(obase + (long)row*512 + off) = val;
    }
  } else {
    // EPI_Z2 (bf16 + fp8 dual) / EPI_ST (bf16 only)
    char* obase = (char*)Out + 2*((long)m0*N + n0);
    const int ldb = N*2;
    #pragma unroll
    for (int i=0;i<4;i++){
      #pragma unroll
      for (int j=0;j<4;j++){
        const int lcol = wn*64 + j*16 + lm;
        #pragma unroll
        for (int r=0;r<4;r++){
          const int lrow = wm*64 + i*16 + kq*4 + r;
          float v = acc[i][j][r];
          if constexpr (EPI==EPI_Z2)
            v += (float)auxb[(long)(m0+lrow)*N + n0 + lcol];
          if constexpr (EPI==EPI_BIAS)
            v += bias[n0 + lcol];
          const int cb = lcol*2;
          const int lb = lrow*256 + (((cb>>5) ^ ((lrow>>2)&3))<<5) + (cb&31);
          *(bhalf*)(lds + lb) = (bhalf)v;
          if constexpr (EPI==EPI_Z2){
            const int lb2 = 32768 + lrow*128 + ((((lcol>>4) ^ (lrow&7)))<<4) + (lcol&15);
            *(unsigned char*)(lds + lb2) = to_fp8(v);
          }
        }
      }
    }
    LGKM0();
    barrier_raw();
    #pragma unroll
    for (int it=0; it<8; ++it){
      const int g = (it*256 + tid)*16;
      const int row = g >> 8, off = g & 255;
      const int lb = row*256 + (((off>>5) ^ ((row>>2)&3))<<5) + (off&31);
      uint4 val = *(const uint4*)(lds + lb);
      *(uint4*)(obase + (long)row*ldb + off) = val;
    }
    if constexpr (EPI==EPI_Z2){
      unsigned char* o8 = (unsigned char*)Out2 + (long)m0*N + n0;
      #pragma unroll
      for (int it=0; it<4; ++it){
        const int g = (it*256 + tid)*16;
        const int row = g >> 7, off = g & 127;
        const int lb = 32768 + row*128 + ((((off>>4) ^ (row&7)))<<4);
        uint4 val = *(const uint4*)(lds + lb);
        *(uint4*)(o8 + (long)row*N + off) = val;
      }
    }
  }
  (void)M; (void)xadd; (void)bias; (void)auxb;
}

// ---------------------------------------------------------------------------
struct CvtArgs { const float* src[5]; bhalf* dst[5]; int n[5]; };
__global__ void cvt_multi(CvtArgs a) {
  int seg = blockIdx.y;
  int i = (blockIdx.x*256 + threadIdx.x)*4;
  if (i >= a.n[seg]) return;
  float4 f = *(const float4*)(a.src[seg] + i);
  bhalf* d = a.dst[seg] + i;
  d[0]=(bhalf)f.x; d[1]=(bhalf)f.y; d[2]=(bhalf)f.z; d[3]=(bhalf)f.w;
}

__global__ void cvt_fp8(const float* __restrict__ src, unsigned char* __restrict__ dst, int n){
  int i = (blockIdx.x*256 + threadIdx.x)*4;
  if (i >= n) return;
  float4 f = *(const float4*)(src + i);
  dst[i+0]=to_fp8(f.x); dst[i+1]=to_fp8(f.y);
  dst[i+2]=to_fp8(f.z); dst[i+3]=to_fp8(f.w);
}

// bf16 transpose: in [R,C] -> out [C,R]
__global__ void transpose_bf16(const bhalf* __restrict__ in, bhalf* __restrict__ out,
                               int R, int C) {
  __shared__ bhalf t[32][33];
  int r0 = blockIdx.x*32, c0 = blockIdx.y*32;
  int tx = threadIdx.x, ty = threadIdx.y;
  #pragma unroll
  for (int r=0;r<4;r++)
    t[ty + r*8][tx] = in[(long)(r0 + ty + r*8)*C + c0 + tx];
  __syncthreads();
  #pragma unroll
  for (int r=0;r<4;r++)
    out[(long)(c0 + ty + r*8)*R + r0 + tx] = t[tx][ty + r*8];
}

// bq[row] = sum_m wqk[row][m] * hb[m]
__global__ void qk_bias(const bhalf* __restrict__ wqk, const float* __restrict__ hb,
                        float* __restrict__ bq){
  int row = blockIdx.x*4 + (threadIdx.x>>6);
  int lane = threadIdx.x & 63;
  const bhalf* p = wqk + (long)row*512;
  float s = 0.f;
  #pragma unroll
  for (int j=0;j<8;j++) s += (float)p[lane*8+j] * hb[lane*8+j];
  for (int off=32; off; off>>=1) s += __shfl_xor(s, off);
  if (lane==0) bq[row] = s;
}

__global__ void gn_part(const float* __restrict__ x, float* __restrict__ ps, float* __restrict__ pss) {
  int b = blockIdx.y;
  const float* xb = x + (long)b*(512*2048);
  float s=0.f, ss=0.f;
  #pragma unroll
  for (int it=0; it<8; it++){
    int idx = ((it*128 + blockIdx.x)*256 + threadIdx.x)*4;
    float4 f = *(const float4*)(xb + idx);
    s  += f.x+f.y+f.z+f.w;
    ss += f.x*f.x+f.y*f.y+f.z*f.z+f.w*f.w;
  }
  for (int off=32; off; off>>=1){ s += __shfl_xor(s,off); ss += __shfl_xor(ss,off); }
  __shared__ float ls[4], lss[4];
  int wid = threadIdx.x>>6, lane = threadIdx.x&63;
  if (lane==0){ ls[wid]=s; lss[wid]=ss; }
  __syncthreads();
  if (threadIdx.x==0){
    s = ls[0]+ls[1]+ls[2]+ls[3]; ss = lss[0]+lss[1]+lss[2]+lss[3];
    ps[b*128 + blockIdx.x] = s; pss[b*128 + blockIdx.x] = ss;
  }
}

__global__ void gn_final(const float* __restrict__ ps, const float* __restrict__ pss,
                         float* __restrict__ stats) {
  int b = blockIdx.x;
  float s = ps[b*128 + threadIdx.x], ss = pss[b*128 + threadIdx.x];
  for (int off=32; off; off>>=1){ s += __shfl_xor(s,off); ss += __shfl_xor(ss,off); }
  __shared__ float l0[2], l1[2];
  int wid = threadIdx.x>>6, lane = threadIdx.x&63;
  if (lane==0){ l0[wid]=s; l1[wid]=ss; }
  __syncthreads();
  if (threadIdx.x==0){
    s = l0[0]+l0[1]; ss = l1[0]+l1[1];
    float mean = s*(1.f/1048576.f);
    float var  = ss*(1.f/1048576.f) - mean*mean;
    stats[b*2] = mean; stats[b*2+1] = rsqrtf(var + 1e-8f);
  }
}

__global__ void norm_dw_T(const float* __restrict__ x, const float* __restrict__ stats,
                          const float* __restrict__ dw_w,
                          bhalf* __restrict__ zT, bhalf* __restrict__ dwT) {
  int b = blockIdx.z, n0 = blockIdx.x*32, c0 = blockIdx.y*32;
  float mean = stats[b*2], rstd = stats[b*2+1];
  __shared__ float zs[32][35];
  int tx = threadIdx.x, ty = threadIdx.y;
  #pragma unroll
  for (int r=0;r<4;r++){
    int c = c0 + ty + r*8;
    for (int cc=tx; cc<34; cc+=32){
      int n = n0 - 1 + cc;
      float v = 0.f;
      if (n>=0 && n<2048) v = (x[((long)b*512 + c)*2048 + n] - mean)*rstd;
      zs[ty + r*8][cc] = v;
    }
  }
  __syncthreads();
  float w0 = dw_w[(c0+tx)*3+0], w1 = dw_w[(c0+tx)*3+1], w2 = dw_w[(c0+tx)*3+2];
  #pragma unroll
  for (int r=0;r<4;r++){
    int ln = ty + r*8;
    float z = zs[tx][ln+1];
    float d = w0*zs[tx][ln] + w1*zs[tx][ln+1] + w2*zs[tx][ln+2];
    long o = ((long)b*2048 + n0 + ln)*512 + c0 + tx;
    zT[o] = (bhalf)z; dwT[o] = (bhalf)d;
  }
}

// ---------------------------------------------------------------------------
extern "C" void kernel_launch(void* const* d_in, const int* in_sizes, int n_in,
                              void* d_out, int out_size, void* d_ws, size_t ws_size,
                              hipStream_t stream) {
  (void)in_sizes; (void)n_in; (void)out_size; (void)ws_size;
  const float* x    = (const float*)d_in[0];
  const float* dw_w = (const float*)d_in[1];
  const float* pw_w = (const float*)d_in[2];
  const float* u_w  = (const float*)d_in[3];
  const float* u_b  = (const float*)d_in[4];
  const float* v_w  = (const float*)d_in[5];
  const float* v_b  = (const float*)d_in[6];
  const float* h_w  = (const float*)d_in[7];
  const float* h_b  = (const float*)d_in[8];
  const float* q_w  = (const float*)d_in[9];
  const float* k_w  = (const float*)d_in[10];
  const float* o_w  = (const float*)d_in[11];
  const float* o_b  = (const float*)d_in[12];
  float* out = (float*)d_out;

  char* ws = (char*)d_ws;
  size_t off = 0;
  auto alloc = [&](size_t bytes) -> void* {
    void* p = ws + off; off = (off + bytes + 255) & ~(size_t)255; return p;
  };

  float* ps    = (float*)alloc(4*128*4);
  float* pss   = (float*)alloc(4*128*4);
  float* stats = (float*)alloc(4*2*4);
  float* rden  = (float*)alloc(4*2048*4);
  float* bq    = (float*)alloc(1024*4);
  bhalf* wb_pw = (bhalf*)alloc(512*512*2);
  unsigned char* wuv8 = (unsigned char*)alloc((size_t)2048*512);  // fp8 u|v
  bhalf* wb_h  = (bhalf*)alloc(512*512*2);
  bhalf* hwT   = (bhalf*)alloc(512*512*2);
  bhalf* wb_qk = (bhalf*)alloc((size_t)1024*512*2);
  bhalf* wqk2  = (bhalf*)alloc((size_t)1024*512*2);
  bhalf* wb_o  = (bhalf*)alloc((size_t)512*1024*2);
  const size_t ACT = (size_t)4*2048*512;
  bhalf* zT   = (bhalf*)alloc(ACT*2);
  bhalf* dwT  = (bhalf*)alloc(ACT*2);
  bhalf* z2T  = (bhalf*)alloc(ACT*2);
  unsigned char* z2f8 = (unsigned char*)alloc(ACT);                 // fp8 z2
  bhalf* ub   = (bhalf*)alloc(ACT*2*2);     // [B,N,1024]
  unsigned char* v_fm = (unsigned char*)alloc((size_t)4*1024*2048); // fp8
  unsigned char* wsc  = (unsigned char*)alloc((size_t)4*2048*2048); // fp8
  unsigned char* qb8  = (unsigned char*)alloc(ACT);                 // fp8 q
  unsigned char* kb8  = (unsigned char*)alloc(ACT);                 // fp8 k
  bhalf* uav  = (bhalf*)alloc(ACT*2*2);

  // 0. zero attention-denominator accumulators
  hipMemsetAsync(rden, 0, 4*2048*4, stream);

  // 1. weights -> bf16 (pw, h, q, k, o) and fp8 (u|v)
  CvtArgs ca;
  ca.src[0]=pw_w; ca.dst[0]=wb_pw;           ca.n[0]=512*512;
  ca.src[1]=h_w;  ca.dst[1]=wb_h;            ca.n[1]=512*512;
  ca.src[2]=q_w;  ca.dst[2]=wb_qk;           ca.n[2]=512*512;
  ca.src[3]=k_w;  ca.dst[3]=wb_qk+512*512;   ca.n[3]=512*512;
  ca.src[4]=o_w;  ca.dst[4]=wb_o;            ca.n[4]=512*1024;
  cvt_multi<<<dim3(512,5), 256, 0, stream>>>(ca);
  cvt_fp8<<<dim3(512), 256, 0, stream>>>(u_w, wuv8,          1024*512);
  cvt_fp8<<<dim3(512), 256, 0, stream>>>(v_w, wuv8+1024*512, 1024*512);

  // 2. fold h into q/k: wqk2 = [q_w;k_w] @ h_w, bq = [q_w;k_w] @ h_b
  transpose_bf16<<<dim3(16,16), dim3(32,8), 0, stream>>>(wb_h, hwT, 512, 512);
  g4k<EPI_ST><<<dim3(4,8,1), 256, 0, stream>>>(wb_qk, hwT, wqk2, nullptr,
      nullptr, nullptr, nullptr, 1024, 512, 512);
  qk_bias<<<dim3(256), 256, 0, stream>>>(wb_qk, h_b, bq);

  // 3-4. GroupNorm stats
  gn_part<<<dim3(128,4), 256, 0, stream>>>(x, ps, pss);
  gn_final<<<dim3(4), 128, 0, stream>>>(ps, pss, stats);

  // 5. normalize + dw conv + transpose -> zT, dwT
  norm_dw_T<<<dim3(64,16,4), dim3(32,8), 0, stream>>>(x, stats, dw_w, zT, dwT);

  const float iscl = 0.044194173824159216f;   // 1/sqrt(512)
  // 6. z2 = z + dw @ pw^T  (bf16 -> z2T, fp8 -> z2f8)
  g4k<EPI_Z2><<<dim3(4,64,1), 256, 0, stream>>>(dwT, wb_pw, z2T, z2f8,
      nullptr, zT, nullptr, 8192, 512, 512);
  // 7. [u|v] = z2f8 @ wuv8^T + b  (fp8 MFMA; u->ub bf16, v->v_fm fp8)
  guv8<<<dim3(16,64,1), 256, 0, stream>>>(z2f8, wuv8, ub, v_fm, u_b, v_b);
  // 8. [q|k](fp8) = z2 @ wqk2^T + bq     (bf16 MFMA, h folded away)
  g4k<EPI_QK><<<dim3(8,64,1), 256, 0, stream>>>(z2T, wqk2, qb8, kb8,
      bq, nullptr, nullptr, 8192, 1024, 512);
  // 9. wsc(fp8) = relu(q@k^T * scale)^2 + fused row-sum atomics (fp8 MFMA)
  gsc8<<<dim3(16,16,4), 256, 0, stream>>>(qb8, kb8, wsc, rden, iscl);
  // 10. uav = u * (wsc @ v_fm^T) / (den+eps)   (fp8 MFMA, batch in M)
  g4k8<<<dim3(8,64,1), 256, 0, stream>>>(wsc, v_fm, uav, ub, rden,
      2048, (long)1024*2048, 11);
  // 11. out = x + (uav @ o_w^T + o_b)^T  (fused residual add)
  g4k<EPI_Y><<<dim3(4,64,1), 256, 0, stream>>>(uav, wb_o, out, nullptr,
      o_b, nullptr, x, 8192, 512, 1024);
}

// Round 20
// 171.113 us; speedup vs baseline: 1.1208x; 1.0101x over previous
//
#include <hip/hip_runtime.h>
#include <hip/hip_bf16.h>
#include <cstdint>

typedef __bf16 bhalf;
typedef __bf16 bhalf8 __attribute__((ext_vector_type(8)));
typedef float f32x4 __attribute__((ext_vector_type(4)));

enum { EPI_Z2=0, EPI_ST=7 };

// async global->LDS, 16B per lane, LDS dest = wave-uniform base + lane*16
__device__ __forceinline__ void gl_lds16(const void* g, void* l) {
  __builtin_amdgcn_global_load_lds(
      (const __attribute__((address_space(1))) unsigned int*)g,
      (__attribute__((address_space(3))) unsigned int*)l,
      16, 0, 0);
}
__device__ __forceinline__ void barrier_raw() { asm volatile("s_barrier" ::: "memory"); }
#define VMW(n)  asm volatile("s_waitcnt vmcnt(" #n ")" ::: "memory")
#define LGKM0() asm volatile("s_waitcnt lgkmcnt(0)" ::: "memory")

// float -> fp8 e4m3 (OCP on gfx950) via HW cvt
__device__ __forceinline__ unsigned char to_fp8(float v){
  return (unsigned char)(__builtin_amdgcn_cvt_pk_fp8_f32(v, v, 0, false) & 0xff);
}

// Staging bank swizzle (verified R4-R19, SQ_LDS_BANK_CONFLICT == 0): 16B chunk
// c of a 64B row r holds global chunk c ^ ((r>>1)&3). Write: pre-swizzled
// GLOBAL source, linear LDS dest (rule #21); read side applies same XOR.
// bf16 C-tile (256B rows): 32B chunk ^ ((row>>2)&3).
// fp8 C-tile 128B rows: 16B chunk ^ (row&7).
// vmcnt ledger rule (R17): P prologue tiles x L loads, stage-at-(kt+P) =>
// steady VMW((P-1)*L); tail decrements by L.
// fp8 subnormal rule (R20): weights ~0.02 sit in e4m3 subnormal range; scale
// x16 at conversion and fold 1/16 (or 1/256 for q*k) into the consumer.

// ---------------------------------------------------------------------------
// gsc8: fp8 x fp8 score GEMM. 128x128, ring-of-3 (48 KB), P=2 -> VMW(4)/0.
// wsc(fp8) = relu(q@k^T * scale)^2 + fused row-sum atomics. scale = iscl/256.
// ---------------------------------------------------------------------------
__global__ void __launch_bounds__(256, 2)
gsc8(const unsigned char* __restrict__ Q, const unsigned char* __restrict__ Kp,
     unsigned char* __restrict__ Wsc, float* __restrict__ rden, float scale)
{
  constexpr int DBUF = 256*64;    // 16 KB: A rows 0-127, B rows 128-255
  __shared__ __align__(16) char lds[3*DBUF];   // 48 KB

  const int gx = gridDim.x, gy = gridDim.y;
  const int nwg = gx*gy;
  const int flat = blockIdx.y*gx + blockIdx.x;
  const int q8 = nwg>>3, r8 = nwg&7, xcd = flat&7, o8 = flat>>3;
  const int w = (xcd<r8 ? xcd*(q8+1) : r8*(q8+1)+(xcd-r8)*q8) + o8;
  const int bx = w % gx, by = w / gx;
  const int m0 = by*128, n0 = bx*128;
  const int bz = blockIdx.z;
  const int K = 512;

  const unsigned char* Ab = Q  + (long)bz*2048*512;
  const unsigned char* Bb = Kp + (long)bz*2048*512;

  const int tid = threadIdx.x;
  const int wid = tid>>6, lane = tid&63;
  const int lm = lane&15, kq = lane>>4;
  const int wm = wid>>1, wn = wid&1;
  const int srow = lane>>2;
  const int csw8 = ((lane&3) ^ ((lane>>3)&3))*16;
  int coff[2];
  #pragma unroll
  for (int ksl=0; ksl<2; ksl++)
    coff[ksl] = ((((ksl*2 + (kq>>1)) ^ ((lm>>1)&3)))<<4) + ((kq&1)<<3);

  f32x4 acc[4][4];
  #pragma unroll
  for (int i=0;i<4;i++)
    #pragma unroll
    for (int j=0;j<4;j++) acc[i][j] = f32x4{0.f,0.f,0.f,0.f};

  auto stage = [&](int kt){                      // 4 loads/wave
    char* base = lds + (kt%3)*DBUF;
    const int k0 = kt*64;
    #pragma unroll
    for (int c=0;c<4;c++){
      const int r0 = c*64 + wid*16;
      char* d = base + r0*64;
      const unsigned char* g = (r0 < 128)
        ? Ab + (long)(m0 + r0 + srow)*K + k0 + csw8
        : Bb + (long)(n0 + r0 - 128 + srow)*K + k0 + csw8;
      gl_lds16(g, d);
    }
  };

  long af[4][2], bf[4][2];
  auto readA = [&](int kt){
    char* base = lds + (kt%3)*DBUF;
    #pragma unroll
    for (int i2=0;i2<4;i2++)
      #pragma unroll
      for (int ksl=0;ksl<2;ksl++)
        af[i2][ksl] = *(const long*)(base + (wm*64 + i2*16 + lm)*64 + coff[ksl]);
  };
  auto readB = [&](int kt, int jh){
    char* base = lds + (kt%3)*DBUF;
    #pragma unroll
    for (int j2=0;j2<2;j2++)
      #pragma unroll
      for (int ksl=0;ksl<2;ksl++)
        bf[jh*2+j2][ksl] = *(const long*)(base + (128 + wn*64 + jh*32 + j2*16 + lm)*64 + coff[ksl]);
  };
  auto mfma16 = [&](int jh){
    __builtin_amdgcn_s_setprio(1);
    #pragma unroll
    for (int i2=0;i2<4;i2++)
      #pragma unroll
      for (int j2=0;j2<2;j2++)
        #pragma unroll
        for (int ksl=0;ksl<2;ksl++)
          acc[i2][jh*2+j2] = __builtin_amdgcn_mfma_f32_16x16x32_fp8_fp8(
              af[i2][ksl], bf[jh*2+j2][ksl], acc[i2][jh*2+j2], 0,0,0);
    __builtin_amdgcn_s_setprio(0);
  };

  const int NT = 8;
  stage(0); stage(1);                            // P=2 prologue
  for (int kt=0; kt<NT; ++kt){
    if (kt==NT-1) { VMW(0); } else { VMW(4); }
    barrier_raw();
    readA(kt); readB(kt,0);
    if (kt+2<NT) stage(kt+2);
    mfma16(0);
    readB(kt,1);
    mfma16(1);
  }
  barrier_raw();

  // ---- epilogue: relu^2 + row-sums + fp8 C-tile (128B rows) ----
  float rs[4][4];
  #pragma unroll
  for (int i=0;i<4;i++)
    #pragma unroll
    for (int r=0;r<4;r++) rs[i][r]=0.f;
  #pragma unroll
  for (int i=0;i<4;i++){
    #pragma unroll
    for (int j=0;j<4;j++){
      const int lcol = wn*64 + j*16 + lm;
      #pragma unroll
      for (int r=0;r<4;r++){
        const int lrow = wm*64 + i*16 + kq*4 + r;
        float v = acc[i][j][r];
        v *= scale; v = fmaxf(v,0.f); v = v*v;
        rs[i][r] += v;
        const int lb = lrow*128 + ((((lcol>>4) ^ (lrow&7)))<<4) + (lcol&15);
        *(unsigned char*)(lds + lb) = to_fp8(v);
      }
    }
  }
  float* rd = rden + (long)bz*2048;
  #pragma unroll
  for (int i=0;i<4;i++){
    const int rbase = m0 + wm*64 + i*16 + kq*4;
    #pragma unroll
    for (int r=0;r<4;r++){
      float s = rs[i][r];
      s += __shfl_xor(s,1); s += __shfl_xor(s,2);
      s += __shfl_xor(s,4); s += __shfl_xor(s,8);
      if (lm==0) atomicAdd(rd + rbase + r, s);
    }
  }
  LGKM0();
  barrier_raw();
  unsigned char* obase = Wsc + (long)bz*2048*2048 + (long)m0*2048 + n0;
  #pragma unroll
  for (int it=0; it<4; ++it){
    const int g = (it*256 + tid)*16;
    const int row = g >> 7, off = g & 127;
    const int lb = row*128 + ((((off>>4) ^ (row&7)))<<4);
    uint4 val = *(const uint4*)(lds + lb);
    *(uint4*)(obase + (long)row*2048 + off) = val;
  }
}

// ---------------------------------------------------------------------------
// guv8: fp8 x fp8 UV GEMM. Skeleton = gsc8 (P=2, VMW(4)/0).
// u-half: sigmoid -> ub bf16. v-half: fp8 transposed -> v_fm.
// ---------------------------------------------------------------------------
__global__ void __launch_bounds__(256, 2)
guv8(const unsigned char* __restrict__ A, const unsigned char* __restrict__ Bw,
     bhalf* __restrict__ Ub, unsigned char* __restrict__ Vfm,
     const float* __restrict__ ubias, const float* __restrict__ vbias)
{
  constexpr int DBUF = 256*64;
  __shared__ __align__(16) char lds[3*DBUF];   // 48 KB

  const int gx = gridDim.x, gy = gridDim.y;
  const int nwg = gx*gy;
  const int flat = blockIdx.y*gx + blockIdx.x;
  const int q8 = nwg>>3, r8 = nwg&7, xcd = flat&7, o8 = flat>>3;
  const int w = (xcd<r8 ? xcd*(q8+1) : r8*(q8+1)+(xcd-r8)*q8) + o8;
  const int bx = w % gx, by = w / gx;
  const int m0 = by*128, n0 = bx*128;
  const int K = 512;

  const int tid = threadIdx.x;
  const int wid = tid>>6, lane = tid&63;
  const int lm = lane&15, kq = lane>>4;
  const int wm = wid>>1, wn = wid&1;
  const int srow = lane>>2;
  const int csw8 = ((lane&3) ^ ((lane>>3)&3))*16;
  int coff[2];
  #pragma unroll
  for (int ksl=0; ksl<2; ksl++)
    coff[ksl] = ((((ksl*2 + (kq>>1)) ^ ((lm>>1)&3)))<<4) + ((kq&1)<<3);

  f32x4 acc[4][4];
  #pragma unroll
  for (int i=0;i<4;i++)
    #pragma unroll
    for (int j=0;j<4;j++) acc[i][j] = f32x4{0.f,0.f,0.f,0.f};

  auto stage = [&](int kt){
    char* base = lds + (kt%3)*DBUF;
    const int k0 = kt*64;
    #pragma unroll
    for (int c=0;c<4;c++){
      const int r0 = c*64 + wid*16;
      char* d = base + r0*64;
      const unsigned char* g = (r0 < 128)
        ? A  + (long)(m0 + r0 + srow)*K + k0 + csw8
        : Bw + (long)(n0 + r0 - 128 + srow)*K + k0 + csw8;
      gl_lds16(g, d);
    }
  };

  long af[4][2], bf[4][2];
  auto readA = [&](int kt){
    char* base = lds + (kt%3)*DBUF;
    #pragma unroll
    for (int i2=0;i2<4;i2++)
      #pragma unroll
      for (int ksl=0;ksl<2;ksl++)
        af[i2][ksl] = *(const long*)(base + (wm*64 + i2*16 + lm)*64 + coff[ksl]);
  };
  auto readB = [&](int kt, int jh){
    char* base = lds + (kt%3)*DBUF;
    #pragma unroll
    for (int j2=0;j2<2;j2++)
      #pragma unroll
      for (int ksl=0;ksl<2;ksl++)
        bf[jh*2+j2][ksl] = *(const long*)(base + (128 + wn*64 + jh*32 + j2*16 + lm)*64 + coff[ksl]);
  };
  auto mfma16 = [&](int jh){
    __builtin_amdgcn_s_setprio(1);
    #pragma unroll
    for (int i2=0;i2<4;i2++)
      #pragma unroll
      for (int j2=0;j2<2;j2++)
        #pragma unroll
        for (int ksl=0;ksl<2;ksl++)
          acc[i2][jh*2+j2] = __builtin_amdgcn_mfma_f32_16x16x32_fp8_fp8(
              af[i2][ksl], bf[jh*2+j2][ksl], acc[i2][jh*2+j2], 0,0,0);
    __builtin_amdgcn_s_setprio(0);
  };

  const int NT = 8;
  stage(0); stage(1);
  for (int kt=0; kt<NT; ++kt){
    if (kt==NT-1) { VMW(0); } else { VMW(4); }
    barrier_raw();
    readA(kt); readB(kt,0);
    if (kt+2<NT) stage(kt+2);
    mfma16(0);
    readB(kt,1);
    mfma16(1);
  }
  barrier_raw();

  const bool uh = n0 < 1024;
  if (uh){
    #pragma unroll
    for (int i=0;i<4;i++){
      #pragma unroll
      for (int j=0;j<4;j++){
        const int lcol = wn*64 + j*16 + lm;
        #pragma unroll
        for (int r=0;r<4;r++){
          const int lrow = wm*64 + i*16 + kq*4 + r;
          float v = acc[i][j][r] + ubias[n0 + lcol];
          v = 1.f/(1.f + __expf(-v));
          const int cb = lcol*2;
          const int lb = lrow*256 + (((cb>>5) ^ ((lrow>>2)&3))<<5) + (cb&31);
          *(bhalf*)(lds + lb) = (bhalf)v;
        }
      }
    }
    LGKM0();
    barrier_raw();
    char* obase = (char*)Ub + 2*((long)m0*1024 + n0);
    #pragma unroll
    for (int it=0; it<8; ++it){
      const int g = (it*256 + tid)*16;
      const int row = g >> 8, off = g & 255;
      const int lb = row*256 + (((off>>5) ^ ((row>>2)&3))<<5) + (off&31);
      uint4 val = *(const uint4*)(lds + lb);
      *(uint4*)(obase + (long)row*2048 + off) = val;
    }
  } else {
    #pragma unroll
    for (int i=0;i<4;i++){
      #pragma unroll
      for (int j=0;j<4;j++){
        const int lcol = wn*64 + j*16 + lm;
        #pragma unroll
        for (int r=0;r<4;r++){
          const int lrow = wm*64 + i*16 + kq*4 + r;
          float v = acc[i][j][r] + vbias[n0 - 1024 + lcol];
          const int lb = lcol*128 + ((((lrow>>4) ^ (lcol&7)))<<4) + (lrow&15);
          *(unsigned char*)(lds + lb) = to_fp8(v);
        }
      }
    }
    LGKM0();
    barrier_raw();
    unsigned char* vb = Vfm + ((long)(m0>>11)*1024*2048 + (long)(n0-1024)*2048 + (m0 & 2047));
    #pragma unroll
    for (int it=0; it<4; ++it){
      const int g = (it*256 + tid)*16;
      const int row = g >> 7, off = g & 127;
      const int lb = row*128 + ((((off>>4) ^ (row&7)))<<4);
      uint4 val = *(const uint4*)(lds + lb);
      *(uint4*)(vb + (long)row*2048 + off) = val;
    }
  }
}

// ---------------------------------------------------------------------------
// gqk8: fp8 x fp8 QK GEMM (z2f8 x wqk28). Skeleton = gsc8 (P=2, VMW(4)/0).
// Weights pre-scaled x16; bias added as 16*bq. q,k out fp8 (16x scaled).
// ---------------------------------------------------------------------------
__global__ void __launch_bounds__(256, 2)
gqk8(const unsigned char* __restrict__ A, const unsigned char* __restrict__ Bw,
     unsigned char* __restrict__ Qo, unsigned char* __restrict__ Ko,
     const float* __restrict__ bq)
{
  constexpr int DBUF = 256*64;
  __shared__ __align__(16) char lds[3*DBUF];   // 48 KB

  const int gx = gridDim.x, gy = gridDim.y;
  const int nwg = gx*gy;
  const int flat = blockIdx.y*gx + blockIdx.x;
  const int q8 = nwg>>3, r8 = nwg&7, xcd = flat&7, o8 = flat>>3;
  const int w = (xcd<r8 ? xcd*(q8+1) : r8*(q8+1)+(xcd-r8)*q8) + o8;
  const int bx = w % gx, by = w / gx;
  const int m0 = by*128, n0 = bx*128;
  const int K = 512;

  const int tid = threadIdx.x;
  const int wid = tid>>6, lane = tid&63;
  const int lm = lane&15, kq = lane>>4;
  const int wm = wid>>1, wn = wid&1;
  const int srow = lane>>2;
  const int csw8 = ((lane&3) ^ ((lane>>3)&3))*16;
  int coff[2];
  #pragma unroll
  for (int ksl=0; ksl<2; ksl++)
    coff[ksl] = ((((ksl*2 + (kq>>1)) ^ ((lm>>1)&3)))<<4) + ((kq&1)<<3);

  f32x4 acc[4][4];
  #pragma unroll
  for (int i=0;i<4;i++)
    #pragma unroll
    for (int j=0;j<4;j++) acc[i][j] = f32x4{0.f,0.f,0.f,0.f};

  auto stage = [&](int kt){
    char* base = lds + (kt%3)*DBUF;
    const int k0 = kt*64;
    #pragma unroll
    for (int c=0;c<4;c++){
      const int r0 = c*64 + wid*16;
      char* d = base + r0*64;
      const unsigned char* g = (r0 < 128)
        ? A  + (long)(m0 + r0 + srow)*K + k0 + csw8
        : Bw + (long)(n0 + r0 - 128 + srow)*K + k0 + csw8;
      gl_lds16(g, d);
    }
  };

  long af[4][2], bf[4][2];
  auto readA = [&](int kt){
    char* base = lds + (kt%3)*DBUF;
    #pragma unroll
    for (int i2=0;i2<4;i2++)
      #pragma unroll
      for (int ksl=0;ksl<2;ksl++)
        af[i2][ksl] = *(const long*)(base + (wm*64 + i2*16 + lm)*64 + coff[ksl]);
  };
  auto readB = [&](int kt, int jh){
    char* base = lds + (kt%3)*DBUF;
    #pragma unroll
    for (int j2=0;j2<2;j2++)
      #pragma unroll
      for (int ksl=0;ksl<2;ksl++)
        bf[jh*2+j2][ksl] = *(const long*)(base + (128 + wn*64 + jh*32 + j2*16 + lm)*64 + coff[ksl]);
  };
  auto mfma16 = [&](int jh){
    __builtin_amdgcn_s_setprio(1);
    #pragma unroll
    for (int i2=0;i2<4;i2++)
      #pragma unroll
      for (int j2=0;j2<2;j2++)
        #pragma unroll
        for (int ksl=0;ksl<2;ksl++)
          acc[i2][jh*2+j2] = __builtin_amdgcn_mfma_f32_16x16x32_fp8_fp8(
              af[i2][ksl], bf[jh*2+j2][ksl], acc[i2][jh*2+j2], 0,0,0);
    __builtin_amdgcn_s_setprio(0);
  };

  const int NT = 8;
  stage(0); stage(1);
  for (int kt=0; kt<NT; ++kt){
    if (kt==NT-1) { VMW(0); } else { VMW(4); }
    barrier_raw();
    readA(kt); readB(kt,0);
    if (kt+2<NT) stage(kt+2);
    mfma16(0);
    readB(kt,1);
    mfma16(1);
  }
  barrier_raw();

  // ---- epilogue: +16*bias, fp8 q/k split (128B-row tiles) ----
  bool qh = n0 < 512;
  unsigned char* obase = (qh?Qo:Ko) + (long)m0*512 + (n0 - (qh?0:512));
  #pragma unroll
  for (int i=0;i<4;i++){
    #pragma unroll
    for (int j=0;j<4;j++){
      const int lcol = wn*64 + j*16 + lm;
      #pragma unroll
      for (int r=0;r<4;r++){
        const int lrow = wm*64 + i*16 + kq*4 + r;
        float v = acc[i][j][r] + 16.f*bq[n0 + lcol];
        const int lb = lrow*128 + ((((lcol>>4) ^ (lrow&7)))<<4) + (lcol&15);
        *(unsigned char*)(lds + lb) = to_fp8(v);
      }
    }
  }
  LGKM0();
  barrier_raw();
  #pragma unroll
  for (int it=0; it<4; ++it){
    const int g = (it*256 + tid)*16;
    const int row = g >> 7, off = g & 127;
    const int lb = row*128 + ((((off>>4) ^ (row&7)))<<4);
    uint4 val = *(const uint4*)(lds + lb);
    *(uint4*)(obase + (long)row*512 + off) = val;
  }
}

// ---------------------------------------------------------------------------
// g4k8: fp8 x fp8 PV GEMM. 128x128, ring-of-4 (64 KB), P=3 -> VMW(8)/4/0.
// uav(fp8) = u * (wsc @ v_fm^T) / (den+eps).
// ---------------------------------------------------------------------------
__global__ void __launch_bounds__(256, 2)
g4k8(const unsigned char* __restrict__ A, const unsigned char* __restrict__ Bw,
     unsigned char* __restrict__ Out,
     const bhalf* __restrict__ ub, const float* __restrict__ rden,
     int K, long sB, int rowshift)
{
  constexpr int DBUF = 256*64;
  __shared__ __align__(16) char lds[4*DBUF];   // 64 KB

  const int gx = gridDim.x, gy = gridDim.y;
  const int nwg = gx*gy;
  const int flat = blockIdx.y*gx + blockIdx.x;
  const int q8 = nwg>>3, r8 = nwg&7, xcd = flat&7, o8 = flat>>3;
  const int w = (xcd<r8 ? xcd*(q8+1) : r8*(q8+1)+(xcd-r8)*q8) + o8;
  const int bx = w % gx, by = w / gx;
  const int m0 = by*128, n0 = bx*128;

  const unsigned char* Bb = Bw + (long)(m0>>rowshift)*sB;

  const int tid = threadIdx.x;
  const int wid = tid>>6, lane = tid&63;
  const int lm = lane&15, kq = lane>>4;
  const int wm = wid>>1, wn = wid&1;
  const int srow = lane>>2;
  const int csw8 = ((lane&3) ^ ((lane>>3)&3))*16;
  int coff[2];
  #pragma unroll
  for (int ksl=0; ksl<2; ksl++)
    coff[ksl] = ((((ksl*2 + (kq>>1)) ^ ((lm>>1)&3)))<<4) + ((kq&1)<<3);

  f32x4 acc[4][4];
  #pragma unroll
  for (int i=0;i<4;i++)
    #pragma unroll
    for (int j=0;j<4;j++) acc[i][j] = f32x4{0.f,0.f,0.f,0.f};

  auto stage = [&](int kt){
    char* base = lds + (kt&3)*DBUF;
    const int k0 = kt*64;
    #pragma unroll
    for (int c=0;c<4;c++){
      const int r0 = c*64 + wid*16;
      char* d = base + r0*64;
      const unsigned char* g = (r0 < 128)
        ? A  + (long)(m0 + r0 + srow)*K + k0 + csw8
        : Bb + (long)(n0 + r0 - 128 + srow)*K + k0 + csw8;
      gl_lds16(g, d);
    }
  };

  long af[4][2], bf[4][2];
  auto readA = [&](int kt){
    char* base = lds + (kt&3)*DBUF;
    #pragma unroll
    for (int i2=0;i2<4;i2++)
      #pragma unroll
      for (int ksl=0;ksl<2;ksl++)
        af[i2][ksl] = *(const long*)(base + (wm*64 + i2*16 + lm)*64 + coff[ksl]);
  };
  auto readB = [&](int kt, int jh){
    char* base = lds + (kt&3)*DBUF;
    #pragma unroll
    for (int j2=0;j2<2;j2++)
      #pragma unroll
      for (int ksl=0;ksl<2;ksl++)
        bf[jh*2+j2][ksl] = *(const long*)(base + (128 + wn*64 + jh*32 + j2*16 + lm)*64 + coff[ksl]);
  };
  auto mfma16 = [&](int jh){
    __builtin_amdgcn_s_setprio(1);
    #pragma unroll
    for (int i2=0;i2<4;i2++)
      #pragma unroll
      for (int j2=0;j2<2;j2++)
        #pragma unroll
        for (int ksl=0;ksl<2;ksl++)
          acc[i2][jh*2+j2] = __builtin_amdgcn_mfma_f32_16x16x32_fp8_fp8(
              af[i2][ksl], bf[jh*2+j2][ksl], acc[i2][jh*2+j2], 0,0,0);
    __builtin_amdgcn_s_setprio(0);
  };

  const int NT = K>>6;
  stage(0); stage(1); stage(2);                  // P=3 prologue
  for (int kt=0; kt<NT; ++kt){
    if (kt==NT-1)      { VMW(0); }
    else if (kt==NT-2) { VMW(4); }
    else               { VMW(8); }
    barrier_raw();
    readA(kt); readB(kt,0);
    if (kt+3<NT) stage(kt+3);
    mfma16(0);
    readB(kt,1);
    mfma16(1);
  }
  barrier_raw();

  // ---- epilogue: u-gate + normalize -> fp8 C-tile (128B rows) ----
  unsigned char* obase = Out + (long)m0*1024 + n0;
  #pragma unroll
  for (int i=0;i<4;i++){
    #pragma unroll
    for (int j=0;j<4;j++){
      const int lcol = wn*64 + j*16 + lm;
      #pragma unroll
      for (int r=0;r<4;r++){
        const int lrow = wm*64 + i*16 + kq*4 + r;
        const int rowg = m0 + lrow;
        float v = acc[i][j][r];
        float den = rden[rowg];
        v *= __builtin_amdgcn_rcpf(den + 1e-8f);
        v *= (float)ub[(long)rowg*1024 + n0 + lcol];
        const int lb = lrow*128 + ((((lcol>>4) ^ (lrow&7)))<<4) + (lcol&15);
        *(unsigned char*)(lds + lb) = to_fp8(v);
      }
    }
  }
  LGKM0();
  barrier_raw();
  #pragma unroll
  for (int it=0; it<4; ++it){
    const int g = (it*256 + tid)*16;
    const int row = g >> 7, off = g & 127;
    const int lb = row*128 + ((((off>>4) ^ (row&7)))<<4);
    uint4 val = *(const uint4*)(lds + lb);
    *(uint4*)(obase + (long)row*1024 + off) = val;
  }
}

// ---------------------------------------------------------------------------
// gy8: fp8 x fp8 Y GEMM (uav8 x wo8, K=1024, NT=16). Skeleton = g4k8
// (P=3 -> VMW(8)/4/0). Weights pre-scaled x16 -> epilogue x(1/16) + bias + x.
// out[b][c][n] fp32, fused residual add (transposed fp32 tile).
// ---------------------------------------------------------------------------
__global__ void __launch_bounds__(256, 2)
gy8(const unsigned char* __restrict__ A, const unsigned char* __restrict__ Bw,
    float* __restrict__ Out, const float* __restrict__ bias,
    const float* __restrict__ xadd)
{
  constexpr int DBUF = 256*64;
  __shared__ __align__(16) char lds[4*DBUF];   // 64 KB

  const int gx = gridDim.x, gy = gridDim.y;
  const int nwg = gx*gy;
  const int flat = blockIdx.y*gx + blockIdx.x;
  const int q8 = nwg>>3, r8 = nwg&7, xcd = flat&7, o8 = flat>>3;
  const int w = (xcd<r8 ? xcd*(q8+1) : r8*(q8+1)+(xcd-r8)*q8) + o8;
  const int bx = w % gx, by = w / gx;
  const int m0 = by*128, n0 = bx*128;
  const int K = 1024;

  const int tid = threadIdx.x;
  const int wid = tid>>6, lane = tid&63;
  const int lm = lane&15, kq = lane>>4;
  const int wm = wid>>1, wn = wid&1;
  const int srow = lane>>2;
  const int csw8 = ((lane&3) ^ ((lane>>3)&3))*16;
  int coff[2];
  #pragma unroll
  for (int ksl=0; ksl<2; ksl++)
    coff[ksl] = ((((ksl*2 + (kq>>1)) ^ ((lm>>1)&3)))<<4) + ((kq&1)<<3);

  f32x4 acc[4][4];
  #pragma unroll
  for (int i=0;i<4;i++)
    #pragma unroll
    for (int j=0;j<4;j++) acc[i][j] = f32x4{0.f,0.f,0.f,0.f};

  auto stage = [&](int kt){
    char* base = lds + (kt&3)*DBUF;
    const int k0 = kt*64;
    #pragma unroll
    for (int c=0;c<4;c++){
      const int r0 = c*64 + wid*16;
      char* d = base + r0*64;
      const unsigned char* g = (r0 < 128)
        ? A  + (long)(m0 + r0 + srow)*K + k0 + csw8
        : Bw + (long)(n0 + r0 - 128 + srow)*K + k0 + csw8;
      gl_lds16(g, d);
    }
  };

  long af[4][2], bf[4][2];
  auto readA = [&](int kt){
    char* base = lds + (kt&3)*DBUF;
    #pragma unroll
    for (int i2=0;i2<4;i2++)
      #pragma unroll
      for (int ksl=0;ksl<2;ksl++)
        af[i2][ksl] = *(const long*)(base + (wm*64 + i2*16 + lm)*64 + coff[ksl]);
  };
  auto readB = [&](int kt, int jh){
    char* base = lds + (kt&3)*DBUF;
    #pragma unroll
    for (int j2=0;j2<2;j2++)
      #pragma unroll
      for (int ksl=0;ksl<2;ksl++)
        bf[jh*2+j2][ksl] = *(const long*)(base + (128 + wn*64 + jh*32 + j2*16 + lm)*64 + coff[ksl]);
  };
  auto mfma16 = [&](int jh){
    __builtin_amdgcn_s_setprio(1);
    #pragma unroll
    for (int i2=0;i2<4;i2++)
      #pragma unroll
      for (int j2=0;j2<2;j2++)
        #pragma unroll
        for (int ksl=0;ksl<2;ksl++)
          acc[i2][jh*2+j2] = __builtin_amdgcn_mfma_f32_16x16x32_fp8_fp8(
              af[i2][ksl], bf[jh*2+j2][ksl], acc[i2][jh*2+j2], 0,0,0);
    __builtin_amdgcn_s_setprio(0);
  };

  const int NT = 16;
  stage(0); stage(1); stage(2);                  // P=3 prologue
  for (int kt=0; kt<NT; ++kt){
    if (kt==NT-1)      { VMW(0); }
    else if (kt==NT-2) { VMW(4); }
    else               { VMW(8); }
    barrier_raw();
    readA(kt); readB(kt,0);
    if (kt+3<NT) stage(kt+3);
    mfma16(0);
    readB(kt,1);
    mfma16(1);
  }
  barrier_raw();

  // ---- epilogue: x(1/16) + bias -> fp32 transposed tile -> out = x + y ----
  #pragma unroll
  for (int i=0;i<4;i++){
    #pragma unroll
    for (int j=0;j<4;j++){
      const int lcol = wn*64 + j*16 + lm;
      #pragma unroll
      for (int r=0;r<4;r++){
        const int lrow = wm*64 + i*16 + kq*4 + r;
        float v = acc[i][j][r]*0.0625f + bias[n0 + lcol];
        const int lb = lcol*512 + 4*(lrow ^ ((lcol&15)<<2));
        *(float*)(lds + lb) = v;
      }
    }
  }
  LGKM0();
  barrier_raw();
  const int b = m0 >> 11, nb = m0 & 2047;
  float* ob = Out + ((long)b*512 + n0)*2048 + nb;
  const float* xb = xadd + ((long)b*512 + n0)*2048 + nb;
  #pragma unroll
  for (int it=0; it<16; ++it){
    const int g = (it*256 + tid)*16;
    const int row = g >> 9, off = g & 511;
    const int t0 = off >> 2;
    const int s = (row&15)<<2;
    f32x4 vv = *(const f32x4*)(lds + row*512 + 4*(t0^s));
    f32x4 xx = *(const f32x4*)(xb + (long)row*2048 + t0);
    *(f32x4*)(ob + (long)row*2048 + t0) = vv + xx;
  }
}

// ---------------------------------------------------------------------------
// g4k: bf16 128x128, 2 dbufs, 2-ahead, VMW(8)/0. For z2 (fp8 out) / wqk2 (ST).
// ---------------------------------------------------------------------------
template<int EPI>
__global__ void __launch_bounds__(256, 2)
g4k(const bhalf* __restrict__ A, const bhalf* __restrict__ Bw,
    void* __restrict__ Out,
    const bhalf* __restrict__ auxb,
    int M, int N, int K)
{
  constexpr int KSL = 256*64;
  constexpr int DBUF = 2*KSL;     // 32 KB
  __shared__ __align__(16) char lds[2*DBUF];   // 64 KB

  const int gx = gridDim.x, gy = gridDim.y;
  const int nwg = gx*gy;
  const int flat = blockIdx.y*gx + blockIdx.x;
  const int q8 = nwg>>3, r8 = nwg&7, xcd = flat&7, o8 = flat>>3;
  const int w = (xcd<r8 ? xcd*(q8+1) : r8*(q8+1)+(xcd-r8)*q8) + o8;
  const int bx = w % gx, by = w / gx;
  const int m0 = by*128, n0 = bx*128;

  const int tid = threadIdx.x;
  const int wid = tid>>6, lane = tid&63;
  const int lm = lane&15, kq = lane>>4;
  const int wm = wid>>1, wn = wid&1;
  const int srow = lane>>2;
  const int csw = ((lane&3) ^ ((lane>>3)&3))*8;
  const int kqs = kq ^ ((lm>>1)&3);

  f32x4 acc[4][4];
  #pragma unroll
  for (int i=0;i<4;i++)
    #pragma unroll
    for (int j=0;j<4;j++) acc[i][j] = f32x4{0.f,0.f,0.f,0.f};

  auto stage = [&](int kt){                      // 8 loads/wave
    char* base = lds + (kt&1)*DBUF;
    const int k0 = kt*64;
    #pragma unroll
    for (int c=0;c<4;c++){
      const int r0 = c*64 + wid*16;
      #pragma unroll
      for (int ksl=0; ksl<2; ksl++){
        bhalf* d = (bhalf*)(base + ksl*KSL + r0*64);
        const bhalf* g = (r0 < 128)
          ? A  + (long)(m0 + r0 + srow)*K + k0 + ksl*32 + csw
          : Bw + (long)(n0 + r0 - 128 + srow)*K + k0 + ksl*32 + csw;
        gl_lds16(g, d);
      }
    }
  };

  bhalf8 af[4][2], bf[4][2];
  auto readA = [&](int kt){
    char* base = lds + (kt&1)*DBUF;
    #pragma unroll
    for (int i2=0;i2<4;i2++)
      #pragma unroll
      for (int ksl=0;ksl<2;ksl++)
        af[i2][ksl] = *(const bhalf8*)(base + ksl*KSL + (wm*64 + i2*16 + lm)*64 + kqs*16);
  };
  auto readB = [&](int kt, int jh){
    char* base = lds + (kt&1)*DBUF;
    #pragma unroll
    for (int j2=0;j2<2;j2++)
      #pragma unroll
      for (int ksl=0;ksl<2;ksl++)
        bf[jh*2+j2][ksl] = *(const bhalf8*)(base + ksl*KSL + (128 + wn*64 + jh*32 + j2*16 + lm)*64 + kqs*16);
  };
  auto mfma16 = [&](int jh){
    __builtin_amdgcn_s_setprio(1);
    #pragma unroll
    for (int i2=0;i2<4;i2++)
      #pragma unroll
      for (int j2=0;j2<2;j2++)
        #pragma unroll
        for (int ksl=0;ksl<2;ksl++)
          acc[i2][jh*2+j2] = __builtin_amdgcn_mfma_f32_16x16x32_bf16(
              af[i2][ksl], bf[jh*2+j2][ksl], acc[i2][jh*2+j2], 0,0,0);
    __builtin_amdgcn_s_setprio(0);
  };

  const int NT = K>>6;
  stage(0); stage(1);
  for (int kt=0; kt<NT; ++kt){
    if (kt==NT-1) { VMW(0); } else { VMW(8); }
    barrier_raw();
    readA(kt); readB(kt,0);
    mfma16(0);
    barrier_raw();
    readB(kt,1);
    if (kt+2<NT) stage(kt+2);
    mfma16(1);
  }
  barrier_raw();

  if constexpr (EPI==EPI_Z2){
    // z2 = acc + z (aux); fp8-only out, 128B-row tile
    unsigned char* obase = (unsigned char*)Out + (long)m0*N + n0;
    #pragma unroll
    for (int i=0;i<4;i++){
      #pragma unroll
      for (int j=0;j<4;j++){
        const int lcol = wn*64 + j*16 + lm;
        #pragma unroll
        for (int r=0;r<4;r++){
          const int lrow = wm*64 + i*16 + kq*4 + r;
          float v = acc[i][j][r] + (float)auxb[(long)(m0+lrow)*N + n0 + lcol];
          const int lb = lrow*128 + ((((lcol>>4) ^ (lrow&7)))<<4) + (lcol&15);
          *(unsigned char*)(lds + lb) = to_fp8(v);
        }
      }
    }
    LGKM0();
    barrier_raw();
    #pragma unroll
    for (int it=0; it<4; ++it){
      const int g = (it*256 + tid)*16;
      const int row = g >> 7, off = g & 127;
      const int lb = row*128 + ((((off>>4) ^ (row&7)))<<4);
      uint4 val = *(const uint4*)(lds + lb);
      *(uint4*)(obase + (long)row*N + off) = val;
    }
  } else {
    // EPI_ST: plain bf16 out (wqk2)
    char* obase = (char*)Out + 2*((long)m0*N + n0);
    const int ldb = N*2;
    #pragma unroll
    for (int i=0;i<4;i++){
      #pragma unroll
      for (int j=0;j<4;j++){
        const int lcol = wn*64 + j*16 + lm;
        #pragma unroll
        for (int r=0;r<4;r++){
          const int lrow = wm*64 + i*16 + kq*4 + r;
          const int cb = lcol*2;
          const int lb = lrow*256 + (((cb>>5) ^ ((lrow>>2)&3))<<5) + (cb&31);
          *(bhalf*)(lds + lb) = (bhalf)acc[i][j][r];
        }
      }
    }
    LGKM0();
    barrier_raw();
    #pragma unroll
    for (int it=0; it<8; ++it){
      const int g = (it*256 + tid)*16;
      const int row = g >> 8, off = g & 255;
      const int lb = row*256 + (((off>>5) ^ ((row>>2)&3))<<5) + (off&31);
      uint4 val = *(const uint4*)(lds + lb);
      *(uint4*)(obase + (long)row*ldb + off) = val;
    }
  }
  (void)M; (void)auxb;
}

// ---------------------------------------------------------------------------
struct CvtArgs { const float* src[4]; bhalf* dst[4]; int n[4]; };
__global__ void cvt_multi(CvtArgs a) {
  int seg = blockIdx.y;
  int i = (blockIdx.x*256 + threadIdx.x)*4;
  if (i >= a.n[seg]) return;
  float4 f = *(const float4*)(a.src[seg] + i);
  bhalf* d = a.dst[seg] + i;
  d[0]=(bhalf)f.x; d[1]=(bhalf)f.y; d[2]=(bhalf)f.z; d[3]=(bhalf)f.w;
}

__global__ void cvt_fp8(const float* __restrict__ src, unsigned char* __restrict__ dst,
                        int n, float scale){
  int i = (blockIdx.x*256 + threadIdx.x)*4;
  if (i >= n) return;
  float4 f = *(const float4*)(src + i);
  dst[i+0]=to_fp8(f.x*scale); dst[i+1]=to_fp8(f.y*scale);
  dst[i+2]=to_fp8(f.z*scale); dst[i+3]=to_fp8(f.w*scale);
}

__global__ void cvt_b2f8(const bhalf* __restrict__ src, unsigned char* __restrict__ dst,
                         int n, float scale){
  int i = (blockIdx.x*256 + threadIdx.x)*4;
  if (i >= n) return;
  #pragma unroll
  for (int j=0;j<4;j++) dst[i+j] = to_fp8((float)src[i+j]*scale);
}

// bf16 transpose: in [R,C] -> out [C,R]
__global__ void transpose_bf16(const bhalf* __restrict__ in, bhalf* __restrict__ out,
                               int R, int C) {
  __shared__ bhalf t[32][33];
  int r0 = blockIdx.x*32, c0 = blockIdx.y*32;
  int tx = threadIdx.x, ty = threadIdx.y;
  #pragma unroll
  for (int r=0;r<4;r++)
    t[ty + r*8][tx] = in[(long)(r0 + ty + r*8)*C + c0 + tx];
  __syncthreads();
  #pragma unroll
  for (int r=0;r<4;r++)
    out[(long)(c0 + ty + r*8)*R + r0 + tx] = t[tx][ty + r*8];
}

// bq[row] = sum_m wqk[row][m] * hb[m]
__global__ void qk_bias(const bhalf* __restrict__ wqk, const float* __restrict__ hb,
                        float* __restrict__ bq){
  int row = blockIdx.x*4 + (threadIdx.x>>6);
  int lane = threadIdx.x & 63;
  const bhalf* p = wqk + (long)row*512;
  float s = 0.f;
  #pragma unroll
  for (int j=0;j<8;j++) s += (float)p[lane*8+j] * hb[lane*8+j];
  for (int off=32; off; off>>=1) s += __shfl_xor(s, off);
  if (lane==0) bq[row] = s;
}

__global__ void gn_part(const float* __restrict__ x, float* __restrict__ ps, float* __restrict__ pss) {
  int b = blockIdx.y;
  const float* xb = x + (long)b*(512*2048);
  float s=0.f, ss=0.f;
  #pragma unroll
  for (int it=0; it<8; it++){
    int idx = ((it*128 + blockIdx.x)*256 + threadIdx.x)*4;
    float4 f = *(const float4*)(xb + idx);
    s  += f.x+f.y+f.z+f.w;
    ss += f.x*f.x+f.y*f.y+f.z*f.z+f.w*f.w;
  }
  for (int off=32; off; off>>=1){ s += __shfl_xor(s,off); ss += __shfl_xor(ss,off); }
  __shared__ float ls[4], lss[4];
  int wid = threadIdx.x>>6, lane = threadIdx.x&63;
  if (lane==0){ ls[wid]=s; lss[wid]=ss; }
  __syncthreads();
  if (threadIdx.x==0){
    s = ls[0]+ls[1]+ls[2]+ls[3]; ss = lss[0]+lss[1]+lss[2]+lss[3];
    ps[b*128 + blockIdx.x] = s; pss[b*128 + blockIdx.x] = ss;
  }
}

__global__ void gn_final(const float* __restrict__ ps, const float* __restrict__ pss,
                         float* __restrict__ stats) {
  int b = blockIdx.x;
  float s = ps[b*128 + threadIdx.x], ss = pss[b*128 + threadIdx.x];
  for (int off=32; off; off>>=1){ s += __shfl_xor(s,off); ss += __shfl_xor(ss,off); }
  __shared__ float l0[2], l1[2];
  int wid = threadIdx.x>>6, lane = threadIdx.x&63;
  if (lane==0){ l0[wid]=s; l1[wid]=ss; }
  __syncthreads();
  if (threadIdx.x==0){
    s = l0[0]+l0[1]; ss = l1[0]+l1[1];
    float mean = s*(1.f/1048576.f);
    float var  = ss*(1.f/1048576.f) - mean*mean;
    stats[b*2] = mean; stats[b*2+1] = rsqrtf(var + 1e-8f);
  }
}

__global__ void norm_dw_T(const float* __restrict__ x, const float* __restrict__ stats,
                          const float* __restrict__ dw_w,
                          bhalf* __restrict__ zT, bhalf* __restrict__ dwT) {
  int b = blockIdx.z, n0 = blockIdx.x*32, c0 = blockIdx.y*32;
  float mean = stats[b*2], rstd = stats[b*2+1];
  __shared__ float zs[32][35];
  int tx = threadIdx.x, ty = threadIdx.y;
  #pragma unroll
  for (int r=0;r<4;r++){
    int c = c0 + ty + r*8;
    for (int cc=tx; cc<34; cc+=32){
      int n = n0 - 1 + cc;
      float v = 0.f;
      if (n>=0 && n<2048) v = (x[((long)b*512 + c)*2048 + n] - mean)*rstd;
      zs[ty + r*8][cc] = v;
    }
  }
  __syncthreads();
  float w0 = dw_w[(c0+tx)*3+0], w1 = dw_w[(c0+tx)*3+1], w2 = dw_w[(c0+tx)*3+2];
  #pragma unroll
  for (int r=0;r<4;r++){
    int ln = ty + r*8;
    float z = zs[tx][ln+1];
    float d = w0*zs[tx][ln] + w1*zs[tx][ln+1] + w2*zs[tx][ln+2];
    long o = ((long)b*2048 + n0 + ln)*512 + c0 + tx;
    zT[o] = (bhalf)z; dwT[o] = (bhalf)d;
  }
}

// ---------------------------------------------------------------------------
extern "C" void kernel_launch(void* const* d_in, const int* in_sizes, int n_in,
                              void* d_out, int out_size, void* d_ws, size_t ws_size,
                              hipStream_t stream) {
  (void)in_sizes; (void)n_in; (void)out_size; (void)ws_size;
  const float* x    = (const float*)d_in[0];
  const float* dw_w = (const float*)d_in[1];
  const float* pw_w = (const float*)d_in[2];
  const float* u_w  = (const float*)d_in[3];
  const float* u_b  = (const float*)d_in[4];
  const float* v_w  = (const float*)d_in[5];
  const float* v_b  = (const float*)d_in[6];
  const float* h_w  = (const float*)d_in[7];
  const float* h_b  = (const float*)d_in[8];
  const float* q_w  = (const float*)d_in[9];
  const float* k_w  = (const float*)d_in[10];
  const float* o_w  = (const float*)d_in[11];
  const float* o_b  = (const float*)d_in[12];
  float* out = (float*)d_out;

  char* ws = (char*)d_ws;
  size_t off = 0;
  auto alloc = [&](size_t bytes) -> void* {
    void* p = ws + off; off = (off + bytes + 255) & ~(size_t)255; return p;
  };

  float* ps    = (float*)alloc(4*128*4);
  float* pss   = (float*)alloc(4*128*4);
  float* stats = (float*)alloc(4*2*4);
  float* rden  = (float*)alloc(4*2048*4);
  float* bq    = (float*)alloc(1024*4);
  bhalf* wb_pw = (bhalf*)alloc(512*512*2);
  unsigned char* wuv8  = (unsigned char*)alloc((size_t)2048*512);  // fp8 u|v
  unsigned char* wo8   = (unsigned char*)alloc((size_t)512*1024);  // fp8 16*o_w
  bhalf* wb_h  = (bhalf*)alloc(512*512*2);
  bhalf* hwT   = (bhalf*)alloc(512*512*2);
  bhalf* wb_qk = (bhalf*)alloc((size_t)1024*512*2);
  bhalf* wqk2  = (bhalf*)alloc((size_t)1024*512*2);
  unsigned char* wqk28 = (unsigned char*)alloc((size_t)1024*512);  // fp8 16*wqk2
  const size_t ACT = (size_t)4*2048*512;
  bhalf* zT   = (bhalf*)alloc(ACT*2);
  bhalf* dwT  = (bhalf*)alloc(ACT*2);
  unsigned char* z2f8 = (unsigned char*)alloc(ACT);                 // fp8 z2
  bhalf* ub   = (bhalf*)alloc(ACT*2*2);     // [B,N,1024] bf16
  unsigned char* v_fm = (unsigned char*)alloc((size_t)4*1024*2048); // fp8
  unsigned char* wsc  = (unsigned char*)alloc((size_t)4*2048*2048); // fp8
  unsigned char* qb8  = (unsigned char*)alloc(ACT);                 // fp8 16q
  unsigned char* kb8  = (unsigned char*)alloc(ACT);                 // fp8 16k
  unsigned char* uav8 = (unsigned char*)alloc(ACT*2);               // fp8 uav

  // 0. zero attention-denominator accumulators
  hipMemsetAsync(rden, 0, 4*2048*4, stream);

  // 1. weights -> bf16 (pw, h, q, k); fp8 (u|v x1, o x16)
  CvtArgs ca;
  ca.src[0]=pw_w; ca.dst[0]=wb_pw;           ca.n[0]=512*512;
  ca.src[1]=h_w;  ca.dst[1]=wb_h;            ca.n[1]=512*512;
  ca.src[2]=q_w;  ca.dst[2]=wb_qk;           ca.n[2]=512*512;
  ca.src[3]=k_w;  ca.dst[3]=wb_qk+512*512;   ca.n[3]=512*512;
  cvt_multi<<<dim3(512,4), 256, 0, stream>>>(ca);
  cvt_fp8<<<dim3(512), 256, 0, stream>>>(u_w, wuv8,          1024*512, 1.f);
  cvt_fp8<<<dim3(512), 256, 0, stream>>>(v_w, wuv8+1024*512, 1024*512, 1.f);
  cvt_fp8<<<dim3(512), 256, 0, stream>>>(o_w, wo8,           512*1024, 16.f);

  // 2. fold h into q/k: wqk2 = [q_w;k_w] @ h_w (bf16), bq = [q_w;k_w] @ h_b,
  //    wqk28 = fp8(16 * wqk2)
  transpose_bf16<<<dim3(16,16), dim3(32,8), 0, stream>>>(wb_h, hwT, 512, 512);
  g4k<EPI_ST><<<dim3(4,8,1), 256, 0, stream>>>(wb_qk, hwT, wqk2, nullptr,
      1024, 512, 512);
  qk_bias<<<dim3(256), 256, 0, stream>>>(wb_qk, h_b, bq);
  cvt_b2f8<<<dim3(512), 256, 0, stream>>>(wqk2, wqk28, 1024*512, 16.f);

  // 3-4. GroupNorm stats
  gn_part<<<dim3(128,4), 256, 0, stream>>>(x, ps, pss);
  gn_final<<<dim3(4), 128, 0, stream>>>(ps, pss, stats);

  // 5. normalize + dw conv + transpose -> zT, dwT
  norm_dw_T<<<dim3(64,16,4), dim3(32,8), 0, stream>>>(x, stats, dw_w, zT, dwT);

  const float iscl256 = 0.044194173824159216f / 256.f;  // (1/sqrt(512))/256
  // 6. z2(fp8) = z + dw @ pw^T
  g4k<EPI_Z2><<<dim3(4,64,1), 256, 0, stream>>>(dwT, wb_pw, z2f8, zT,
      8192, 512, 512);
  // 7. [u|v] = z2f8 @ wuv8^T + b  (fp8; u->ub bf16, v->v_fm fp8)
  guv8<<<dim3(16,64,1), 256, 0, stream>>>(z2f8, wuv8, ub, v_fm, u_b, v_b);
  // 8. [q|k](fp8, 16x) = z2f8 @ wqk28^T + 16*bq
  gqk8<<<dim3(8,64,1), 256, 0, stream>>>(z2f8, wqk28, qb8, kb8, bq);
  // 9. wsc(fp8) = relu(q'k' * iscl/256)^2 + fused row-sum atomics
  gsc8<<<dim3(16,16,4), 256, 0, stream>>>(qb8, kb8, wsc, rden, iscl256);
  // 10. uav(fp8) = u * (wsc @ v_fm^T) / (den+eps)
  g4k8<<<dim3(8,64,1), 256, 0, stream>>>(wsc, v_fm, uav8, ub, rden,
      2048, (long)1024*2048, 11);
  // 11. out = x + (uav8 @ wo8^T)/16 + o_b   (fp8 Y, fused residual)
  gy8<<<dim3(4,64,1), 256, 0, stream>>>(uav8, wo8, out, o_b, x);
}